// Round 3
// baseline (553.355 us; speedup 1.0000x reference)
//
#include <hip/hip_runtime.h>
#include <stdint.h>

// ---------------- constants ----------------
namespace {
constexpr int B_ = 128;
constexpr int L_ = 50;
constexpr int D_ = 128;
constexpr int S_ = 8;
constexpr int NSC_ = 99999;       // NUM_NODE-1
constexpr int NBR_ = 9;
}
#define LEAKY_ 0.2f
#define BETA_ 0.005f

typedef __attribute__((ext_vector_type(8))) __bf16 bf16x8;
typedef __attribute__((ext_vector_type(4))) float f32x4;

__device__ __forceinline__ float leaky_(float x){ return x >= 0.f ? x : LEAKY_*x; }
__device__ __forceinline__ float sigm_(float x){ return 1.f/(1.f+expf(-x)); }

__device__ __forceinline__ short f2b(float f){
  uint32_t u = __float_as_uint(f);
  u += 0x7fffu + ((u >> 16) & 1u);
  return (short)(u >> 16);
}
__device__ __forceinline__ float b2f(short s){
  return __uint_as_float(((uint32_t)(uint16_t)s) << 16);
}
__device__ __forceinline__ f32x4 zero4(){ f32x4 z = {0.f,0.f,0.f,0.f}; return z; }
__device__ __forceinline__ f32x4 mfma_bf16(bf16x8 a, bf16x8 b, f32x4 c){
  return __builtin_amdgcn_mfma_f32_16x16x32_bf16(a, b, c, 0, 0, 0);
}

// ---------------- threefry2x32 (JAX-compatible) ----------------
__device__ __forceinline__ void tf2x32(uint32_t k0, uint32_t k1, uint32_t c0, uint32_t c1,
                                       uint32_t* o0, uint32_t* o1){
  uint32_t ks2 = k0 ^ k1 ^ 0x1BD11BDAu;
  uint32_t x0 = c0 + k0, x1 = c1 + k1;
#define RND_(r) { x0 += x1; x1 = (x1<<(r))|(x1>>(32-(r))); x1 ^= x0; }
  RND_(13) RND_(15) RND_(26) RND_(6)   x0 += k1;  x1 += ks2 + 1u;
  RND_(17) RND_(29) RND_(16) RND_(24)  x0 += ks2; x1 += k0  + 2u;
  RND_(13) RND_(15) RND_(26) RND_(6)   x0 += k0;  x1 += k1  + 3u;
  RND_(17) RND_(29) RND_(16) RND_(24)  x0 += k1;  x1 += ks2 + 4u;
  RND_(13) RND_(15) RND_(26) RND_(6)   x0 += ks2; x1 += k0  + 5u;
#undef RND_
  *o0 = x0; *o1 = x1;
}

// ---------------- fused prep: embB + weight transposes + sess ----------------
__global__ __launch_bounds__(256) void k_prep_all(
    const float* __restrict__ emb, const int* __restrict__ item,
    const int* __restrict__ mask, const float* __restrict__ gw1,
    const float* __restrict__ gw3, const float* __restrict__ glu1w,
    short* __restrict__ embB, float* __restrict__ w1T,
    float* __restrict__ glu1wT, short* __restrict__ w3T,
    float* __restrict__ sess)
{
  int blk = blockIdx.x, tid = threadIdx.x;
  if (blk < 3125){
    size_t base = (size_t)blk*4096 + (size_t)tid*16;
    float4 f0 = *(const float4*)(emb + base);
    float4 f1 = *(const float4*)(emb + base + 4);
    float4 f2 = *(const float4*)(emb + base + 8);
    float4 f3 = *(const float4*)(emb + base + 12);
    short4 s0, s1, s2, s3;
    s0.x=f2b(f0.x); s0.y=f2b(f0.y); s0.z=f2b(f0.z); s0.w=f2b(f0.w);
    s1.x=f2b(f1.x); s1.y=f2b(f1.y); s1.z=f2b(f1.z); s1.w=f2b(f1.w);
    s2.x=f2b(f2.x); s2.y=f2b(f2.y); s2.z=f2b(f2.z); s2.w=f2b(f2.w);
    s3.x=f2b(f3.x); s3.y=f2b(f3.y); s3.z=f2b(f3.z); s3.w=f2b(f3.w);
    *(short4*)(embB + base)      = s0;
    *(short4*)(embB + base + 4)  = s1;
    *(short4*)(embB + base + 8)  = s2;
    *(short4*)(embB + base + 12) = s3;
  } else if (blk < 3573){
    int o = (blk - 3125)*256 + tid;
    if (o < 32768){
      int hop = o >> 14, r = o & 16383;
      int d = r >> 7, e = r & 127;
      w1T[o] = gw1[hop*(129*128) + e*128 + d];
    } else if (o < 49152){
      int o2 = o - 32768;
      int e = o2 >> 7, t = o2 & 127;
      glu1wT[o2] = glu1w[t*128 + e];
    } else if (o < 114688){
      int o3 = o - 49152;
      int hop = o3 >> 15, r = o3 & 32767;
      int nn = r >> 8, k = r & 255;
      w3T[hop*(128*264) + nn*264 + k] = f2b(gw3[hop*(256*128) + k*128 + nn]);
    }
  } else {
    int b = blk - 3573;
    if (tid < 128){
      float acc = 0.f, ms = 0.f;
      for (int l = 0; l < L_; l++){
        float mk = (float)mask[b*L_ + l];
        ms += mk;
        acc += mk * emb[(size_t)item[b*L_ + l]*D_ + tid];
      }
      sess[(size_t)b*D_ + tid] = acc / ms;
    }
  }
}

// ---------------- fused stage2: Bsess + 2-hop sampling ----------------
__global__ __launch_bounds__(256) void k_stage2(
    const float* __restrict__ w1T, const float* __restrict__ sess,
    const int* __restrict__ inputs, const int* __restrict__ adj_all,
    const float* __restrict__ num_w,
    short* __restrict__ Bsess, int* __restrict__ n1i, float* __restrict__ n1w,
    int* __restrict__ n2i, float* __restrict__ n2w)
{
  int blk = blockIdx.x, tid = threadIdx.x;
  if (blk < 256){
    int hop = blk >> 7, b = blk & 127;
    const float* wt = w1T + hop*16384;
    short* outp = Bsess + ((size_t)hop*128 + b)*16384;
    __shared__ float sessS[128];
    if (tid < 128) sessS[tid] = sess[b*128 + tid];
    __syncthreads();
    for (int it = 0; it < 64; it++){
      int u = it*256 + tid;
      outp[u] = f2b(wt[u] * sessS[u & 127]);
    }
  } else {
    int p = (blk - 256)*256 + tid;   // p < 51200
    int base = inputs[p >> 3];
    int off  = base*S_ + (p & 7);
    int i1 = adj_all[off];
    n1i[p] = i1;
    n1w[p] = num_w[off];
#pragma unroll
    for (int j = 0; j < 8; j++){
      n2i[(size_t)p*8 + j] = adj_all[i1*8 + j];
      n2w[(size_t)p*8 + j] = num_w[i1*8 + j];
    }
  }
}

// ---------------- local GAT aggregation ----------------
__global__ __launch_bounds__(256) void k_local(const int* __restrict__ inputs,
                                               const short* __restrict__ embB,
                                               const int* __restrict__ adj,
                                               const float* __restrict__ a_local,
                                               float* __restrict__ hl){
  __shared__ float hs[L_*129];
  __shared__ float att[25*52];
  __shared__ float al[4*132];
  __shared__ int idxs[L_];
  int b = blockIdx.y, half = blockIdx.x, tid = threadIdx.x;
  int i0 = half*25;
  if (tid < L_) idxs[tid] = inputs[b*L_ + tid];
  __syncthreads();
  for (int u = tid; u < L_*16; u += 256){
    int i = u >> 4, c = u & 15;
    union { bf16x8 v; short sh[8]; } w;
    w.v = *(const bf16x8*)&embB[(size_t)idxs[i]*128 + c*8];
#pragma unroll
    for (int j = 0; j < 8; j++) hs[i*129 + c*8 + j] = b2f(w.sh[j]);
  }
  for (int e = tid; e < 4*D_; e += 256) al[(e>>7)*132 + (e&127)] = a_local[e];
  __syncthreads();
  for (int p = tid; p < 25*L_; p += 256){
    int il = p / L_, j = p % L_;
    int i = i0 + il;
    int k = adj[((size_t)b*L_ + i)*L_ + j];
    float v = -9e15f;
    if (k >= 1){
      const float* ak = &al[(k-1)*132];
      float acc = 0.f;
      for (int d = 0; d < D_; d++) acc += hs[i*129+d]*hs[j*129+d]*ak[d];
      v = leaky_(acc);
    }
    att[il*52 + j] = v;
  }
  __syncthreads();
  if (tid < 25){
    int il = tid;
    float mx = -INFINITY;
    for (int j = 0; j < L_; j++) mx = fmaxf(mx, att[il*52+j]);
    float sm = 0.f;
    for (int j = 0; j < L_; j++){ float e_ = expf(att[il*52+j] - mx); att[il*52+j] = e_; sm += e_; }
    float inv = 1.f/sm;
    for (int j = 0; j < L_; j++) att[il*52+j] *= inv;
  }
  __syncthreads();
  for (int q = tid; q < 25*D_; q += 256){
    int il = q >> 7, d = q & 127;
    float acc = 0.f;
    for (int j = 0; j < L_; j++) acc += att[il*52+j]*hs[j*129+d];
    hl[((size_t)b*L_ + i0 + il)*D_ + d] = acc;
  }
}

// ---------------- MFMA global-agg attention (bf16 in, bf16 out) — R1 structure --------
__global__ __launch_bounds__(256, 4) void k_att(
    const short* __restrict__ embB, const short* __restrict__ denseB,
    const int* __restrict__ nidx, const float* __restrict__ nw,
    const short* __restrict__ Bsess,
    const float* __restrict__ w1g, const float* __restrict__ w2g,
    short* __restrict__ outn, int rpb)
{
  __shared__ __align__(16) short As[128*136];
  __shared__ float w1lS[128], w2S[128], nwsS[128], logitsS[128], alphaS[128];
  const int tid = threadIdx.x;
  const int b = blockIdx.y;
  const int r0 = blockIdx.x * 128;
  if (tid < 128){
    w1lS[tid]  = w1g[128*128 + tid];
    w2S[tid]   = w2g[tid];
    int rr = min(r0 + tid, rpb - 1);
    nwsS[tid]  = nw[(size_t)b*rpb + rr];
  }
  for (int it = 0; it < 8; it++){
    int u = it*256 + tid;
    int lr = u >> 4, c = u & 15;
    int rr = min(r0 + lr, rpb - 1);
    const short* src = denseB ? denseB + ((size_t)b*rpb + rr)*128
                              : embB + (size_t)nidx[(size_t)b*rpb + rr]*128;
    *(bf16x8*)&As[lr*136 + c*8] = *(const bf16x8*)&src[c*8];
  }
  __syncthreads();
  const int lane = tid & 63, wave = tid >> 6;
  const int quad = lane >> 4, l16 = lane & 15;
  const int wr0 = wave * 32;
  const short* Bb = Bsess + (size_t)b*16384;
  f32x4 acc[2][8];
#pragma unroll
  for (int i=0;i<2;i++)
#pragma unroll
    for (int j=0;j<8;j++) acc[i][j] = zero4();
  for (int kc = 0; kc < 4; kc++){
    int k = kc*32 + quad*8;
    bf16x8 a0 = *(const bf16x8*)&As[(wr0 + l16)*136 + k];
    bf16x8 a1 = *(const bf16x8*)&As[(wr0 + 16 + l16)*136 + k];
    bf16x8 bb[8];
#pragma unroll
    for (int nt = 0; nt < 8; nt++)
      bb[nt] = *(const bf16x8*)&Bb[(size_t)(nt*16 + l16)*128 + k];
#pragma unroll
    for (int nt = 0; nt < 8; nt++){
      acc[0][nt] = mfma_bf16(a0, bb[nt], acc[0][nt]);
      acc[1][nt] = mfma_bf16(a1, bb[nt], acc[1][nt]);
    }
  }
#pragma unroll
  for (int rt = 0; rt < 2; rt++){
#pragma unroll
    for (int r = 0; r < 4; r++){
      int rowl = wr0 + rt*16 + quad*4 + r;
      float nwv = nwsS[rowl];
      float c = 0.f;
#pragma unroll
      for (int nt = 0; nt < 8; nt++){
        int col = nt*16 + l16;
        float v = acc[rt][nt][r] + nwv * w1lS[col];
        c += leaky_(v) * w2S[col];
      }
      c += __shfl_xor(c, 1, 64);
      c += __shfl_xor(c, 2, 64);
      c += __shfl_xor(c, 4, 64);
      c += __shfl_xor(c, 8, 64);
      if (l16 == 0) logitsS[rowl] = c;
    }
  }
  __syncthreads();
  if (tid < 16){
    float mx = -INFINITY;
    for (int s = 0; s < 8; s++) mx = fmaxf(mx, logitsS[tid*8+s]);
    float sm = 0.f; float ev[8];
    for (int s = 0; s < 8; s++){ ev[s] = expf(logitsS[tid*8+s]-mx); sm += ev[s]; }
    for (int s = 0; s < 8; s++) alphaS[tid*8+s] = ev[s]/sm;
  }
  __syncthreads();
  {
    int mg = tid >> 4;
    int dc = tid & 15;
    float o[8];
#pragma unroll
    for (int j = 0; j < 8; j++) o[j] = 0.f;
#pragma unroll
    for (int s = 0; s < 8; s++){
      float al = alphaS[mg*8+s];
      union { bf16x8 v; short sh[8]; } u;
      u.v = *(const bf16x8*)&As[(mg*8+s)*136 + dc*8];
#pragma unroll
      for (int j = 0; j < 8; j++) o[j] += al * b2f(u.sh[j]);
    }
    if (r0 + mg*8 < rpb){
      int m = (r0 >> 3) + mg;
      union { short s[8]; bf16x8 v; } pk;
#pragma unroll
      for (int j = 0; j < 8; j++) pk.s[j] = f2b(o[j]);
      *(bf16x8*)(outn + ((size_t)b*(rpb>>3) + m)*128 + dc*8) = pk.v;
    }
  }
}

// ---------------- MFMA global-agg output: out = relu([self||neigh]@w3) — R1 --------
__global__ __launch_bounds__(256) void k_gout(
    const short* __restrict__ embB, const short* __restrict__ selfB,
    const int* __restrict__ self_idx, const short* __restrict__ w3T,
    const short* __restrict__ neighB, float* __restrict__ outF,
    short* __restrict__ outB)
{
  const int tid = threadIdx.x;
  const int lane = tid & 63, wave = tid >> 6;
  const int quad = lane >> 4, l16 = lane & 15;
  const int rbase = blockIdx.x*64 + wave*16;
  const int row = rbase + l16;
  const short* selfp = self_idx ? embB + (size_t)self_idx[row]*128
                                : selfB + (size_t)row*128;
  const short* neighp = neighB + (size_t)row*128;
  f32x4 acc[8];
#pragma unroll
  for (int i=0;i<8;i++) acc[i] = zero4();
  for (int kc = 0; kc < 4; kc++){
    int k = kc*32 + quad*8;
    bf16x8 a = *(const bf16x8*)&selfp[k];
#pragma unroll
    for (int nt = 0; nt < 8; nt++){
      bf16x8 bb = *(const bf16x8*)&w3T[(size_t)(nt*16 + l16)*264 + k];
      acc[nt] = mfma_bf16(a, bb, acc[nt]);
    }
  }
  for (int kc = 4; kc < 8; kc++){
    int k = kc*32 + quad*8;
    bf16x8 a = *(const bf16x8*)&neighp[k - 128];
#pragma unroll
    for (int nt = 0; nt < 8; nt++){
      bf16x8 bb = *(const bf16x8*)&w3T[(size_t)(nt*16 + l16)*264 + k];
      acc[nt] = mfma_bf16(a, bb, acc[nt]);
    }
  }
  if (outF){
#pragma unroll
    for (int nt = 0; nt < 8; nt++)
#pragma unroll
      for (int r = 0; r < 4; r++){
        int orow = rbase + quad*4 + r;
        outF[(size_t)orow*128 + nt*16 + l16] = fmaxf(acc[nt][r], 0.f);
      }
  } else {
#pragma unroll
    for (int nt = 0; nt < 8; nt++)
#pragma unroll
      for (int r = 0; r < 4; r++){
        int orow = rbase + quad*4 + r;
        outB[(size_t)orow*128 + nt*16 + l16] = f2b(fmaxf(acc[nt][r], 0.f));
      }
  }
}

// ---------------- fused: perms + SSL partial + out = hl + hg + hs/g2 ----------------
__global__ __launch_bounds__(128) void k_sslhs(
    const float* __restrict__ hl, const float* __restrict__ hg,
    const int* __restrict__ mask, const float* __restrict__ glu2_w,
    float* __restrict__ out, float* __restrict__ wsLoss,
    float* __restrict__ g2)
{
  __shared__ uint32_t keys[128];
  __shared__ float red[128];
  __shared__ float hss[128];
  __shared__ int pcS[50];
  __shared__ int prbS;
  int b = blockIdx.x, tid = threadIdx.x;
  uint32_t kr0, kr1, kc0, kc1, sk0, sk1, o0, o1;
  tf2x32(0u, 42u, 0u, 0u, &kr0, &kr1);
  tf2x32(0u, 42u, 0u, 1u, &kc0, &kc1);
  tf2x32(kr0, kr1, 0u, 1u, &sk0, &sk1);
  tf2x32(sk0, sk1, 0u, (uint32_t)tid, &o0, &o1);
  keys[tid] = o0 ^ o1;
  __syncthreads();
  {
    uint32_t mk = keys[tid];
    int rank = 0;
    for (int j = 0; j < 128; j++){
      uint32_t kj = keys[j];
      rank += (kj < mk) || (kj == mk && j < tid);
    }
    if (rank == b) prbS = tid;
  }
  __syncthreads();
  tf2x32(kc0, kc1, 0u, 1u, &sk0, &sk1);
  if (tid < 50){
    tf2x32(sk0, sk1, 0u, (uint32_t)tid, &o0, &o1);
    keys[tid] = o0 ^ o1;
  }
  __syncthreads();
  if (tid < 50){
    uint32_t mk = keys[tid];
    int rank = 0;
    for (int j = 0; j < 50; j++){
      uint32_t kj = keys[j];
      rank += (kj < mk) || (kj == mk && j < tid);
    }
    pcS[rank] = tid;
  }
  __syncthreads();
  int prb = prbS, d = tid;
  float pos = 0.f, neg = 0.f, hsacc = 0.f, ms = 0.f;
  for (int l = 0; l < L_; l++){
    size_t off = ((size_t)b*L_ + l)*D_ + d;
    float hlv = hl[off], hgv = hg[off];
    float o = hlv + hgv;
    out[off] = o;
    pos += hlv * hgv;
    neg += hgv * hl[((size_t)prb*L_ + pcS[l])*D_ + d];
    float mk = (float)mask[b*L_ + l];
    ms += mk;
    hsacc += mk * o;
  }
  hss[d] = hsacc / ms;
  red[d] = -logf(1e-8f + sigm_(pos)) - logf(1e-8f + 1.f - sigm_(neg));
  __syncthreads();
  for (int off = 64; off >= 1; off >>= 1){
    if (d < off) red[d] += red[d + off];
    __syncthreads();
  }
  if (d == 0) wsLoss[b] = red[0];
  // g2 = hs @ glu2_w^T  (hss valid after the first barrier)
  float g = 0.f;
  for (int e = 0; e < 128; e++) g += hss[e]*glu2_w[d*128 + e];
  g2[(size_t)b*128 + d] = g;
}

// ---------------- fused beta + select + norms (per-b, exact f32) ----------------
// nh = tanh([pos||hidden] @ w1); ns = sigm(nh@glu1w^T + glu1b + g2);
// beta_l = (ns@w2)*mask; select = sum_l beta_l*hidden; norms.
__global__ __launch_bounds__(256) void k_bsel(
    const float* __restrict__ hidden, const int* __restrict__ mask,
    const float* __restrict__ pose, const float* __restrict__ w1s,
    const float* __restrict__ w2s, const float* __restrict__ glu1wT,
    const float* __restrict__ glu1b, const float* __restrict__ g2,
    float* __restrict__ select, float* __restrict__ norms)
{
  __shared__ float x[50][260];     // cols 0..127: pos (later nh); 128..255: hidden
  __shared__ float buf[10][132];   // half-combine scratch
  __shared__ float bufB[2][64];
  __shared__ float bet[52];
  int b = blockIdx.x, tid = threadIdx.x;
  int t = tid & 127, eh = tid >> 7;
  // stage pos | hidden (float4)
  for (int u = tid; u < 50*64; u += 256){
    int row = u >> 6, c4 = u & 63;
    float4 v;
    int col;
    if (c4 < 32){ v = *(const float4*)(pose + row*128 + c4*4); col = c4*4; }
    else        { v = *(const float4*)(hidden + ((size_t)b*L_ + row)*128 + (c4-32)*4); col = 128 + (c4-32)*4; }
    *(float4*)&x[row][col] = v;
  }
  __syncthreads();
  // phase1: nh-pre, e split across eh halves (128 e each)
  float acc[50];
#pragma unroll
  for (int l = 0; l < 50; l++) acc[l] = 0.f;
  {
    int e0 = eh*128;
    for (int e = e0; e < e0 + 128; e += 4){
      float wa = w1s[(e+0)*128 + t];
      float wb = w1s[(e+1)*128 + t];
      float wc = w1s[(e+2)*128 + t];
      float wd = w1s[(e+3)*128 + t];
#pragma unroll
      for (int l = 0; l < 50; l++){
        float4 xv = *(const float4*)&x[l][e];
        acc[l] += xv.x*wa; acc[l] += xv.y*wb; acc[l] += xv.z*wc; acc[l] += xv.w*wd;
      }
    }
  }
#pragma unroll
  for (int lc = 0; lc < 5; lc++){
    if (eh == 1){
#pragma unroll
      for (int i = 0; i < 10; i++) buf[i][t] = acc[lc*10 + i];
    }
    __syncthreads();
    if (eh == 0){
#pragma unroll
      for (int i = 0; i < 10; i++) acc[lc*10 + i] += buf[i][t];
    }
    __syncthreads();
  }
  // tanh -> nh into x[:,0..127]
  if (eh == 0){
#pragma unroll
    for (int l = 0; l < 50; l++) x[l][t] = tanhf(acc[l]);
  }
  __syncthreads();
  // phase2: a2 = nh @ glu1wT, e split (64 each)
  float acc2[50];
#pragma unroll
  for (int l = 0; l < 50; l++) acc2[l] = 0.f;
  {
    int e0 = eh*64;
    for (int e = e0; e < e0 + 64; e += 4){
      float wa = glu1wT[(e+0)*128 + t];
      float wb = glu1wT[(e+1)*128 + t];
      float wc = glu1wT[(e+2)*128 + t];
      float wd = glu1wT[(e+3)*128 + t];
#pragma unroll
      for (int l = 0; l < 50; l++){
        float4 xv = *(const float4*)&x[l][e];
        acc2[l] += xv.x*wa; acc2[l] += xv.y*wb; acc2[l] += xv.z*wc; acc2[l] += xv.w*wd;
      }
    }
  }
#pragma unroll
  for (int lc = 0; lc < 5; lc++){
    if (eh == 1){
#pragma unroll
      for (int i = 0; i < 10; i++) buf[i][t] = acc2[lc*10 + i];
    }
    __syncthreads();
    if (eh == 0){
#pragma unroll
      for (int i = 0; i < 10; i++) acc2[lc*10 + i] += buf[i][t];
    }
    __syncthreads();
  }
  // ns, beta (per-l reduce over t via wave shuffles + cross-wave LDS)
  if (eh == 0){
    float g2v = g2[(size_t)b*128 + t];
    float g1b = glu1b[t];
    float w2v = w2s[t];
    int lane = tid & 63, wv = tid >> 6;
#pragma unroll
    for (int l = 0; l < 50; l++){
      float ns = sigm_(acc2[l] + g1b + g2v);
      float v = ns * w2v;
      v += __shfl_xor(v, 1, 64);
      v += __shfl_xor(v, 2, 64);
      v += __shfl_xor(v, 4, 64);
      v += __shfl_xor(v, 8, 64);
      v += __shfl_xor(v, 16, 64);
      v += __shfl_xor(v, 32, 64);
      if (lane == 0) bufB[wv][l] = v;
    }
  }
  __syncthreads();
  if (tid < 50) bet[tid] = (bufB[0][tid] + bufB[1][tid]) * (float)mask[b*L_ + tid];
  __syncthreads();
  if (eh == 0){
    float sel = 0.f;
#pragma unroll
    for (int l = 0; l < 50; l++) sel += bet[l] * x[l][128 + t];
    select[(size_t)b*128 + t] = sel;
    float v = sel*sel + 1e-6f;
    int lane = tid & 63, wv = tid >> 6;
    v += __shfl_xor(v, 1, 64);
    v += __shfl_xor(v, 2, 64);
    v += __shfl_xor(v, 4, 64);
    v += __shfl_xor(v, 8, 64);
    v += __shfl_xor(v, 16, 64);
    v += __shfl_xor(v, 32, 64);
    if (lane == 0) bufB[wv][63] = v;
  }
  __syncthreads();
  if (tid == 0) norms[b] = sqrtf(bufB[0][63] + bufB[1][63]);
}

// ---------------- cosine softmax + top-9 + neighbor mix (+ loss finalize) ----------
__global__ __launch_bounds__(128) void k_topk(const float* __restrict__ select,
                                              const float* __restrict__ norms,
                                              const float* __restrict__ wsLoss,
                                              short* __restrict__ select2b,
                                              float* __restrict__ out_loss){
  __shared__ float p[B_];
  __shared__ float red[128];
  __shared__ float tv[NBR_];
  __shared__ int   ti[NBR_];
  int b = blockIdx.x, t = threadIdx.x;
  float dot = 0.f;
  for (int d = 0; d < D_; d++) dot += select[(size_t)b*D_ + d]*select[(size_t)t*D_ + d];
  float logit = dot / (norms[b]*norms[t]);
  red[t] = logit; __syncthreads();
  for (int off = 64; off >= 1; off >>= 1){
    if (t < off) red[t] = fmaxf(red[t], red[t + off]);
    __syncthreads();
  }
  float mx = red[0]; __syncthreads();
  float e_ = expf(logit - mx);
  red[t] = e_; __syncthreads();
  for (int off = 64; off >= 1; off >>= 1){
    if (t < off) red[t] += red[t + off];
    __syncthreads();
  }
  p[t] = e_ / red[0];
  __syncthreads();
  if (t == 0){
    unsigned long long used0 = 0ull, used1 = 0ull;
    for (int k = 0; k < NBR_; k++){
      float best = -INFINITY; int bi = 0;
      for (int j = 0; j < B_; j++){
        bool u = (j < 64) ? ((used0 >> j) & 1ull) : ((used1 >> (j-64)) & 1ull);
        if (!u && p[j] > best){ best = p[j]; bi = j; }
      }
      if (bi < 64) used0 |= 1ull << bi; else used1 |= 1ull << (bi-64);
      tv[k] = best; ti[k] = bi;
    }
    float mx2 = -INFINITY;
    for (int k = 0; k < NBR_; k++) mx2 = fmaxf(mx2, tv[k]);
    float s2 = 0.f;
    for (int k = 0; k < NBR_; k++){ tv[k] = expf(tv[k]-mx2); s2 += tv[k]; }
    for (int k = 0; k < NBR_; k++) tv[k] /= s2;
  }
  __syncthreads();
  float nb = 0.f;
#pragma unroll
  for (int k = 0; k < NBR_; k++) nb += tv[k]*select[(size_t)ti[k]*D_ + t];
  select2b[(size_t)b*D_ + t] = f2b(select[(size_t)b*D_ + t] + nb);
  // loss finalize on block 0
  if (b == 0){
    __syncthreads();
    red[t] = wsLoss[t];
    __syncthreads();
    for (int off = 64; off >= 1; off >>= 1){
      if (t < off) red[t] += red[t + off];
      __syncthreads();
    }
    if (t == 0) out_loss[0] = BETA_ * red[0];
  }
}

// ---------------- MFMA scores = sel2 @ emb[1:].T (LDS-staged B) ----------------
__global__ __launch_bounds__(256) void k_scores(
    const short* __restrict__ sel2b, const float* __restrict__ emb,
    float* __restrict__ scores)
{
  __shared__ __align__(16) short Es[64*136];
  const int tid = threadIdx.x;
  const int n0 = blockIdx.x*64;
  for (int it = 0; it < 8; it++){
    int u = it*256 + tid;
    int lr = u >> 5, c = u & 31;
    int n = min(n0 + lr, NSC_ - 1);
    float4 v = *(const float4*)(emb + (size_t)(1 + n)*128 + c*4);
    short4 s4; s4.x=f2b(v.x); s4.y=f2b(v.y); s4.z=f2b(v.z); s4.w=f2b(v.w);
    *(short4*)&Es[lr*136 + c*4] = s4;
  }
  __syncthreads();
  const int lane = tid & 63, wave = tid >> 6;
  const int quad = lane >> 4, l16 = lane & 15;
  int n = n0 + wave*16 + l16;
  f32x4 acc[8];
#pragma unroll
  for (int i=0;i<8;i++) acc[i] = zero4();
  for (int kc = 0; kc < 4; kc++){
    int k = kc*32 + quad*8;
    bf16x8 bb = *(const bf16x8*)&Es[(wave*16 + l16)*136 + k];
#pragma unroll
    for (int rt = 0; rt < 8; rt++){
      bf16x8 a = *(const bf16x8*)&sel2b[(rt*16 + l16)*128 + k];
      acc[rt] = mfma_bf16(a, bb, acc[rt]);
    }
  }
  if (n < NSC_){
#pragma unroll
    for (int rt = 0; rt < 8; rt++)
#pragma unroll
      for (int r = 0; r < 4; r++){
        int brow = rt*16 + quad*4 + r;
        scores[(size_t)brow*NSC_ + n] = acc[rt][r];
      }
  }
}

// ---------------- launcher ----------------
extern "C" void kernel_launch(void* const* d_in, const int* in_sizes, int n_in,
                              void* d_out, int out_size, void* d_ws, size_t ws_size,
                              hipStream_t stream) {
  (void)in_sizes; (void)n_in; (void)out_size; (void)ws_size;
  const int*   inputs  = (const int*)  d_in[0];
  const int*   adj     = (const int*)  d_in[1];
  const int*   mask    = (const int*)  d_in[2];
  const int*   item    = (const int*)  d_in[3];
  const int*   adj_all = (const int*)  d_in[5];
  const float* num_w   = (const float*)d_in[6];
  const float* emb     = (const float*)d_in[7];
  const float* pose    = (const float*)d_in[8];
  const float* a_local = (const float*)d_in[9];
  const float* gw1     = (const float*)d_in[10];
  const float* gw2     = (const float*)d_in[11];
  const float* gw3     = (const float*)d_in[12];
  const float* w1      = (const float*)d_in[13];
  const float* w2      = (const float*)d_in[14];
  const float* glu1w   = (const float*)d_in[15];
  const float* glu1b   = (const float*)d_in[16];
  const float* glu2w   = (const float*)d_in[17];
  float* out = (float*)d_out;

  // workspace layout (float units)
  float* W     = (float*)d_ws;
  float* hl    = W;                    // 819200
  float* hg    = W + 819200;           // 819200
  short* e0pB  = (short*)(W + 1638400);// bf16 gout output hop0-i0, 819200 shorts
  short* e1pB  = (short*)(W + 2457600);// bf16 gout output hop0-i1, 6553600 shorts
  float* sess  = W + 9011200;          // 16384
  float* g2    = W + 9027584;          // 16384
  float* sel   = W + 9043968;          // 16384
  short* sel2b = (short*)(W + 9060352);// 16384 shorts
  float* norms = W + 9076736;          // 128
  float* wsLoss= W + 9076864;          // 128
  float* n1w   = W + 9076992;          // 51200
  float* n2w   = W + 9128192;          // 409600
  float* betaW = W + 9537792;          // 6400 (unused now)
  float* w1T   = W + 9544192;          // 32768 (2 hops)
  float* glu1wT= W + 9576960;          // 16384
  short* w3Tb  = (short*)(W + 9593344);// 2*128*264 shorts
  int*   n1i   = (int*)(W + 9627136);  // 51200
  int*   n2i   = n1i + 51200;          // 409600
  (void)betaW;

  // d_out scratch (scores region, fully overwritten by k_scores at the end):
  short* embB   = (short*)(out + 819712);
  short* BsessG = (short*)(out + 819712 + 3200000);
  short* hgB    = (short*)(out + 819712 + 3200000 + 2097152);

  k_prep_all<<<3701, 256, 0, stream>>>(emb, item, mask, gw1, gw3, glu1w,
                                       embB, w1T, glu1wT, w3Tb, sess);
  k_stage2<<<456, 256, 0, stream>>>(w1T, sess, inputs, adj_all, num_w,
                                    BsessG, n1i, n1w, n2i, n2w);
  k_local<<<dim3(2, B_), 256, 0, stream>>>(inputs, embB, adj, a_local, hl);

  // hop0 i=0: A=embB[n1i], self=embB[inputs] -> e0pB (rpb=400)
  k_att <<<dim3(4, B_),  256, 0, stream>>>(embB, nullptr, n1i, n1w, BsessG,
                                           gw1, gw2, e0pB, 400);
  k_gout<<<100, 256, 0, stream>>>(embB, nullptr, inputs, w3Tb, e0pB, nullptr, e0pB);
  // hop0 i=1: A=embB[n2i], self=embB[n1i] -> e1pB (rpb=3200)
  k_att <<<dim3(25, B_), 256, 0, stream>>>(embB, nullptr, n2i, n2w, BsessG,
                                           gw1, gw2, e1pB, 3200);
  k_gout<<<800, 256, 0, stream>>>(embB, nullptr, n1i, w3Tb, e1pB, nullptr, e1pB);
  // hop1: A=e1pB dense, self=e0pB dense -> hgB (bf16) -> gout -> hg (f32)
  k_att <<<dim3(4, B_),  256, 0, stream>>>(embB, e1pB, nullptr, n1w,
                                           BsessG + (size_t)128*16384,
                                           gw1 + 129*128, gw2 + 128, hgB, 400);
  k_gout<<<100, 256, 0, stream>>>(embB, e0pB, nullptr, w3Tb + 128*264, hgB, hg, nullptr);

  k_sslhs<<<B_, 128, 0, stream>>>(hl, hg, mask, glu2w, out, wsLoss, g2);
  k_bsel<<<B_, 256, 0, stream>>>(out, mask, pose, w1, w2, glu1wT, glu1b, g2, sel, norms);
  k_topk<<<B_, 128, 0, stream>>>(sel, norms, wsLoss, sel2b, out + B_*L_*D_);
  k_scores<<<(NSC_ + 63)/64, 256, 0, stream>>>(sel2b, emb, out + B_*L_*D_ + 1);
}

// Round 4
// 498.351 us; speedup vs baseline: 1.1104x; 1.1104x over previous
//
#include <hip/hip_runtime.h>
#include <stdint.h>

// ---------------- constants ----------------
namespace {
constexpr int B_ = 128;
constexpr int L_ = 50;
constexpr int D_ = 128;
constexpr int S_ = 8;
constexpr int NSC_ = 99999;       // NUM_NODE-1
constexpr int NBR_ = 9;
}
#define LEAKY_ 0.2f
#define BETA_ 0.005f

typedef __attribute__((ext_vector_type(8))) __bf16 bf16x8;
typedef __attribute__((ext_vector_type(4))) float f32x4;

__device__ __forceinline__ float leaky_(float x){ return x >= 0.f ? x : LEAKY_*x; }
__device__ __forceinline__ float sigm_(float x){ return 1.f/(1.f+expf(-x)); }

__device__ __forceinline__ short f2b(float f){
  uint32_t u = __float_as_uint(f);
  u += 0x7fffu + ((u >> 16) & 1u);
  return (short)(u >> 16);
}
__device__ __forceinline__ float b2f(short s){
  return __uint_as_float(((uint32_t)(uint16_t)s) << 16);
}
__device__ __forceinline__ f32x4 zero4(){ f32x4 z = {0.f,0.f,0.f,0.f}; return z; }
__device__ __forceinline__ f32x4 mfma_bf16(bf16x8 a, bf16x8 b, f32x4 c){
  return __builtin_amdgcn_mfma_f32_16x16x32_bf16(a, b, c, 0, 0, 0);
}

// ---------------- threefry2x32 (JAX-compatible) ----------------
__device__ __forceinline__ void tf2x32(uint32_t k0, uint32_t k1, uint32_t c0, uint32_t c1,
                                       uint32_t* o0, uint32_t* o1){
  uint32_t ks2 = k0 ^ k1 ^ 0x1BD11BDAu;
  uint32_t x0 = c0 + k0, x1 = c1 + k1;
#define RND_(r) { x0 += x1; x1 = (x1<<(r))|(x1>>(32-(r))); x1 ^= x0; }
  RND_(13) RND_(15) RND_(26) RND_(6)   x0 += k1;  x1 += ks2 + 1u;
  RND_(17) RND_(29) RND_(16) RND_(24)  x0 += ks2; x1 += k0  + 2u;
  RND_(13) RND_(15) RND_(26) RND_(6)   x0 += k0;  x1 += k1  + 3u;
  RND_(17) RND_(29) RND_(16) RND_(24)  x0 += k1;  x1 += ks2 + 4u;
  RND_(13) RND_(15) RND_(26) RND_(6)   x0 += ks2; x1 += k0  + 5u;
#undef RND_
  *o0 = x0; *o1 = x1;
}

// ---------------- fused prep: embB + weight transposes + sess ----------------
__global__ __launch_bounds__(256) void k_prep_all(
    const float* __restrict__ emb, const int* __restrict__ item,
    const int* __restrict__ mask, const float* __restrict__ gw1,
    const float* __restrict__ gw3, const float* __restrict__ glu1w,
    short* __restrict__ embB, float* __restrict__ w1T,
    float* __restrict__ glu1wT, short* __restrict__ w3T,
    float* __restrict__ sess)
{
  int blk = blockIdx.x, tid = threadIdx.x;
  if (blk < 3125){
    size_t base = (size_t)blk*4096 + (size_t)tid*16;
    float4 f0 = *(const float4*)(emb + base);
    float4 f1 = *(const float4*)(emb + base + 4);
    float4 f2 = *(const float4*)(emb + base + 8);
    float4 f3 = *(const float4*)(emb + base + 12);
    short4 s0, s1, s2, s3;
    s0.x=f2b(f0.x); s0.y=f2b(f0.y); s0.z=f2b(f0.z); s0.w=f2b(f0.w);
    s1.x=f2b(f1.x); s1.y=f2b(f1.y); s1.z=f2b(f1.z); s1.w=f2b(f1.w);
    s2.x=f2b(f2.x); s2.y=f2b(f2.y); s2.z=f2b(f2.z); s2.w=f2b(f2.w);
    s3.x=f2b(f3.x); s3.y=f2b(f3.y); s3.z=f2b(f3.z); s3.w=f2b(f3.w);
    *(short4*)(embB + base)      = s0;
    *(short4*)(embB + base + 4)  = s1;
    *(short4*)(embB + base + 8)  = s2;
    *(short4*)(embB + base + 12) = s3;
  } else if (blk < 3573){
    int o = (blk - 3125)*256 + tid;
    if (o < 32768){
      int hop = o >> 14, r = o & 16383;
      int d = r >> 7, e = r & 127;
      w1T[o] = gw1[hop*(129*128) + e*128 + d];
    } else if (o < 49152){
      int o2 = o - 32768;
      int e = o2 >> 7, t = o2 & 127;
      glu1wT[o2] = glu1w[t*128 + e];
    } else if (o < 114688){
      int o3 = o - 49152;
      int hop = o3 >> 15, r = o3 & 32767;
      int nn = r >> 8, k = r & 255;
      w3T[hop*(128*264) + nn*264 + k] = f2b(gw3[hop*(256*128) + k*128 + nn]);
    }
  } else {
    int b = blk - 3573;
    if (tid < 128){
      float acc = 0.f, ms = 0.f;
      for (int l = 0; l < L_; l++){
        float mk = (float)mask[b*L_ + l];
        ms += mk;
        acc += mk * emb[(size_t)item[b*L_ + l]*D_ + tid];
      }
      sess[(size_t)b*D_ + tid] = acc / ms;
    }
  }
}

// ---------------- fused stage2: Bsess + 2-hop sampling ----------------
__global__ __launch_bounds__(256) void k_stage2(
    const float* __restrict__ w1T, const float* __restrict__ sess,
    const int* __restrict__ inputs, const int* __restrict__ adj_all,
    const float* __restrict__ num_w,
    short* __restrict__ Bsess, int* __restrict__ n1i, float* __restrict__ n1w,
    int* __restrict__ n2i, float* __restrict__ n2w)
{
  int blk = blockIdx.x, tid = threadIdx.x;
  if (blk < 256){
    int hop = blk >> 7, b = blk & 127;
    const float* wt = w1T + hop*16384;
    short* outp = Bsess + ((size_t)hop*128 + b)*16384;
    __shared__ float sessS[128];
    if (tid < 128) sessS[tid] = sess[b*128 + tid];
    __syncthreads();
    for (int it = 0; it < 64; it++){
      int u = it*256 + tid;
      outp[u] = f2b(wt[u] * sessS[u & 127]);
    }
  } else {
    int p = (blk - 256)*256 + tid;   // p < 51200
    int base = inputs[p >> 3];
    int off  = base*S_ + (p & 7);
    int i1 = adj_all[off];
    n1i[p] = i1;
    n1w[p] = num_w[off];
#pragma unroll
    for (int j = 0; j < 8; j++){
      n2i[(size_t)p*8 + j] = adj_all[i1*8 + j];
      n2w[(size_t)p*8 + j] = num_w[i1*8 + j];
    }
  }
}

// ---------------- local GAT aggregation ----------------
__global__ __launch_bounds__(256) void k_local(const int* __restrict__ inputs,
                                               const short* __restrict__ embB,
                                               const int* __restrict__ adj,
                                               const float* __restrict__ a_local,
                                               float* __restrict__ hl){
  __shared__ float hs[L_*129];
  __shared__ float att[25*52];
  __shared__ float al[4*132];
  __shared__ int idxs[L_];
  int b = blockIdx.y, half = blockIdx.x, tid = threadIdx.x;
  int i0 = half*25;
  if (tid < L_) idxs[tid] = inputs[b*L_ + tid];
  __syncthreads();
  for (int u = tid; u < L_*16; u += 256){
    int i = u >> 4, c = u & 15;
    union { bf16x8 v; short sh[8]; } w;
    w.v = *(const bf16x8*)&embB[(size_t)idxs[i]*128 + c*8];
#pragma unroll
    for (int j = 0; j < 8; j++) hs[i*129 + c*8 + j] = b2f(w.sh[j]);
  }
  for (int e = tid; e < 4*D_; e += 256) al[(e>>7)*132 + (e&127)] = a_local[e];
  __syncthreads();
  for (int p = tid; p < 25*L_; p += 256){
    int il = p / L_, j = p % L_;
    int i = i0 + il;
    int k = adj[((size_t)b*L_ + i)*L_ + j];
    float v = -9e15f;
    if (k >= 1){
      const float* ak = &al[(k-1)*132];
      float acc = 0.f;
      for (int d = 0; d < D_; d++) acc += hs[i*129+d]*hs[j*129+d]*ak[d];
      v = leaky_(acc);
    }
    att[il*52 + j] = v;
  }
  __syncthreads();
  if (tid < 25){
    int il = tid;
    float mx = -INFINITY;
    for (int j = 0; j < L_; j++) mx = fmaxf(mx, att[il*52+j]);
    float sm = 0.f;
    for (int j = 0; j < L_; j++){ float e_ = expf(att[il*52+j] - mx); att[il*52+j] = e_; sm += e_; }
    float inv = 1.f/sm;
    for (int j = 0; j < L_; j++) att[il*52+j] *= inv;
  }
  __syncthreads();
  for (int q = tid; q < 25*D_; q += 256){
    int il = q >> 7, d = q & 127;
    float acc = 0.f;
    for (int j = 0; j < L_; j++) acc += att[il*52+j]*hs[j*129+d];
    hl[((size_t)b*L_ + i0 + il)*D_ + d] = acc;
  }
}

// ---------------- MFMA global-agg attention (bf16 in, bf16 out) — R1 structure --------
__global__ __launch_bounds__(256, 4) void k_att(
    const short* __restrict__ embB, const short* __restrict__ denseB,
    const int* __restrict__ nidx, const float* __restrict__ nw,
    const short* __restrict__ Bsess,
    const float* __restrict__ w1g, const float* __restrict__ w2g,
    short* __restrict__ outn, int rpb)
{
  __shared__ __align__(16) short As[128*136];
  __shared__ float w1lS[128], w2S[128], nwsS[128], logitsS[128], alphaS[128];
  const int tid = threadIdx.x;
  const int b = blockIdx.y;
  const int r0 = blockIdx.x * 128;
  if (tid < 128){
    w1lS[tid]  = w1g[128*128 + tid];
    w2S[tid]   = w2g[tid];
    int rr = min(r0 + tid, rpb - 1);
    nwsS[tid]  = nw[(size_t)b*rpb + rr];
  }
  for (int it = 0; it < 8; it++){
    int u = it*256 + tid;
    int lr = u >> 4, c = u & 15;
    int rr = min(r0 + lr, rpb - 1);
    const short* src = denseB ? denseB + ((size_t)b*rpb + rr)*128
                              : embB + (size_t)nidx[(size_t)b*rpb + rr]*128;
    *(bf16x8*)&As[lr*136 + c*8] = *(const bf16x8*)&src[c*8];
  }
  __syncthreads();
  const int lane = tid & 63, wave = tid >> 6;
  const int quad = lane >> 4, l16 = lane & 15;
  const int wr0 = wave * 32;
  const short* Bb = Bsess + (size_t)b*16384;
  f32x4 acc[2][8];
#pragma unroll
  for (int i=0;i<2;i++)
#pragma unroll
    for (int j=0;j<8;j++) acc[i][j] = zero4();
  for (int kc = 0; kc < 4; kc++){
    int k = kc*32 + quad*8;
    bf16x8 a0 = *(const bf16x8*)&As[(wr0 + l16)*136 + k];
    bf16x8 a1 = *(const bf16x8*)&As[(wr0 + 16 + l16)*136 + k];
    bf16x8 bb[8];
#pragma unroll
    for (int nt = 0; nt < 8; nt++)
      bb[nt] = *(const bf16x8*)&Bb[(size_t)(nt*16 + l16)*128 + k];
#pragma unroll
    for (int nt = 0; nt < 8; nt++){
      acc[0][nt] = mfma_bf16(a0, bb[nt], acc[0][nt]);
      acc[1][nt] = mfma_bf16(a1, bb[nt], acc[1][nt]);
    }
  }
#pragma unroll
  for (int rt = 0; rt < 2; rt++){
#pragma unroll
    for (int r = 0; r < 4; r++){
      int rowl = wr0 + rt*16 + quad*4 + r;
      float nwv = nwsS[rowl];
      float c = 0.f;
#pragma unroll
      for (int nt = 0; nt < 8; nt++){
        int col = nt*16 + l16;
        float v = acc[rt][nt][r] + nwv * w1lS[col];
        c += leaky_(v) * w2S[col];
      }
      c += __shfl_xor(c, 1, 64);
      c += __shfl_xor(c, 2, 64);
      c += __shfl_xor(c, 4, 64);
      c += __shfl_xor(c, 8, 64);
      if (l16 == 0) logitsS[rowl] = c;
    }
  }
  __syncthreads();
  if (tid < 16){
    float mx = -INFINITY;
    for (int s = 0; s < 8; s++) mx = fmaxf(mx, logitsS[tid*8+s]);
    float sm = 0.f; float ev[8];
    for (int s = 0; s < 8; s++){ ev[s] = expf(logitsS[tid*8+s]-mx); sm += ev[s]; }
    for (int s = 0; s < 8; s++) alphaS[tid*8+s] = ev[s]/sm;
  }
  __syncthreads();
  {
    int mg = tid >> 4;
    int dc = tid & 15;
    float o[8];
#pragma unroll
    for (int j = 0; j < 8; j++) o[j] = 0.f;
#pragma unroll
    for (int s = 0; s < 8; s++){
      float al = alphaS[mg*8+s];
      union { bf16x8 v; short sh[8]; } u;
      u.v = *(const bf16x8*)&As[(mg*8+s)*136 + dc*8];
#pragma unroll
      for (int j = 0; j < 8; j++) o[j] += al * b2f(u.sh[j]);
    }
    if (r0 + mg*8 < rpb){
      int m = (r0 >> 3) + mg;
      union { short s[8]; bf16x8 v; } pk;
#pragma unroll
      for (int j = 0; j < 8; j++) pk.s[j] = f2b(o[j]);
      *(bf16x8*)(outn + ((size_t)b*(rpb>>3) + m)*128 + dc*8) = pk.v;
    }
  }
}

// ---------------- MFMA global-agg output: out = relu([self||neigh]@w3) — R1 --------
__global__ __launch_bounds__(256) void k_gout(
    const short* __restrict__ embB, const short* __restrict__ selfB,
    const int* __restrict__ self_idx, const short* __restrict__ w3T,
    const short* __restrict__ neighB, float* __restrict__ outF,
    short* __restrict__ outB)
{
  const int tid = threadIdx.x;
  const int lane = tid & 63, wave = tid >> 6;
  const int quad = lane >> 4, l16 = lane & 15;
  const int rbase = blockIdx.x*64 + wave*16;
  const int row = rbase + l16;
  const short* selfp = self_idx ? embB + (size_t)self_idx[row]*128
                                : selfB + (size_t)row*128;
  const short* neighp = neighB + (size_t)row*128;
  f32x4 acc[8];
#pragma unroll
  for (int i=0;i<8;i++) acc[i] = zero4();
  for (int kc = 0; kc < 4; kc++){
    int k = kc*32 + quad*8;
    bf16x8 a = *(const bf16x8*)&selfp[k];
#pragma unroll
    for (int nt = 0; nt < 8; nt++){
      bf16x8 bb = *(const bf16x8*)&w3T[(size_t)(nt*16 + l16)*264 + k];
      acc[nt] = mfma_bf16(a, bb, acc[nt]);
    }
  }
  for (int kc = 4; kc < 8; kc++){
    int k = kc*32 + quad*8;
    bf16x8 a = *(const bf16x8*)&neighp[k - 128];
#pragma unroll
    for (int nt = 0; nt < 8; nt++){
      bf16x8 bb = *(const bf16x8*)&w3T[(size_t)(nt*16 + l16)*264 + k];
      acc[nt] = mfma_bf16(a, bb, acc[nt]);
    }
  }
  if (outF){
#pragma unroll
    for (int nt = 0; nt < 8; nt++)
#pragma unroll
      for (int r = 0; r < 4; r++){
        int orow = rbase + quad*4 + r;
        outF[(size_t)orow*128 + nt*16 + l16] = fmaxf(acc[nt][r], 0.f);
      }
  } else {
#pragma unroll
    for (int nt = 0; nt < 8; nt++)
#pragma unroll
      for (int r = 0; r < 4; r++){
        int orow = rbase + quad*4 + r;
        outB[(size_t)orow*128 + nt*16 + l16] = f2b(fmaxf(acc[nt][r], 0.f));
      }
  }
}

// ---------------- fused: perms + SSL partial + out = hl + hg + hs/g2 ----------------
__global__ __launch_bounds__(128) void k_sslhs(
    const float* __restrict__ hl, const float* __restrict__ hg,
    const int* __restrict__ mask, const float* __restrict__ glu2_w,
    float* __restrict__ out, float* __restrict__ wsLoss,
    float* __restrict__ g2)
{
  __shared__ uint32_t keys[128];
  __shared__ float red[128];
  __shared__ float hss[128];
  __shared__ int pcS[50];
  __shared__ int prbS;
  int b = blockIdx.x, tid = threadIdx.x;
  uint32_t kr0, kr1, kc0, kc1, sk0, sk1, o0, o1;
  tf2x32(0u, 42u, 0u, 0u, &kr0, &kr1);
  tf2x32(0u, 42u, 0u, 1u, &kc0, &kc1);
  tf2x32(kr0, kr1, 0u, 1u, &sk0, &sk1);
  tf2x32(sk0, sk1, 0u, (uint32_t)tid, &o0, &o1);
  keys[tid] = o0 ^ o1;
  __syncthreads();
  {
    uint32_t mk = keys[tid];
    int rank = 0;
    for (int j = 0; j < 128; j++){
      uint32_t kj = keys[j];
      rank += (kj < mk) || (kj == mk && j < tid);
    }
    if (rank == b) prbS = tid;
  }
  __syncthreads();
  tf2x32(kc0, kc1, 0u, 1u, &sk0, &sk1);
  if (tid < 50){
    tf2x32(sk0, sk1, 0u, (uint32_t)tid, &o0, &o1);
    keys[tid] = o0 ^ o1;
  }
  __syncthreads();
  if (tid < 50){
    uint32_t mk = keys[tid];
    int rank = 0;
    for (int j = 0; j < 50; j++){
      uint32_t kj = keys[j];
      rank += (kj < mk) || (kj == mk && j < tid);
    }
    pcS[rank] = tid;
  }
  __syncthreads();
  int prb = prbS, d = tid;
  float pos = 0.f, neg = 0.f, hsacc = 0.f, ms = 0.f;
  for (int l = 0; l < L_; l++){
    size_t off = ((size_t)b*L_ + l)*D_ + d;
    float hlv = hl[off], hgv = hg[off];
    float o = hlv + hgv;
    out[off] = o;
    pos += hlv * hgv;
    neg += hgv * hl[((size_t)prb*L_ + pcS[l])*D_ + d];
    float mk = (float)mask[b*L_ + l];
    ms += mk;
    hsacc += mk * o;
  }
  hss[d] = hsacc / ms;
  red[d] = -logf(1e-8f + sigm_(pos)) - logf(1e-8f + 1.f - sigm_(neg));
  __syncthreads();
  for (int off = 64; off >= 1; off >>= 1){
    if (d < off) red[d] += red[d + off];
    __syncthreads();
  }
  if (d == 0) wsLoss[b] = red[0];
  // g2 = hs @ glu2_w^T  (hss valid after the barriers above)
  float g = 0.f;
  for (int e = 0; e < 128; e++) g += hss[e]*glu2_w[d*128 + e];
  g2[(size_t)b*128 + d] = g;
}

// ---------------- beta[b,l] (R1 structure) ----------------
__global__ __launch_bounds__(128) void k_beta(
    const float* __restrict__ hidden, const int* __restrict__ mask,
    const float* __restrict__ pose, const float* __restrict__ w1s,
    const float* __restrict__ w2s, const float* __restrict__ glu1wT,
    const float* __restrict__ glu1b, const float* __restrict__ g2,
    float* __restrict__ betaW)
{
  __shared__ float hrow[128], prow[128], nh[128], red[128];
  int l = blockIdx.x, b = blockIdx.y, t = threadIdx.x;
  hrow[t] = hidden[((size_t)b*L_ + l)*128 + t];
  prow[t] = pose[l*128 + t];
  __syncthreads();
  float acc = 0.f;
  for (int e = 0; e < 128; e++) acc += prow[e]*w1s[e*128 + t];
  for (int e = 0; e < 128; e++) acc += hrow[e]*w1s[(128+e)*128 + t];
  nh[t] = tanhf(acc);
  __syncthreads();
  float a2 = 0.f;
  for (int e = 0; e < 128; e++) a2 += nh[e]*glu1wT[e*128 + t];
  float ns = sigm_(a2 + glu1b[t] + g2[(size_t)b*128 + t]);
  red[t] = ns * w2s[t];
  __syncthreads();
  for (int off = 64; off >= 1; off >>= 1){
    if (t < off) red[t] += red[t+off];
    __syncthreads();
  }
  if (t == 0) betaW[b*L_ + l] = red[0] * (float)mask[b*L_ + l];
}

// ---------------- select = sum_l beta*hidden; norms (R1 structure) ----------------
__global__ __launch_bounds__(128) void k_selnorm(
    const float* __restrict__ hidden, const float* __restrict__ betaW,
    float* __restrict__ select, float* __restrict__ norms)
{
  __shared__ float bet[56];
  __shared__ float red[128];
  int b = blockIdx.x, t = threadIdx.x;
  if (t < L_) bet[t] = betaW[b*L_ + t];
  __syncthreads();
  float sel = 0.f;
  for (int l = 0; l < L_; l++) sel += bet[l]*hidden[((size_t)b*L_ + l)*128 + t];
  select[(size_t)b*128 + t] = sel;
  red[t] = sel*sel + 1e-6f;
  __syncthreads();
  for (int off=64; off>=1; off>>=1){ if (t<off) red[t]+=red[t+off]; __syncthreads(); }
  if (t==0) norms[b] = sqrtf(red[0]);
}

// ---------------- cosine softmax + top-9 + neighbor mix (+ loss finalize) ----------
__global__ __launch_bounds__(128) void k_topk(const float* __restrict__ select,
                                              const float* __restrict__ norms,
                                              const float* __restrict__ wsLoss,
                                              short* __restrict__ select2b,
                                              float* __restrict__ out_loss){
  __shared__ float p[B_];
  __shared__ float red[128];
  __shared__ float tv[NBR_];
  __shared__ int   ti[NBR_];
  int b = blockIdx.x, t = threadIdx.x;
  float dot = 0.f;
  for (int d = 0; d < D_; d++) dot += select[(size_t)b*D_ + d]*select[(size_t)t*D_ + d];
  float logit = dot / (norms[b]*norms[t]);
  red[t] = logit; __syncthreads();
  for (int off = 64; off >= 1; off >>= 1){
    if (t < off) red[t] = fmaxf(red[t], red[t + off]);
    __syncthreads();
  }
  float mx = red[0]; __syncthreads();
  float e_ = expf(logit - mx);
  red[t] = e_; __syncthreads();
  for (int off = 64; off >= 1; off >>= 1){
    if (t < off) red[t] += red[t + off];
    __syncthreads();
  }
  p[t] = e_ / red[0];
  __syncthreads();
  if (t == 0){
    unsigned long long used0 = 0ull, used1 = 0ull;
    for (int k = 0; k < NBR_; k++){
      float best = -INFINITY; int bi = 0;
      for (int j = 0; j < B_; j++){
        bool u = (j < 64) ? ((used0 >> j) & 1ull) : ((used1 >> (j-64)) & 1ull);
        if (!u && p[j] > best){ best = p[j]; bi = j; }
      }
      if (bi < 64) used0 |= 1ull << bi; else used1 |= 1ull << (bi-64);
      tv[k] = best; ti[k] = bi;
    }
    float mx2 = -INFINITY;
    for (int k = 0; k < NBR_; k++) mx2 = fmaxf(mx2, tv[k]);
    float s2 = 0.f;
    for (int k = 0; k < NBR_; k++){ tv[k] = expf(tv[k]-mx2); s2 += tv[k]; }
    for (int k = 0; k < NBR_; k++) tv[k] /= s2;
  }
  __syncthreads();
  float nb = 0.f;
#pragma unroll
  for (int k = 0; k < NBR_; k++) nb += tv[k]*select[(size_t)ti[k]*D_ + t];
  select2b[(size_t)b*D_ + t] = f2b(select[(size_t)b*D_ + t] + nb);
  // loss finalize on block 0
  if (b == 0){
    __syncthreads();
    red[t] = wsLoss[t];
    __syncthreads();
    for (int off = 64; off >= 1; off >>= 1){
      if (t < off) red[t] += red[t + off];
      __syncthreads();
    }
    if (t == 0) out_loss[0] = BETA_ * red[0];
  }
}

// ---------------- MFMA scores = sel2 @ emb[1:].T (LDS-staged B) ----------------
__global__ __launch_bounds__(256) void k_scores(
    const short* __restrict__ sel2b, const float* __restrict__ emb,
    float* __restrict__ scores)
{
  __shared__ __align__(16) short Es[64*136];
  const int tid = threadIdx.x;
  const int n0 = blockIdx.x*64;
  for (int it = 0; it < 8; it++){
    int u = it*256 + tid;
    int lr = u >> 5, c = u & 31;
    int n = min(n0 + lr, NSC_ - 1);
    float4 v = *(const float4*)(emb + (size_t)(1 + n)*128 + c*4);
    short4 s4; s4.x=f2b(v.x); s4.y=f2b(v.y); s4.z=f2b(v.z); s4.w=f2b(v.w);
    *(short4*)&Es[lr*136 + c*4] = s4;
  }
  __syncthreads();
  const int lane = tid & 63, wave = tid >> 6;
  const int quad = lane >> 4, l16 = lane & 15;
  int n = n0 + wave*16 + l16;
  f32x4 acc[8];
#pragma unroll
  for (int i=0;i<8;i++) acc[i] = zero4();
  for (int kc = 0; kc < 4; kc++){
    int k = kc*32 + quad*8;
    bf16x8 bb = *(const bf16x8*)&Es[(wave*16 + l16)*136 + k];
#pragma unroll
    for (int rt = 0; rt < 8; rt++){
      bf16x8 a = *(const bf16x8*)&sel2b[(rt*16 + l16)*128 + k];
      acc[rt] = mfma_bf16(a, bb, acc[rt]);
    }
  }
  if (n < NSC_){
#pragma unroll
    for (int rt = 0; rt < 8; rt++)
#pragma unroll
      for (int r = 0; r < 4; r++){
        int brow = rt*16 + quad*4 + r;
        scores[(size_t)brow*NSC_ + n] = acc[rt][r];
      }
  }
}

// ---------------- launcher ----------------
extern "C" void kernel_launch(void* const* d_in, const int* in_sizes, int n_in,
                              void* d_out, int out_size, void* d_ws, size_t ws_size,
                              hipStream_t stream) {
  (void)in_sizes; (void)n_in; (void)out_size; (void)ws_size;
  const int*   inputs  = (const int*)  d_in[0];
  const int*   adj     = (const int*)  d_in[1];
  const int*   mask    = (const int*)  d_in[2];
  const int*   item    = (const int*)  d_in[3];
  const int*   adj_all = (const int*)  d_in[5];
  const float* num_w   = (const float*)d_in[6];
  const float* emb     = (const float*)d_in[7];
  const float* pose    = (const float*)d_in[8];
  const float* a_local = (const float*)d_in[9];
  const float* gw1     = (const float*)d_in[10];
  const float* gw2     = (const float*)d_in[11];
  const float* gw3     = (const float*)d_in[12];
  const float* w1      = (const float*)d_in[13];
  const float* w2      = (const float*)d_in[14];
  const float* glu1w   = (const float*)d_in[15];
  const float* glu1b   = (const float*)d_in[16];
  const float* glu2w   = (const float*)d_in[17];
  float* out = (float*)d_out;

  // workspace layout (float units)
  float* W     = (float*)d_ws;
  float* hl    = W;                    // 819200
  float* hg    = W + 819200;           // 819200
  short* e0pB  = (short*)(W + 1638400);// bf16 gout output hop0-i0, 819200 shorts
  short* e1pB  = (short*)(W + 2457600);// bf16 gout output hop0-i1, 6553600 shorts
  float* sess  = W + 9011200;          // 16384
  float* g2    = W + 9027584;          // 16384
  float* sel   = W + 9043968;          // 16384
  short* sel2b = (short*)(W + 9060352);// 16384 shorts
  float* norms = W + 9076736;          // 128
  float* wsLoss= W + 9076864;          // 128
  float* n1w   = W + 9076992;          // 51200
  float* n2w   = W + 9128192;          // 409600
  float* betaW = W + 9537792;          // 6400
  float* w1T   = W + 9544192;          // 32768 (2 hops)
  float* glu1wT= W + 9576960;          // 16384
  short* w3Tb  = (short*)(W + 9593344);// 2*128*264 shorts
  int*   n1i   = (int*)(W + 9627136);  // 51200
  int*   n2i   = n1i + 51200;          // 409600

  // d_out scratch (scores region, fully overwritten by k_scores at the end):
  short* embB   = (short*)(out + 819712);
  short* BsessG = (short*)(out + 819712 + 3200000);
  short* hgB    = (short*)(out + 819712 + 3200000 + 2097152);

  k_prep_all<<<3701, 256, 0, stream>>>(emb, item, mask, gw1, gw3, glu1w,
                                       embB, w1T, glu1wT, w3Tb, sess);
  k_stage2<<<456, 256, 0, stream>>>(w1T, sess, inputs, adj_all, num_w,
                                    BsessG, n1i, n1w, n2i, n2w);
  k_local<<<dim3(2, B_), 256, 0, stream>>>(inputs, embB, adj, a_local, hl);

  // hop0 i=0: A=embB[n1i], self=embB[inputs] -> e0pB (rpb=400)
  k_att <<<dim3(4, B_),  256, 0, stream>>>(embB, nullptr, n1i, n1w, BsessG,
                                           gw1, gw2, e0pB, 400);
  k_gout<<<100, 256, 0, stream>>>(embB, nullptr, inputs, w3Tb, e0pB, nullptr, e0pB);
  // hop0 i=1: A=embB[n2i], self=embB[n1i] -> e1pB (rpb=3200)
  k_att <<<dim3(25, B_), 256, 0, stream>>>(embB, nullptr, n2i, n2w, BsessG,
                                           gw1, gw2, e1pB, 3200);
  k_gout<<<800, 256, 0, stream>>>(embB, nullptr, n1i, w3Tb, e1pB, nullptr, e1pB);
  // hop1: A=e1pB dense, self=e0pB dense -> hgB (bf16) -> gout -> hg (f32)
  k_att <<<dim3(4, B_),  256, 0, stream>>>(embB, e1pB, nullptr, n1w,
                                           BsessG + (size_t)128*16384,
                                           gw1 + 129*128, gw2 + 128, hgB, 400);
  k_gout<<<100, 256, 0, stream>>>(embB, e0pB, nullptr, w3Tb + 128*264, hgB, hg, nullptr);

  k_sslhs<<<B_, 128, 0, stream>>>(hl, hg, mask, glu2w, out, wsLoss, g2);
  k_beta<<<dim3(L_, B_), 128, 0, stream>>>(out, mask, pose, w1, w2, glu1wT, glu1b, g2, betaW);
  k_selnorm<<<B_, 128, 0, stream>>>(out, betaW, sel, norms);
  k_topk<<<B_, 128, 0, stream>>>(sel, norms, wsLoss, sel2b, out + B_*L_*D_);
  k_scores<<<(NSC_ + 63)/64, 256, 0, stream>>>(sel2b, emb, out + B_*L_*D_ + 1);
}

// Round 6
// 483.361 us; speedup vs baseline: 1.1448x; 1.0310x over previous
//
#include <hip/hip_runtime.h>
#include <stdint.h>

// ---------------- constants ----------------
namespace {
constexpr int B_ = 128;
constexpr int L_ = 50;
constexpr int D_ = 128;
constexpr int S_ = 8;
constexpr int NSC_ = 99999;       // NUM_NODE-1
constexpr int NBR_ = 9;
}
#define LEAKY_ 0.2f
#define BETA_ 0.005f

typedef __attribute__((ext_vector_type(8))) __bf16 bf16x8;
typedef __attribute__((ext_vector_type(4))) float f32x4;

__device__ __forceinline__ float leaky_(float x){ return x >= 0.f ? x : LEAKY_*x; }
__device__ __forceinline__ float sigm_(float x){ return 1.f/(1.f+expf(-x)); }

__device__ __forceinline__ short f2b(float f){
  uint32_t u = __float_as_uint(f);
  u += 0x7fffu + ((u >> 16) & 1u);
  return (short)(u >> 16);
}
__device__ __forceinline__ float b2f(short s){
  return __uint_as_float(((uint32_t)(uint16_t)s) << 16);
}
__device__ __forceinline__ f32x4 zero4(){ f32x4 z = {0.f,0.f,0.f,0.f}; return z; }
__device__ __forceinline__ f32x4 mfma_bf16(bf16x8 a, bf16x8 b, f32x4 c){
  return __builtin_amdgcn_mfma_f32_16x16x32_bf16(a, b, c, 0, 0, 0);
}

// ---------------- threefry2x32 (JAX-compatible) ----------------
__device__ __forceinline__ void tf2x32(uint32_t k0, uint32_t k1, uint32_t c0, uint32_t c1,
                                       uint32_t* o0, uint32_t* o1){
  uint32_t ks2 = k0 ^ k1 ^ 0x1BD11BDAu;
  uint32_t x0 = c0 + k0, x1 = c1 + k1;
#define RND_(r) { x0 += x1; x1 = (x1<<(r))|(x1>>(32-(r))); x1 ^= x0; }
  RND_(13) RND_(15) RND_(26) RND_(6)   x0 += k1;  x1 += ks2 + 1u;
  RND_(17) RND_(29) RND_(16) RND_(24)  x0 += ks2; x1 += k0  + 2u;
  RND_(13) RND_(15) RND_(26) RND_(6)   x0 += k0;  x1 += k1  + 3u;
  RND_(17) RND_(29) RND_(16) RND_(24)  x0 += k1;  x1 += ks2 + 4u;
  RND_(13) RND_(15) RND_(26) RND_(6)   x0 += ks2; x1 += k0  + 5u;
#undef RND_
  *o0 = x0; *o1 = x1;
}

// ---------------- fused prep: embB + weight transposes + sess ----------------
__global__ __launch_bounds__(256) void k_prep_all(
    const float* __restrict__ emb, const int* __restrict__ item,
    const int* __restrict__ mask, const float* __restrict__ gw1,
    const float* __restrict__ gw3, const float* __restrict__ glu1w,
    short* __restrict__ embB, float* __restrict__ w1T,
    float* __restrict__ glu1wT, short* __restrict__ w3T,
    float* __restrict__ sess)
{
  int blk = blockIdx.x, tid = threadIdx.x;
  if (blk < 3125){
    size_t base = (size_t)blk*4096 + (size_t)tid*16;
    float4 f0 = *(const float4*)(emb + base);
    float4 f1 = *(const float4*)(emb + base + 4);
    float4 f2 = *(const float4*)(emb + base + 8);
    float4 f3 = *(const float4*)(emb + base + 12);
    short4 s0, s1, s2, s3;
    s0.x=f2b(f0.x); s0.y=f2b(f0.y); s0.z=f2b(f0.z); s0.w=f2b(f0.w);
    s1.x=f2b(f1.x); s1.y=f2b(f1.y); s1.z=f2b(f1.z); s1.w=f2b(f1.w);
    s2.x=f2b(f2.x); s2.y=f2b(f2.y); s2.z=f2b(f2.z); s2.w=f2b(f2.w);
    s3.x=f2b(f3.x); s3.y=f2b(f3.y); s3.z=f2b(f3.z); s3.w=f2b(f3.w);
    *(short4*)(embB + base)      = s0;
    *(short4*)(embB + base + 4)  = s1;
    *(short4*)(embB + base + 8)  = s2;
    *(short4*)(embB + base + 12) = s3;
  } else if (blk < 3573){
    int o = (blk - 3125)*256 + tid;
    if (o < 32768){
      int hop = o >> 14, r = o & 16383;
      int d = r >> 7, e = r & 127;
      w1T[o] = gw1[hop*(129*128) + e*128 + d];
    } else if (o < 49152){
      int o2 = o - 32768;
      int e = o2 >> 7, t = o2 & 127;
      glu1wT[o2] = glu1w[t*128 + e];
    } else if (o < 114688){
      int o3 = o - 49152;
      int hop = o3 >> 15, r = o3 & 32767;
      int nn = r >> 8, k = r & 255;
      w3T[hop*(128*264) + nn*264 + k] = f2b(gw3[hop*(256*128) + k*128 + nn]);
    }
  } else {
    int b = blk - 3573;
    if (tid < 128){
      float acc = 0.f, ms = 0.f;
      for (int l = 0; l < L_; l++){
        float mk = (float)mask[b*L_ + l];
        ms += mk;
        acc += mk * emb[(size_t)item[b*L_ + l]*D_ + tid];
      }
      sess[(size_t)b*D_ + tid] = acc / ms;
    }
  }
}

// ---------------- fused stage2: Bsess + 2-hop sampling ----------------
__global__ __launch_bounds__(256) void k_stage2(
    const float* __restrict__ w1T, const float* __restrict__ sess,
    const int* __restrict__ inputs, const int* __restrict__ adj_all,
    const float* __restrict__ num_w,
    short* __restrict__ Bsess, int* __restrict__ n1i, float* __restrict__ n1w,
    int* __restrict__ n2i, float* __restrict__ n2w)
{
  int blk = blockIdx.x, tid = threadIdx.x;
  if (blk < 256){
    int hop = blk >> 7, b = blk & 127;
    const float* wt = w1T + hop*16384;
    short* outp = Bsess + ((size_t)hop*128 + b)*16384;
    __shared__ float sessS[128];
    if (tid < 128) sessS[tid] = sess[b*128 + tid];
    __syncthreads();
    for (int it = 0; it < 64; it++){
      int u = it*256 + tid;
      outp[u] = f2b(wt[u] * sessS[u & 127]);
    }
  } else {
    int p = (blk - 256)*256 + tid;   // p < 51200
    int base = inputs[p >> 3];
    int off  = base*S_ + (p & 7);
    int i1 = adj_all[off];
    n1i[p] = i1;
    n1w[p] = num_w[off];
#pragma unroll
    for (int j = 0; j < 8; j++){
      n2i[(size_t)p*8 + j] = adj_all[i1*8 + j];
      n2w[(size_t)p*8 + j] = num_w[i1*8 + j];
    }
  }
}

// ---------------- local GAT aggregation ----------------
__global__ __launch_bounds__(256) void k_local(const int* __restrict__ inputs,
                                               const short* __restrict__ embB,
                                               const int* __restrict__ adj,
                                               const float* __restrict__ a_local,
                                               float* __restrict__ hl){
  __shared__ float hs[L_*129];
  __shared__ float att[25*52];
  __shared__ float al[4*132];
  __shared__ int idxs[L_];
  int b = blockIdx.y, half = blockIdx.x, tid = threadIdx.x;
  int i0 = half*25;
  if (tid < L_) idxs[tid] = inputs[b*L_ + tid];
  __syncthreads();
  for (int u = tid; u < L_*16; u += 256){
    int i = u >> 4, c = u & 15;
    union { bf16x8 v; short sh[8]; } w;
    w.v = *(const bf16x8*)&embB[(size_t)idxs[i]*128 + c*8];
#pragma unroll
    for (int j = 0; j < 8; j++) hs[i*129 + c*8 + j] = b2f(w.sh[j]);
  }
  for (int e = tid; e < 4*D_; e += 256) al[(e>>7)*132 + (e&127)] = a_local[e];
  __syncthreads();
  for (int p = tid; p < 25*L_; p += 256){
    int il = p / L_, j = p % L_;
    int i = i0 + il;
    int k = adj[((size_t)b*L_ + i)*L_ + j];
    float v = -9e15f;
    if (k >= 1){
      const float* ak = &al[(k-1)*132];
      float acc = 0.f;
      for (int d = 0; d < D_; d++) acc += hs[i*129+d]*hs[j*129+d]*ak[d];
      v = leaky_(acc);
    }
    att[il*52 + j] = v;
  }
  __syncthreads();
  if (tid < 25){
    int il = tid;
    float mx = -INFINITY;
    for (int j = 0; j < L_; j++) mx = fmaxf(mx, att[il*52+j]);
    float sm = 0.f;
    for (int j = 0; j < L_; j++){ float e_ = expf(att[il*52+j] - mx); att[il*52+j] = e_; sm += e_; }
    float inv = 1.f/sm;
    for (int j = 0; j < L_; j++) att[il*52+j] *= inv;
  }
  __syncthreads();
  for (int q = tid; q < 25*D_; q += 256){
    int il = q >> 7, d = q & 127;
    float acc = 0.f;
    for (int j = 0; j < L_; j++) acc += att[il*52+j]*hs[j*129+d];
    hl[((size_t)b*L_ + i0 + il)*D_ + d] = acc;
  }
}

// ---------------- MFMA global-agg attention (bf16 in, bf16 out) ----------------
__global__ __launch_bounds__(256, 4) void k_att(
    const short* __restrict__ embB, const short* __restrict__ denseB,
    const int* __restrict__ nidx, const float* __restrict__ nw,
    const short* __restrict__ Bsess,
    const float* __restrict__ w1g, const float* __restrict__ w2g,
    short* __restrict__ outn, int rpb)
{
  __shared__ __align__(16) short As[128*136];
  __shared__ float w1lS[128], w2S[128], nwsS[128], logitsS[128], alphaS[128];
  const int tid = threadIdx.x;
  const int b = blockIdx.y;
  const int r0 = blockIdx.x * 128;
  if (tid < 128){
    w1lS[tid]  = w1g[128*128 + tid];
    w2S[tid]   = w2g[tid];
    int rr = min(r0 + tid, rpb - 1);
    nwsS[tid]  = nw[(size_t)b*rpb + rr];
  }
  for (int it = 0; it < 8; it++){
    int u = it*256 + tid;
    int lr = u >> 4, c = u & 15;
    int rr = min(r0 + lr, rpb - 1);
    const short* src = denseB ? denseB + ((size_t)b*rpb + rr)*128
                              : embB + (size_t)nidx[(size_t)b*rpb + rr]*128;
    *(bf16x8*)&As[lr*136 + c*8] = *(const bf16x8*)&src[c*8];
  }
  __syncthreads();
  const int lane = tid & 63, wave = tid >> 6;
  const int quad = lane >> 4, l16 = lane & 15;
  const int wr0 = wave * 32;
  const short* Bb = Bsess + (size_t)b*16384;
  f32x4 acc[2][8];
#pragma unroll
  for (int i=0;i<2;i++)
#pragma unroll
    for (int j=0;j<8;j++) acc[i][j] = zero4();
  for (int kc = 0; kc < 4; kc++){
    int k = kc*32 + quad*8;
    bf16x8 a0 = *(const bf16x8*)&As[(wr0 + l16)*136 + k];
    bf16x8 a1 = *(const bf16x8*)&As[(wr0 + 16 + l16)*136 + k];
    bf16x8 bb[8];
#pragma unroll
    for (int nt = 0; nt < 8; nt++)
      bb[nt] = *(const bf16x8*)&Bb[(size_t)(nt*16 + l16)*128 + k];
#pragma unroll
    for (int nt = 0; nt < 8; nt++){
      acc[0][nt] = mfma_bf16(a0, bb[nt], acc[0][nt]);
      acc[1][nt] = mfma_bf16(a1, bb[nt], acc[1][nt]);
    }
  }
#pragma unroll
  for (int rt = 0; rt < 2; rt++){
#pragma unroll
    for (int r = 0; r < 4; r++){
      int rowl = wr0 + rt*16 + quad*4 + r;
      float nwv = nwsS[rowl];
      float c = 0.f;
#pragma unroll
      for (int nt = 0; nt < 8; nt++){
        int col = nt*16 + l16;
        float v = acc[rt][nt][r] + nwv * w1lS[col];
        c += leaky_(v) * w2S[col];
      }
      c += __shfl_xor(c, 1, 64);
      c += __shfl_xor(c, 2, 64);
      c += __shfl_xor(c, 4, 64);
      c += __shfl_xor(c, 8, 64);
      if (l16 == 0) logitsS[rowl] = c;
    }
  }
  __syncthreads();
  if (tid < 16){
    float mx = -INFINITY;
    for (int s = 0; s < 8; s++) mx = fmaxf(mx, logitsS[tid*8+s]);
    float sm = 0.f; float ev[8];
    for (int s = 0; s < 8; s++){ ev[s] = expf(logitsS[tid*8+s]-mx); sm += ev[s]; }
    for (int s = 0; s < 8; s++) alphaS[tid*8+s] = ev[s]/sm;
  }
  __syncthreads();
  {
    int mg = tid >> 4;
    int dc = tid & 15;
    float o[8];
#pragma unroll
    for (int j = 0; j < 8; j++) o[j] = 0.f;
#pragma unroll
    for (int s = 0; s < 8; s++){
      float al = alphaS[mg*8+s];
      union { bf16x8 v; short sh[8]; } u;
      u.v = *(const bf16x8*)&As[(mg*8+s)*136 + dc*8];
#pragma unroll
      for (int j = 0; j < 8; j++) o[j] += al * b2f(u.sh[j]);
    }
    if (r0 + mg*8 < rpb){
      int m = (r0 >> 3) + mg;
      union { short s[8]; bf16x8 v; } pk;
#pragma unroll
      for (int j = 0; j < 8; j++) pk.s[j] = f2b(o[j]);
      *(bf16x8*)(outn + ((size_t)b*(rpb>>3) + m)*128 + dc*8) = pk.v;
    }
  }
}

// ---------------- MFMA global-agg output: out = relu([self||neigh]@w3) ----------------
__global__ __launch_bounds__(256) void k_gout(
    const short* __restrict__ embB, const short* __restrict__ selfB,
    const int* __restrict__ self_idx, const short* __restrict__ w3T,
    const short* __restrict__ neighB, float* __restrict__ outF,
    short* __restrict__ outB)
{
  const int tid = threadIdx.x;
  const int lane = tid & 63, wave = tid >> 6;
  const int quad = lane >> 4, l16 = lane & 15;
  const int rbase = blockIdx.x*64 + wave*16;
  const int row = rbase + l16;
  const short* selfp = self_idx ? embB + (size_t)self_idx[row]*128
                                : selfB + (size_t)row*128;
  const short* neighp = neighB + (size_t)row*128;
  f32x4 acc[8];
#pragma unroll
  for (int i=0;i<8;i++) acc[i] = zero4();
  for (int kc = 0; kc < 4; kc++){
    int k = kc*32 + quad*8;
    bf16x8 a = *(const bf16x8*)&selfp[k];
#pragma unroll
    for (int nt = 0; nt < 8; nt++){
      bf16x8 bb = *(const bf16x8*)&w3T[(size_t)(nt*16 + l16)*264 + k];
      acc[nt] = mfma_bf16(a, bb, acc[nt]);
    }
  }
  for (int kc = 4; kc < 8; kc++){
    int k = kc*32 + quad*8;
    bf16x8 a = *(const bf16x8*)&neighp[k - 128];
#pragma unroll
    for (int nt = 0; nt < 8; nt++){
      bf16x8 bb = *(const bf16x8*)&w3T[(size_t)(nt*16 + l16)*264 + k];
      acc[nt] = mfma_bf16(a, bb, acc[nt]);
    }
  }
  if (outF){
#pragma unroll
    for (int nt = 0; nt < 8; nt++)
#pragma unroll
      for (int r = 0; r < 4; r++){
        int orow = rbase + quad*4 + r;
        outF[(size_t)orow*128 + nt*16 + l16] = fmaxf(acc[nt][r], 0.f);
      }
  } else {
#pragma unroll
    for (int nt = 0; nt < 8; nt++)
#pragma unroll
      for (int r = 0; r < 4; r++){
        int orow = rbase + quad*4 + r;
        outB[(size_t)orow*128 + nt*16 + l16] = f2b(fmaxf(acc[nt][r], 0.f));
      }
  }
}

// ---------------- fused: perms + SSL partial + out = hl + hg + hs/g2 ----------------
__global__ __launch_bounds__(128) void k_sslhs(
    const float* __restrict__ hl, const float* __restrict__ hg,
    const int* __restrict__ mask, const float* __restrict__ glu2_w,
    float* __restrict__ out, float* __restrict__ wsLoss,
    float* __restrict__ g2)
{
  __shared__ uint32_t keys[128];
  __shared__ float red[128];
  __shared__ float hss[128];
  __shared__ int pcS[50];
  __shared__ int prbS;
  int b = blockIdx.x, tid = threadIdx.x;
  uint32_t kr0, kr1, kc0, kc1, sk0, sk1, o0, o1;
  tf2x32(0u, 42u, 0u, 0u, &kr0, &kr1);
  tf2x32(0u, 42u, 0u, 1u, &kc0, &kc1);
  tf2x32(kr0, kr1, 0u, 1u, &sk0, &sk1);
  tf2x32(sk0, sk1, 0u, (uint32_t)tid, &o0, &o1);
  keys[tid] = o0 ^ o1;
  __syncthreads();
  {
    uint32_t mk = keys[tid];
    int rank = 0;
    for (int j = 0; j < 128; j++){
      uint32_t kj = keys[j];
      rank += (kj < mk) || (kj == mk && j < tid);
    }
    if (rank == b) prbS = tid;
  }
  __syncthreads();
  tf2x32(kc0, kc1, 0u, 1u, &sk0, &sk1);
  if (tid < 50){
    tf2x32(sk0, sk1, 0u, (uint32_t)tid, &o0, &o1);
    keys[tid] = o0 ^ o1;
  }
  __syncthreads();
  if (tid < 50){
    uint32_t mk = keys[tid];
    int rank = 0;
    for (int j = 0; j < 50; j++){
      uint32_t kj = keys[j];
      rank += (kj < mk) || (kj == mk && j < tid);
    }
    pcS[rank] = tid;
  }
  __syncthreads();
  int prb = prbS, d = tid;
  float pos = 0.f, neg = 0.f, hsacc = 0.f, ms = 0.f;
  for (int l = 0; l < L_; l++){
    size_t off = ((size_t)b*L_ + l)*D_ + d;
    float hlv = hl[off], hgv = hg[off];
    float o = hlv + hgv;
    out[off] = o;
    pos += hlv * hgv;
    neg += hgv * hl[((size_t)prb*L_ + pcS[l])*D_ + d];
    float mk = (float)mask[b*L_ + l];
    ms += mk;
    hsacc += mk * o;
  }
  hss[d] = hsacc / ms;
  red[d] = -logf(1e-8f + sigm_(pos)) - logf(1e-8f + 1.f - sigm_(neg));
  __syncthreads();
  for (int off = 64; off >= 1; off >>= 1){
    if (d < off) red[d] += red[d + off];
    __syncthreads();
  }
  if (d == 0) wsLoss[b] = red[0];
  // g2 = hs @ glu2_w^T  (hss valid after the barriers above)
  float g = 0.f;
  for (int e = 0; e < 128; e++) g += hss[e]*glu2_w[d*128 + e];
  g2[(size_t)b*128 + d] = g;
}

// ---------------- beta, 10 l-rows per block (weight-reuse version) ----------------
// grid (5, B_), 256 threads. Same accumulation order as R3's verified k_bsel.
__global__ __launch_bounds__(256) void k_beta10(
    const float* __restrict__ hidden, const int* __restrict__ mask,
    const float* __restrict__ pose, const float* __restrict__ w1s,
    const float* __restrict__ w2s, const float* __restrict__ glu1wT,
    const float* __restrict__ glu1b, const float* __restrict__ g2,
    float* __restrict__ betaW)
{
  __shared__ float x[10][260];   // cols 0..127: pos (later nh); 128..255: hidden
  __shared__ float buf[10][132];
  __shared__ float bufB[2][16];
  int lg = blockIdx.x, b = blockIdx.y, tid = threadIdx.x;
  int t = tid & 127, eh = tid >> 7;
  int l0 = lg*10;
  for (int u = tid; u < 10*64; u += 256){
    int row = u >> 6, c4 = u & 63;
    float4 v; int col;
    if (c4 < 32){ v = *(const float4*)(pose + (l0+row)*128 + c4*4); col = c4*4; }
    else        { v = *(const float4*)(hidden + ((size_t)b*L_ + l0+row)*128 + (c4-32)*4); col = 128 + (c4-32)*4; }
    *(float4*)&x[row][col] = v;
  }
  __syncthreads();
  // phase1: nh-pre over e in [eh*128, eh*128+128)
  float acc[10];
#pragma unroll
  for (int l = 0; l < 10; l++) acc[l] = 0.f;
  {
    int e0 = eh*128;
    for (int e = e0; e < e0 + 128; e += 4){
      float wa = w1s[(e+0)*128 + t];
      float wb = w1s[(e+1)*128 + t];
      float wc = w1s[(e+2)*128 + t];
      float wd = w1s[(e+3)*128 + t];
#pragma unroll
      for (int l = 0; l < 10; l++){
        float4 xv = *(const float4*)&x[l][e];
        acc[l] += xv.x*wa; acc[l] += xv.y*wb; acc[l] += xv.z*wc; acc[l] += xv.w*wd;
      }
    }
  }
  if (eh == 1){
#pragma unroll
    for (int i = 0; i < 10; i++) buf[i][t] = acc[i];
  }
  __syncthreads();
  if (eh == 0){
#pragma unroll
    for (int i = 0; i < 10; i++) acc[i] += buf[i][t];
  }
  __syncthreads();
  if (eh == 0){
#pragma unroll
    for (int l = 0; l < 10; l++) x[l][t] = tanhf(acc[l]);
  }
  __syncthreads();
  // phase2: a2 = nh @ glu1wT over e in [eh*64, eh*64+64)
  float acc2[10];
#pragma unroll
  for (int l = 0; l < 10; l++) acc2[l] = 0.f;
  {
    int e0 = eh*64;
    for (int e = e0; e < e0 + 64; e += 4){
      float wa = glu1wT[(e+0)*128 + t];
      float wb = glu1wT[(e+1)*128 + t];
      float wc = glu1wT[(e+2)*128 + t];
      float wd = glu1wT[(e+3)*128 + t];
#pragma unroll
      for (int l = 0; l < 10; l++){
        float4 xv = *(const float4*)&x[l][e];
        acc2[l] += xv.x*wa; acc2[l] += xv.y*wb; acc2[l] += xv.z*wc; acc2[l] += xv.w*wd;
      }
    }
  }
  if (eh == 1){
#pragma unroll
    for (int i = 0; i < 10; i++) buf[i][t] = acc2[i];
  }
  __syncthreads();
  if (eh == 0){
#pragma unroll
    for (int i = 0; i < 10; i++) acc2[i] += buf[i][t];
  }
  __syncthreads();
  if (eh == 0){
    float g2v = g2[(size_t)b*128 + t];
    float g1b = glu1b[t];
    float w2v = w2s[t];
    int lane = tid & 63, wv = tid >> 6;
#pragma unroll
    for (int l = 0; l < 10; l++){
      float ns = sigm_(acc2[l] + g1b + g2v);
      float v = ns * w2v;
      v += __shfl_xor(v, 1, 64);
      v += __shfl_xor(v, 2, 64);
      v += __shfl_xor(v, 4, 64);
      v += __shfl_xor(v, 8, 64);
      v += __shfl_xor(v, 16, 64);
      v += __shfl_xor(v, 32, 64);
      if (lane == 0) bufB[wv][l] = v;
    }
  }
  __syncthreads();
  if (tid < 10)
    betaW[b*L_ + l0 + tid] = (bufB[0][tid] + bufB[1][tid]) * (float)mask[b*L_ + l0 + tid];
}

// ---------------- select = sum_l beta*hidden; norms ----------------
__global__ __launch_bounds__(128) void k_selnorm(
    const float* __restrict__ hidden, const float* __restrict__ betaW,
    float* __restrict__ select, float* __restrict__ norms)
{
  __shared__ float bet[56];
  __shared__ float red[128];
  int b = blockIdx.x, t = threadIdx.x;
  if (t < L_) bet[t] = betaW[b*L_ + t];
  __syncthreads();
  float sel = 0.f;
  for (int l = 0; l < L_; l++) sel += bet[l]*hidden[((size_t)b*L_ + l)*128 + t];
  select[(size_t)b*128 + t] = sel;
  red[t] = sel*sel + 1e-6f;
  __syncthreads();
  for (int off=64; off>=1; off>>=1){ if (t<off) red[t]+=red[t+off]; __syncthreads(); }
  if (t==0) norms[b] = sqrtf(red[0]);
}

// ---------------- cosine softmax + top-9 + neighbor mix (+ loss finalize) ----------
__global__ __launch_bounds__(128) void k_topk(const float* __restrict__ select,
                                              const float* __restrict__ norms,
                                              const float* __restrict__ wsLoss,
                                              short* __restrict__ select2b,
                                              float* __restrict__ out_loss){
  __shared__ float p[B_];
  __shared__ float red[128];
  __shared__ float tv[NBR_];
  __shared__ int   ti[NBR_];
  int b = blockIdx.x, t = threadIdx.x;
  float dot = 0.f;
  for (int d = 0; d < D_; d++) dot += select[(size_t)b*D_ + d]*select[(size_t)t*D_ + d];
  float logit = dot / (norms[b]*norms[t]);
  red[t] = logit; __syncthreads();
  for (int off = 64; off >= 1; off >>= 1){
    if (t < off) red[t] = fmaxf(red[t], red[t + off]);
    __syncthreads();
  }
  float mx = red[0]; __syncthreads();
  float e_ = expf(logit - mx);
  red[t] = e_; __syncthreads();
  for (int off = 64; off >= 1; off >>= 1){
    if (t < off) red[t] += red[t + off];
    __syncthreads();
  }
  p[t] = e_ / red[0];
  __syncthreads();
  if (t == 0){
    unsigned long long used0 = 0ull, used1 = 0ull;
    for (int k = 0; k < NBR_; k++){
      float best = -INFINITY; int bi = 0;
      for (int j = 0; j < B_; j++){
        bool u = (j < 64) ? ((used0 >> j) & 1ull) : ((used1 >> (j-64)) & 1ull);
        if (!u && p[j] > best){ best = p[j]; bi = j; }
      }
      if (bi < 64) used0 |= 1ull << bi; else used1 |= 1ull << (bi-64);
      tv[k] = best; ti[k] = bi;
    }
    float mx2 = -INFINITY;
    for (int k = 0; k < NBR_; k++) mx2 = fmaxf(mx2, tv[k]);
    float s2 = 0.f;
    for (int k = 0; k < NBR_; k++){ tv[k] = expf(tv[k]-mx2); s2 += tv[k]; }
    for (int k = 0; k < NBR_; k++) tv[k] /= s2;
  }
  __syncthreads();
  float nb = 0.f;
#pragma unroll
  for (int k = 0; k < NBR_; k++) nb += tv[k]*select[(size_t)ti[k]*D_ + t];
  select2b[(size_t)b*D_ + t] = f2b(select[(size_t)b*D_ + t] + nb);
  // loss finalize on block 0
  if (b == 0){
    __syncthreads();
    red[t] = wsLoss[t];
    __syncthreads();
    for (int off = 64; off >= 1; off >>= 1){
      if (t < off) red[t] += red[t + off];
      __syncthreads();
    }
    if (t == 0) out_loss[0] = BETA_ * red[0];
  }
}

// ---------------- MFMA scores = sel2 @ emb[1:].T (LDS-staged B) ----------------
__global__ __launch_bounds__(256) void k_scores(
    const short* __restrict__ sel2b, const float* __restrict__ emb,
    float* __restrict__ scores)
{
  __shared__ __align__(16) short Es[64*136];
  const int tid = threadIdx.x;
  const int n0 = blockIdx.x*64;
  for (int it = 0; it < 8; it++){
    int u = it*256 + tid;
    int lr = u >> 5, c = u & 31;
    int n = min(n0 + lr, NSC_ - 1);
    float4 v = *(const float4*)(emb + (size_t)(1 + n)*128 + c*4);
    short4 s4; s4.x=f2b(v.x); s4.y=f2b(v.y); s4.z=f2b(v.z); s4.w=f2b(v.w);
    *(short4*)&Es[lr*136 + c*4] = s4;
  }
  __syncthreads();
  const int lane = tid & 63, wave = tid >> 6;
  const int quad = lane >> 4, l16 = lane & 15;
  int n = n0 + wave*16 + l16;
  f32x4 acc[8];
#pragma unroll
  for (int i=0;i<8;i++) acc[i] = zero4();
  for (int kc = 0; kc < 4; kc++){
    int k = kc*32 + quad*8;
    bf16x8 bb = *(const bf16x8*)&Es[(wave*16 + l16)*136 + k];
#pragma unroll
    for (int rt = 0; rt < 8; rt++){
      bf16x8 a = *(const bf16x8*)&sel2b[(rt*16 + l16)*128 + k];
      acc[rt] = mfma_bf16(a, bb, acc[rt]);
    }
  }
  if (n < NSC_){
#pragma unroll
    for (int rt = 0; rt < 8; rt++)
#pragma unroll
      for (int r = 0; r < 4; r++){
        int brow = rt*16 + quad*4 + r;
        scores[(size_t)brow*NSC_ + n] = acc[rt][r];
      }
  }
}

// ---------------- launcher ----------------
extern "C" void kernel_launch(void* const* d_in, const int* in_sizes, int n_in,
                              void* d_out, int out_size, void* d_ws, size_t ws_size,
                              hipStream_t stream) {
  (void)in_sizes; (void)n_in; (void)out_size; (void)ws_size;
  const int*   inputs  = (const int*)  d_in[0];
  const int*   adj     = (const int*)  d_in[1];
  const int*   mask    = (const int*)  d_in[2];
  const int*   item    = (const int*)  d_in[3];
  const int*   adj_all = (const int*)  d_in[5];
  const float* num_w   = (const float*)d_in[6];
  const float* emb     = (const float*)d_in[7];
  const float* pose    = (const float*)d_in[8];
  const float* a_local = (const float*)d_in[9];
  const float* gw1     = (const float*)d_in[10];
  const float* gw2     = (const float*)d_in[11];
  const float* gw3     = (const float*)d_in[12];
  const float* w1      = (const float*)d_in[13];
  const float* w2      = (const float*)d_in[14];
  const float* glu1w   = (const float*)d_in[15];
  const float* glu1b   = (const float*)d_in[16];
  const float* glu2w   = (const float*)d_in[17];
  float* out = (float*)d_out;

  // workspace layout (float units)
  float* W     = (float*)d_ws;
  float* hl    = W;                    // 819200
  float* hg    = W + 819200;           // 819200
  short* e0pB  = (short*)(W + 1638400);// bf16 gout output hop0-i0, 819200 shorts
  short* e1pB  = (short*)(W + 2457600);// bf16 gout output hop0-i1, 6553600 shorts
  float* sess  = W + 9011200;          // 16384
  float* g2    = W + 9027584;          // 16384
  float* sel   = W + 9043968;          // 16384
  short* sel2b = (short*)(W + 9060352);// 16384 shorts
  float* norms = W + 9076736;          // 128
  float* wsLoss= W + 9076864;          // 128
  float* n1w   = W + 9076992;          // 51200
  float* n2w   = W + 9128192;          // 409600
  float* betaW = W + 9537792;          // 6400
  float* w1T   = W + 9544192;          // 32768 (2 hops)
  float* glu1wT= W + 9576960;          // 16384
  short* w3Tb  = (short*)(W + 9593344);// 2*128*264 shorts
  int*   n1i   = (int*)(W + 9627136);  // 51200
  int*   n2i   = n1i + 51200;          // 409600

  // d_out scratch (scores region, fully overwritten by k_scores at the end):
  short* embB   = (short*)(out + 819712);
  short* BsessG = (short*)(out + 819712 + 3200000);
  short* hgB    = (short*)(out + 819712 + 3200000 + 2097152);

  k_prep_all<<<3701, 256, 0, stream>>>(emb, item, mask, gw1, gw3, glu1w,
                                       embB, w1T, glu1wT, w3Tb, sess);
  k_stage2<<<456, 256, 0, stream>>>(w1T, sess, inputs, adj_all, num_w,
                                    BsessG, n1i, n1w, n2i, n2w);
  k_local<<<dim3(2, B_), 256, 0, stream>>>(inputs, embB, adj, a_local, hl);

  // hop0 i=0: A=embB[n1i], self=embB[inputs] -> e0pB (rpb=400)
  k_att <<<dim3(4, B_),  256, 0, stream>>>(embB, nullptr, n1i, n1w, BsessG,
                                           gw1, gw2, e0pB, 400);
  k_gout<<<100, 256, 0, stream>>>(embB, nullptr, inputs, w3Tb, e0pB, nullptr, e0pB);
  // hop0 i=1: A=embB[n2i], self=embB[n1i] -> e1pB (rpb=3200)
  k_att <<<dim3(25, B_), 256, 0, stream>>>(embB, nullptr, n2i, n2w, BsessG,
                                           gw1, gw2, e1pB, 3200);
  k_gout<<<800, 256, 0, stream>>>(embB, nullptr, n1i, w3Tb, e1pB, nullptr, e1pB);
  // hop1: A=e1pB dense, self=e0pB dense -> hgB (bf16) -> gout -> hg (f32)
  k_att <<<dim3(4, B_),  256, 0, stream>>>(embB, e1pB, nullptr, n1w,
                                           BsessG + (size_t)128*16384,
                                           gw1 + 129*128, gw2 + 128, hgB, 400);
  k_gout<<<100, 256, 0, stream>>>(embB, e0pB, nullptr, w3Tb + 128*264, hgB, hg, nullptr);

  k_sslhs<<<B_, 128, 0, stream>>>(hl, hg, mask, glu2w, out, wsLoss, g2);
  k_beta10<<<dim3(5, B_), 256, 0, stream>>>(out, mask, pose, w1, w2, glu1wT,
                                            glu1b, g2, betaW);
  k_selnorm<<<B_, 128, 0, stream>>>(out, betaW, sel, norms);
  k_topk<<<B_, 128, 0, stream>>>(sel, norms, wsLoss, sel2b, out + B_*L_*D_);
  k_scores<<<(NSC_ + 63)/64, 256, 0, stream>>>(sel2b, emb, out + B_*L_*D_ + 1);
}

// Round 7
// 461.078 us; speedup vs baseline: 1.2001x; 1.0483x over previous
//
#include <hip/hip_runtime.h>
#include <stdint.h>

// ---------------- constants ----------------
namespace {
constexpr int B_ = 128;
constexpr int L_ = 50;
constexpr int D_ = 128;
constexpr int S_ = 8;
constexpr int NSC_ = 99999;       // NUM_NODE-1
constexpr int NBR_ = 9;
}
#define LEAKY_ 0.2f
#define BETA_ 0.005f

typedef __attribute__((ext_vector_type(8))) __bf16 bf16x8;
typedef __attribute__((ext_vector_type(4))) float f32x4;

__device__ __forceinline__ float leaky_(float x){ return x >= 0.f ? x : LEAKY_*x; }
__device__ __forceinline__ float sigm_(float x){ return 1.f/(1.f+expf(-x)); }

__device__ __forceinline__ short f2b(float f){
  uint32_t u = __float_as_uint(f);
  u += 0x7fffu + ((u >> 16) & 1u);
  return (short)(u >> 16);
}
__device__ __forceinline__ float b2f(short s){
  return __uint_as_float(((uint32_t)(uint16_t)s) << 16);
}
__device__ __forceinline__ f32x4 zero4(){ f32x4 z = {0.f,0.f,0.f,0.f}; return z; }
__device__ __forceinline__ f32x4 mfma_bf16(bf16x8 a, bf16x8 b, f32x4 c){
  return __builtin_amdgcn_mfma_f32_16x16x32_bf16(a, b, c, 0, 0, 0);
}

// ---------------- threefry2x32 (JAX-compatible) ----------------
__device__ __forceinline__ void tf2x32(uint32_t k0, uint32_t k1, uint32_t c0, uint32_t c1,
                                       uint32_t* o0, uint32_t* o1){
  uint32_t ks2 = k0 ^ k1 ^ 0x1BD11BDAu;
  uint32_t x0 = c0 + k0, x1 = c1 + k1;
#define RND_(r) { x0 += x1; x1 = (x1<<(r))|(x1>>(32-(r))); x1 ^= x0; }
  RND_(13) RND_(15) RND_(26) RND_(6)   x0 += k1;  x1 += ks2 + 1u;
  RND_(17) RND_(29) RND_(16) RND_(24)  x0 += ks2; x1 += k0  + 2u;
  RND_(13) RND_(15) RND_(26) RND_(6)   x0 += k0;  x1 += k1  + 3u;
  RND_(17) RND_(29) RND_(16) RND_(24)  x0 += k1;  x1 += ks2 + 4u;
  RND_(13) RND_(15) RND_(26) RND_(6)   x0 += ks2; x1 += k0  + 5u;
#undef RND_
  *o0 = x0; *o1 = x1;
}

// ---------------- fused prep: embB + weight transposes + sess + sampling ----------
// blocks 0..3124: embB; 3125..3572: weights; 3573..3700: sess; 3701..3900: sampling
__global__ __launch_bounds__(256) void k_prep_all(
    const float* __restrict__ emb, const int* __restrict__ item,
    const int* __restrict__ mask, const float* __restrict__ gw1,
    const float* __restrict__ gw3, const float* __restrict__ glu1w,
    const int* __restrict__ inputs, const int* __restrict__ adj_all,
    const float* __restrict__ num_w,
    short* __restrict__ embB, float* __restrict__ w1T,
    float* __restrict__ glu1wT, short* __restrict__ w3T,
    float* __restrict__ sess,
    int* __restrict__ n1i, float* __restrict__ n1w,
    int* __restrict__ n2i, float* __restrict__ n2w)
{
  int blk = blockIdx.x, tid = threadIdx.x;
  if (blk < 3125){
    size_t base = (size_t)blk*4096 + (size_t)tid*16;
    float4 f0 = *(const float4*)(emb + base);
    float4 f1 = *(const float4*)(emb + base + 4);
    float4 f2 = *(const float4*)(emb + base + 8);
    float4 f3 = *(const float4*)(emb + base + 12);
    short4 s0, s1, s2, s3;
    s0.x=f2b(f0.x); s0.y=f2b(f0.y); s0.z=f2b(f0.z); s0.w=f2b(f0.w);
    s1.x=f2b(f1.x); s1.y=f2b(f1.y); s1.z=f2b(f1.z); s1.w=f2b(f1.w);
    s2.x=f2b(f2.x); s2.y=f2b(f2.y); s2.z=f2b(f2.z); s2.w=f2b(f2.w);
    s3.x=f2b(f3.x); s3.y=f2b(f3.y); s3.z=f2b(f3.z); s3.w=f2b(f3.w);
    *(short4*)(embB + base)      = s0;
    *(short4*)(embB + base + 4)  = s1;
    *(short4*)(embB + base + 8)  = s2;
    *(short4*)(embB + base + 12) = s3;
  } else if (blk < 3573){
    int o = (blk - 3125)*256 + tid;
    if (o < 32768){
      int hop = o >> 14, r = o & 16383;
      int d = r >> 7, e = r & 127;
      w1T[o] = gw1[hop*(129*128) + e*128 + d];
    } else if (o < 49152){
      int o2 = o - 32768;
      int e = o2 >> 7, t = o2 & 127;
      glu1wT[o2] = glu1w[t*128 + e];
    } else if (o < 114688){
      int o3 = o - 49152;
      int hop = o3 >> 15, r = o3 & 32767;
      int nn = r >> 8, k = r & 255;
      w3T[hop*(128*264) + nn*264 + k] = f2b(gw3[hop*(256*128) + k*128 + nn]);
    }
  } else if (blk < 3701){
    int b = blk - 3573;
    if (tid < 128){
      float acc = 0.f, ms = 0.f;
      for (int l = 0; l < L_; l++){
        float mk = (float)mask[b*L_ + l];
        ms += mk;
        acc += mk * emb[(size_t)item[b*L_ + l]*D_ + tid];
      }
      sess[(size_t)b*D_ + tid] = acc / ms;
    }
  } else {
    int p = (blk - 3701)*256 + tid;   // p < 51200
    int base = inputs[p >> 3];
    int off  = base*S_ + (p & 7);
    int i1 = adj_all[off];
    n1i[p] = i1;
    n1w[p] = num_w[off];
#pragma unroll
    for (int j = 0; j < 8; j++){
      n2i[(size_t)p*8 + j] = adj_all[i1*8 + j];
      n2w[(size_t)p*8 + j] = num_w[i1*8 + j];
    }
  }
}

// ---------------- Bsess only ----------------
__global__ __launch_bounds__(256) void k_bsess(
    const float* __restrict__ w1T, const float* __restrict__ sess,
    short* __restrict__ Bsess)
{
  int blk = blockIdx.x, tid = threadIdx.x;
  int hop = blk >> 7, b = blk & 127;
  const float* wt = w1T + hop*16384;
  short* outp = Bsess + ((size_t)hop*128 + b)*16384;
  __shared__ float sessS[128];
  if (tid < 128) sessS[tid] = sess[b*128 + tid];
  __syncthreads();
  for (int it = 0; it < 64; it++){
    int u = it*256 + tid;
    outp[u] = f2b(wt[u] * sessS[u & 127]);
  }
}

// ---------------- local GAT aggregation ----------------
__global__ __launch_bounds__(256) void k_local(const int* __restrict__ inputs,
                                               const short* __restrict__ embB,
                                               const int* __restrict__ adj,
                                               const float* __restrict__ a_local,
                                               float* __restrict__ hl){
  __shared__ float hs[L_*129];
  __shared__ float att[25*52];
  __shared__ float al[4*132];
  __shared__ int idxs[L_];
  int b = blockIdx.y, half = blockIdx.x, tid = threadIdx.x;
  int i0 = half*25;
  if (tid < L_) idxs[tid] = inputs[b*L_ + tid];
  __syncthreads();
  for (int u = tid; u < L_*16; u += 256){
    int i = u >> 4, c = u & 15;
    union { bf16x8 v; short sh[8]; } w;
    w.v = *(const bf16x8*)&embB[(size_t)idxs[i]*128 + c*8];
#pragma unroll
    for (int j = 0; j < 8; j++) hs[i*129 + c*8 + j] = b2f(w.sh[j]);
  }
  for (int e = tid; e < 4*D_; e += 256) al[(e>>7)*132 + (e&127)] = a_local[e];
  __syncthreads();
  for (int p = tid; p < 25*L_; p += 256){
    int il = p / L_, j = p % L_;
    int i = i0 + il;
    int k = adj[((size_t)b*L_ + i)*L_ + j];
    float v = -9e15f;
    if (k >= 1){
      const float* ak = &al[(k-1)*132];
      float acc = 0.f;
      for (int d = 0; d < D_; d++) acc += hs[i*129+d]*hs[j*129+d]*ak[d];
      v = leaky_(acc);
    }
    att[il*52 + j] = v;
  }
  __syncthreads();
  if (tid < 25){
    int il = tid;
    float mx = -INFINITY;
    for (int j = 0; j < L_; j++) mx = fmaxf(mx, att[il*52+j]);
    float sm = 0.f;
    for (int j = 0; j < L_; j++){ float e_ = expf(att[il*52+j] - mx); att[il*52+j] = e_; sm += e_; }
    float inv = 1.f/sm;
    for (int j = 0; j < L_; j++) att[il*52+j] *= inv;
  }
  __syncthreads();
  for (int q = tid; q < 25*D_; q += 256){
    int il = q >> 7, d = q & 127;
    float acc = 0.f;
    for (int j = 0; j < L_; j++) acc += att[il*52+j]*hs[j*129+d];
    hl[((size_t)b*L_ + i0 + il)*D_ + d] = acc;
  }
}

// ---------------- merged MFMA att hop0 (i0: bx<4, i1: bx>=4) ----------------
__global__ __launch_bounds__(256, 4) void k_att2(
    const short* __restrict__ embB,
    const int* __restrict__ n1i, const float* __restrict__ n1w,
    const int* __restrict__ n2i, const float* __restrict__ n2w,
    const short* __restrict__ Bsess,
    const float* __restrict__ w1g, const float* __restrict__ w2g,
    short* __restrict__ e0pB, short* __restrict__ e1pB)
{
  __shared__ __align__(16) short As[128*136];
  __shared__ float w1lS[128], w2S[128], nwsS[128], logitsS[128], alphaS[128];
  const int tid = threadIdx.x;
  const int b = blockIdx.y;
  const int bx = blockIdx.x;
  const int* nidx; const float* nw; short* outn; int rpb, r0;
  if (bx < 4){ nidx = n1i; nw = n1w; outn = e0pB; rpb = 400;  r0 = bx*128; }
  else       { nidx = n2i; nw = n2w; outn = e1pB; rpb = 3200; r0 = (bx-4)*128; }
  if (tid < 128){
    w1lS[tid]  = w1g[128*128 + tid];
    w2S[tid]   = w2g[tid];
    int rr = min(r0 + tid, rpb - 1);
    nwsS[tid]  = nw[(size_t)b*rpb + rr];
  }
  for (int it = 0; it < 8; it++){
    int u = it*256 + tid;
    int lr = u >> 4, c = u & 15;
    int rr = min(r0 + lr, rpb - 1);
    const short* src = embB + (size_t)nidx[(size_t)b*rpb + rr]*128;
    *(bf16x8*)&As[lr*136 + c*8] = *(const bf16x8*)&src[c*8];
  }
  __syncthreads();
  const int lane = tid & 63, wave = tid >> 6;
  const int quad = lane >> 4, l16 = lane & 15;
  const int wr0 = wave * 32;
  const short* Bb = Bsess + (size_t)b*16384;
  f32x4 acc[2][8];
#pragma unroll
  for (int i=0;i<2;i++)
#pragma unroll
    for (int j=0;j<8;j++) acc[i][j] = zero4();
  for (int kc = 0; kc < 4; kc++){
    int k = kc*32 + quad*8;
    bf16x8 a0 = *(const bf16x8*)&As[(wr0 + l16)*136 + k];
    bf16x8 a1 = *(const bf16x8*)&As[(wr0 + 16 + l16)*136 + k];
    bf16x8 bb[8];
#pragma unroll
    for (int nt = 0; nt < 8; nt++)
      bb[nt] = *(const bf16x8*)&Bb[(size_t)(nt*16 + l16)*128 + k];
#pragma unroll
    for (int nt = 0; nt < 8; nt++){
      acc[0][nt] = mfma_bf16(a0, bb[nt], acc[0][nt]);
      acc[1][nt] = mfma_bf16(a1, bb[nt], acc[1][nt]);
    }
  }
#pragma unroll
  for (int rt = 0; rt < 2; rt++){
#pragma unroll
    for (int r = 0; r < 4; r++){
      int rowl = wr0 + rt*16 + quad*4 + r;
      float nwv = nwsS[rowl];
      float c = 0.f;
#pragma unroll
      for (int nt = 0; nt < 8; nt++){
        int col = nt*16 + l16;
        float v = acc[rt][nt][r] + nwv * w1lS[col];
        c += leaky_(v) * w2S[col];
      }
      c += __shfl_xor(c, 1, 64);
      c += __shfl_xor(c, 2, 64);
      c += __shfl_xor(c, 4, 64);
      c += __shfl_xor(c, 8, 64);
      if (l16 == 0) logitsS[rowl] = c;
    }
  }
  __syncthreads();
  if (tid < 16){
    float mx = -INFINITY;
    for (int s = 0; s < 8; s++) mx = fmaxf(mx, logitsS[tid*8+s]);
    float sm = 0.f; float ev[8];
    for (int s = 0; s < 8; s++){ ev[s] = expf(logitsS[tid*8+s]-mx); sm += ev[s]; }
    for (int s = 0; s < 8; s++) alphaS[tid*8+s] = ev[s]/sm;
  }
  __syncthreads();
  {
    int mg = tid >> 4;
    int dc = tid & 15;
    float o[8];
#pragma unroll
    for (int j = 0; j < 8; j++) o[j] = 0.f;
#pragma unroll
    for (int s = 0; s < 8; s++){
      float al = alphaS[mg*8+s];
      union { bf16x8 v; short sh[8]; } u;
      u.v = *(const bf16x8*)&As[(mg*8+s)*136 + dc*8];
#pragma unroll
      for (int j = 0; j < 8; j++) o[j] += al * b2f(u.sh[j]);
    }
    if (r0 + mg*8 < rpb){
      int m = (r0 >> 3) + mg;
      union { short s[8]; bf16x8 v; } pk;
#pragma unroll
      for (int j = 0; j < 8; j++) pk.s[j] = f2b(o[j]);
      *(bf16x8*)(outn + ((size_t)b*(rpb>>3) + m)*128 + dc*8) = pk.v;
    }
  }
}

// ---------------- standalone MFMA att (hop1 dense) ----------------
__global__ __launch_bounds__(256, 4) void k_att(
    const short* __restrict__ embB, const short* __restrict__ denseB,
    const int* __restrict__ nidx, const float* __restrict__ nw,
    const short* __restrict__ Bsess,
    const float* __restrict__ w1g, const float* __restrict__ w2g,
    short* __restrict__ outn, int rpb)
{
  __shared__ __align__(16) short As[128*136];
  __shared__ float w1lS[128], w2S[128], nwsS[128], logitsS[128], alphaS[128];
  const int tid = threadIdx.x;
  const int b = blockIdx.y;
  const int r0 = blockIdx.x * 128;
  if (tid < 128){
    w1lS[tid]  = w1g[128*128 + tid];
    w2S[tid]   = w2g[tid];
    int rr = min(r0 + tid, rpb - 1);
    nwsS[tid]  = nw[(size_t)b*rpb + rr];
  }
  for (int it = 0; it < 8; it++){
    int u = it*256 + tid;
    int lr = u >> 4, c = u & 15;
    int rr = min(r0 + lr, rpb - 1);
    const short* src = denseB ? denseB + ((size_t)b*rpb + rr)*128
                              : embB + (size_t)nidx[(size_t)b*rpb + rr]*128;
    *(bf16x8*)&As[lr*136 + c*8] = *(const bf16x8*)&src[c*8];
  }
  __syncthreads();
  const int lane = tid & 63, wave = tid >> 6;
  const int quad = lane >> 4, l16 = lane & 15;
  const int wr0 = wave * 32;
  const short* Bb = Bsess + (size_t)b*16384;
  f32x4 acc[2][8];
#pragma unroll
  for (int i=0;i<2;i++)
#pragma unroll
    for (int j=0;j<8;j++) acc[i][j] = zero4();
  for (int kc = 0; kc < 4; kc++){
    int k = kc*32 + quad*8;
    bf16x8 a0 = *(const bf16x8*)&As[(wr0 + l16)*136 + k];
    bf16x8 a1 = *(const bf16x8*)&As[(wr0 + 16 + l16)*136 + k];
    bf16x8 bb[8];
#pragma unroll
    for (int nt = 0; nt < 8; nt++)
      bb[nt] = *(const bf16x8*)&Bb[(size_t)(nt*16 + l16)*128 + k];
#pragma unroll
    for (int nt = 0; nt < 8; nt++){
      acc[0][nt] = mfma_bf16(a0, bb[nt], acc[0][nt]);
      acc[1][nt] = mfma_bf16(a1, bb[nt], acc[1][nt]);
    }
  }
#pragma unroll
  for (int rt = 0; rt < 2; rt++){
#pragma unroll
    for (int r = 0; r < 4; r++){
      int rowl = wr0 + rt*16 + quad*4 + r;
      float nwv = nwsS[rowl];
      float c = 0.f;
#pragma unroll
      for (int nt = 0; nt < 8; nt++){
        int col = nt*16 + l16;
        float v = acc[rt][nt][r] + nwv * w1lS[col];
        c += leaky_(v) * w2S[col];
      }
      c += __shfl_xor(c, 1, 64);
      c += __shfl_xor(c, 2, 64);
      c += __shfl_xor(c, 4, 64);
      c += __shfl_xor(c, 8, 64);
      if (l16 == 0) logitsS[rowl] = c;
    }
  }
  __syncthreads();
  if (tid < 16){
    float mx = -INFINITY;
    for (int s = 0; s < 8; s++) mx = fmaxf(mx, logitsS[tid*8+s]);
    float sm = 0.f; float ev[8];
    for (int s = 0; s < 8; s++){ ev[s] = expf(logitsS[tid*8+s]-mx); sm += ev[s]; }
    for (int s = 0; s < 8; s++) alphaS[tid*8+s] = ev[s]/sm;
  }
  __syncthreads();
  {
    int mg = tid >> 4;
    int dc = tid & 15;
    float o[8];
#pragma unroll
    for (int j = 0; j < 8; j++) o[j] = 0.f;
#pragma unroll
    for (int s = 0; s < 8; s++){
      float al = alphaS[mg*8+s];
      union { bf16x8 v; short sh[8]; } u;
      u.v = *(const bf16x8*)&As[(mg*8+s)*136 + dc*8];
#pragma unroll
      for (int j = 0; j < 8; j++) o[j] += al * b2f(u.sh[j]);
    }
    if (r0 + mg*8 < rpb){
      int m = (r0 >> 3) + mg;
      union { short s[8]; bf16x8 v; } pk;
#pragma unroll
      for (int j = 0; j < 8; j++) pk.s[j] = f2b(o[j]);
      *(bf16x8*)(outn + ((size_t)b*(rpb>>3) + m)*128 + dc*8) = pk.v;
    }
  }
}

// ---------------- merged gout hop0 (i0: blk<100, i1: blk>=100), bf16 in-place -------
__global__ __launch_bounds__(256) void k_gout2(
    const short* __restrict__ embB, const int* __restrict__ inputs,
    const int* __restrict__ n1i, const short* __restrict__ w3T,
    short* __restrict__ e0pB, short* __restrict__ e1pB)
{
  const int blk = blockIdx.x;
  const int* self_idx; short* buf; int rblk;
  if (blk < 100){ self_idx = inputs; buf = e0pB; rblk = blk; }
  else          { self_idx = n1i;    buf = e1pB; rblk = blk - 100; }
  const int tid = threadIdx.x;
  const int lane = tid & 63, wave = tid >> 6;
  const int quad = lane >> 4, l16 = lane & 15;
  const int rbase = rblk*64 + wave*16;
  const int row = rbase + l16;
  const short* selfp = embB + (size_t)self_idx[row]*128;
  const short* neighp = buf + (size_t)row*128;
  f32x4 acc[8];
#pragma unroll
  for (int i=0;i<8;i++) acc[i] = zero4();
  for (int kc = 0; kc < 4; kc++){
    int k = kc*32 + quad*8;
    bf16x8 a = *(const bf16x8*)&selfp[k];
#pragma unroll
    for (int nt = 0; nt < 8; nt++){
      bf16x8 bb = *(const bf16x8*)&w3T[(size_t)(nt*16 + l16)*264 + k];
      acc[nt] = mfma_bf16(a, bb, acc[nt]);
    }
  }
  for (int kc = 4; kc < 8; kc++){
    int k = kc*32 + quad*8;
    bf16x8 a = *(const bf16x8*)&neighp[k - 128];
#pragma unroll
    for (int nt = 0; nt < 8; nt++){
      bf16x8 bb = *(const bf16x8*)&w3T[(size_t)(nt*16 + l16)*264 + k];
      acc[nt] = mfma_bf16(a, bb, acc[nt]);
    }
  }
#pragma unroll
  for (int nt = 0; nt < 8; nt++)
#pragma unroll
    for (int r = 0; r < 4; r++){
      int orow = rbase + quad*4 + r;
      buf[(size_t)orow*128 + nt*16 + l16] = f2b(fmaxf(acc[nt][r], 0.f));
    }
}

// ---------------- standalone gout (hop1, f32 out) ----------------
__global__ __launch_bounds__(256) void k_gout(
    const short* __restrict__ embB, const short* __restrict__ selfB,
    const int* __restrict__ self_idx, const short* __restrict__ w3T,
    const short* __restrict__ neighB, float* __restrict__ outF,
    short* __restrict__ outB)
{
  const int tid = threadIdx.x;
  const int lane = tid & 63, wave = tid >> 6;
  const int quad = lane >> 4, l16 = lane & 15;
  const int rbase = blockIdx.x*64 + wave*16;
  const int row = rbase + l16;
  const short* selfp = self_idx ? embB + (size_t)self_idx[row]*128
                                : selfB + (size_t)row*128;
  const short* neighp = neighB + (size_t)row*128;
  f32x4 acc[8];
#pragma unroll
  for (int i=0;i<8;i++) acc[i] = zero4();
  for (int kc = 0; kc < 4; kc++){
    int k = kc*32 + quad*8;
    bf16x8 a = *(const bf16x8*)&selfp[k];
#pragma unroll
    for (int nt = 0; nt < 8; nt++){
      bf16x8 bb = *(const bf16x8*)&w3T[(size_t)(nt*16 + l16)*264 + k];
      acc[nt] = mfma_bf16(a, bb, acc[nt]);
    }
  }
  for (int kc = 4; kc < 8; kc++){
    int k = kc*32 + quad*8;
    bf16x8 a = *(const bf16x8*)&neighp[k - 128];
#pragma unroll
    for (int nt = 0; nt < 8; nt++){
      bf16x8 bb = *(const bf16x8*)&w3T[(size_t)(nt*16 + l16)*264 + k];
      acc[nt] = mfma_bf16(a, bb, acc[nt]);
    }
  }
  if (outF){
#pragma unroll
    for (int nt = 0; nt < 8; nt++)
#pragma unroll
      for (int r = 0; r < 4; r++){
        int orow = rbase + quad*4 + r;
        outF[(size_t)orow*128 + nt*16 + l16] = fmaxf(acc[nt][r], 0.f);
      }
  } else {
#pragma unroll
    for (int nt = 0; nt < 8; nt++)
#pragma unroll
      for (int r = 0; r < 4; r++){
        int orow = rbase + quad*4 + r;
        outB[(size_t)orow*128 + nt*16 + l16] = f2b(fmaxf(acc[nt][r], 0.f));
      }
  }
}

// ---------------- fused: perms + SSL partial + out = hl + hg + hs/g2 ----------------
__global__ __launch_bounds__(128) void k_sslhs(
    const float* __restrict__ hl, const float* __restrict__ hg,
    const int* __restrict__ mask, const float* __restrict__ glu2_w,
    float* __restrict__ out, float* __restrict__ wsLoss,
    float* __restrict__ g2)
{
  __shared__ uint32_t keys[128];
  __shared__ float red[128];
  __shared__ float hss[128];
  __shared__ int pcS[50];
  __shared__ int prbS;
  int b = blockIdx.x, tid = threadIdx.x;
  uint32_t kr0, kr1, kc0, kc1, sk0, sk1, o0, o1;
  tf2x32(0u, 42u, 0u, 0u, &kr0, &kr1);
  tf2x32(0u, 42u, 0u, 1u, &kc0, &kc1);
  tf2x32(kr0, kr1, 0u, 1u, &sk0, &sk1);
  tf2x32(sk0, sk1, 0u, (uint32_t)tid, &o0, &o1);
  keys[tid] = o0 ^ o1;
  __syncthreads();
  {
    uint32_t mk = keys[tid];
    int rank = 0;
    for (int j = 0; j < 128; j++){
      uint32_t kj = keys[j];
      rank += (kj < mk) || (kj == mk && j < tid);
    }
    if (rank == b) prbS = tid;
  }
  __syncthreads();
  tf2x32(kc0, kc1, 0u, 1u, &sk0, &sk1);
  if (tid < 50){
    tf2x32(sk0, sk1, 0u, (uint32_t)tid, &o0, &o1);
    keys[tid] = o0 ^ o1;
  }
  __syncthreads();
  if (tid < 50){
    uint32_t mk = keys[tid];
    int rank = 0;
    for (int j = 0; j < 50; j++){
      uint32_t kj = keys[j];
      rank += (kj < mk) || (kj == mk && j < tid);
    }
    pcS[rank] = tid;
  }
  __syncthreads();
  int prb = prbS, d = tid;
  float pos = 0.f, neg = 0.f, hsacc = 0.f, ms = 0.f;
  for (int l = 0; l < L_; l++){
    size_t off = ((size_t)b*L_ + l)*D_ + d;
    float hlv = hl[off], hgv = hg[off];
    float o = hlv + hgv;
    out[off] = o;
    pos += hlv * hgv;
    neg += hgv * hl[((size_t)prb*L_ + pcS[l])*D_ + d];
    float mk = (float)mask[b*L_ + l];
    ms += mk;
    hsacc += mk * o;
  }
  hss[d] = hsacc / ms;
  red[d] = -logf(1e-8f + sigm_(pos)) - logf(1e-8f + 1.f - sigm_(neg));
  __syncthreads();
  for (int off = 64; off >= 1; off >>= 1){
    if (d < off) red[d] += red[d + off];
    __syncthreads();
  }
  if (d == 0) wsLoss[b] = red[0];
  float g = 0.f;
  for (int e = 0; e < 128; e++) g += hss[e]*glu2_w[d*128 + e];
  g2[(size_t)b*128 + d] = g;
}

// ---------------- beta, 10 l-rows per block ----------------
__global__ __launch_bounds__(256) void k_beta10(
    const float* __restrict__ hidden, const int* __restrict__ mask,
    const float* __restrict__ pose, const float* __restrict__ w1s,
    const float* __restrict__ w2s, const float* __restrict__ glu1wT,
    const float* __restrict__ glu1b, const float* __restrict__ g2,
    float* __restrict__ betaW)
{
  __shared__ float x[10][260];
  __shared__ float buf[10][132];
  __shared__ float bufB[2][16];
  int lg = blockIdx.x, b = blockIdx.y, tid = threadIdx.x;
  int t = tid & 127, eh = tid >> 7;
  int l0 = lg*10;
  for (int u = tid; u < 10*64; u += 256){
    int row = u >> 6, c4 = u & 63;
    float4 v; int col;
    if (c4 < 32){ v = *(const float4*)(pose + (l0+row)*128 + c4*4); col = c4*4; }
    else        { v = *(const float4*)(hidden + ((size_t)b*L_ + l0+row)*128 + (c4-32)*4); col = 128 + (c4-32)*4; }
    *(float4*)&x[row][col] = v;
  }
  __syncthreads();
  float acc[10];
#pragma unroll
  for (int l = 0; l < 10; l++) acc[l] = 0.f;
  {
    int e0 = eh*128;
    for (int e = e0; e < e0 + 128; e += 4){
      float wa = w1s[(e+0)*128 + t];
      float wb = w1s[(e+1)*128 + t];
      float wc = w1s[(e+2)*128 + t];
      float wd = w1s[(e+3)*128 + t];
#pragma unroll
      for (int l = 0; l < 10; l++){
        float4 xv = *(const float4*)&x[l][e];
        acc[l] += xv.x*wa; acc[l] += xv.y*wb; acc[l] += xv.z*wc; acc[l] += xv.w*wd;
      }
    }
  }
  if (eh == 1){
#pragma unroll
    for (int i = 0; i < 10; i++) buf[i][t] = acc[i];
  }
  __syncthreads();
  if (eh == 0){
#pragma unroll
    for (int i = 0; i < 10; i++) acc[i] += buf[i][t];
  }
  __syncthreads();
  if (eh == 0){
#pragma unroll
    for (int l = 0; l < 10; l++) x[l][t] = tanhf(acc[l]);
  }
  __syncthreads();
  float acc2[10];
#pragma unroll
  for (int l = 0; l < 10; l++) acc2[l] = 0.f;
  {
    int e0 = eh*64;
    for (int e = e0; e < e0 + 64; e += 4){
      float wa = glu1wT[(e+0)*128 + t];
      float wb = glu1wT[(e+1)*128 + t];
      float wc = glu1wT[(e+2)*128 + t];
      float wd = glu1wT[(e+3)*128 + t];
#pragma unroll
      for (int l = 0; l < 10; l++){
        float4 xv = *(const float4*)&x[l][e];
        acc2[l] += xv.x*wa; acc2[l] += xv.y*wb; acc2[l] += xv.z*wc; acc2[l] += xv.w*wd;
      }
    }
  }
  if (eh == 1){
#pragma unroll
    for (int i = 0; i < 10; i++) buf[i][t] = acc2[i];
  }
  __syncthreads();
  if (eh == 0){
#pragma unroll
    for (int i = 0; i < 10; i++) acc2[i] += buf[i][t];
  }
  __syncthreads();
  if (eh == 0){
    float g2v = g2[(size_t)b*128 + t];
    float g1b = glu1b[t];
    float w2v = w2s[t];
    int lane = tid & 63, wv = tid >> 6;
#pragma unroll
    for (int l = 0; l < 10; l++){
      float ns = sigm_(acc2[l] + g1b + g2v);
      float v = ns * w2v;
      v += __shfl_xor(v, 1, 64);
      v += __shfl_xor(v, 2, 64);
      v += __shfl_xor(v, 4, 64);
      v += __shfl_xor(v, 8, 64);
      v += __shfl_xor(v, 16, 64);
      v += __shfl_xor(v, 32, 64);
      if (lane == 0) bufB[wv][l] = v;
    }
  }
  __syncthreads();
  if (tid < 10)
    betaW[b*L_ + l0 + tid] = (bufB[0][tid] + bufB[1][tid]) * (float)mask[b*L_ + l0 + tid];
}

// ---------------- select = sum_l beta*hidden; norms ----------------
__global__ __launch_bounds__(128) void k_selnorm(
    const float* __restrict__ hidden, const float* __restrict__ betaW,
    float* __restrict__ select, float* __restrict__ norms)
{
  __shared__ float bet[56];
  __shared__ float red[128];
  int b = blockIdx.x, t = threadIdx.x;
  if (t < L_) bet[t] = betaW[b*L_ + t];
  __syncthreads();
  float sel = 0.f;
  for (int l = 0; l < L_; l++) sel += bet[l]*hidden[((size_t)b*L_ + l)*128 + t];
  select[(size_t)b*128 + t] = sel;
  red[t] = sel*sel + 1e-6f;
  __syncthreads();
  for (int off=64; off>=1; off>>=1){ if (t<off) red[t]+=red[t+off]; __syncthreads(); }
  if (t==0) norms[b] = sqrtf(red[0]);
}

// ---------------- cosine softmax + top-9 + neighbor mix (+ loss finalize) ----------
__global__ __launch_bounds__(128) void k_topk(const float* __restrict__ select,
                                              const float* __restrict__ norms,
                                              const float* __restrict__ wsLoss,
                                              short* __restrict__ select2b,
                                              float* __restrict__ out_loss){
  __shared__ float p[B_];
  __shared__ float red[128];
  __shared__ float tv[NBR_];
  __shared__ int   ti[NBR_];
  int b = blockIdx.x, t = threadIdx.x;
  float dot = 0.f;
  for (int d = 0; d < D_; d++) dot += select[(size_t)b*D_ + d]*select[(size_t)t*D_ + d];
  float logit = dot / (norms[b]*norms[t]);
  red[t] = logit; __syncthreads();
  for (int off = 64; off >= 1; off >>= 1){
    if (t < off) red[t] = fmaxf(red[t], red[t + off]);
    __syncthreads();
  }
  float mx = red[0]; __syncthreads();
  float e_ = expf(logit - mx);
  red[t] = e_; __syncthreads();
  for (int off = 64; off >= 1; off >>= 1){
    if (t < off) red[t] += red[t + off];
    __syncthreads();
  }
  p[t] = e_ / red[0];
  __syncthreads();
  if (t == 0){
    unsigned long long used0 = 0ull, used1 = 0ull;
    for (int k = 0; k < NBR_; k++){
      float best = -INFINITY; int bi = 0;
      for (int j = 0; j < B_; j++){
        bool u = (j < 64) ? ((used0 >> j) & 1ull) : ((used1 >> (j-64)) & 1ull);
        if (!u && p[j] > best){ best = p[j]; bi = j; }
      }
      if (bi < 64) used0 |= 1ull << bi; else used1 |= 1ull << (bi-64);
      tv[k] = best; ti[k] = bi;
    }
    float mx2 = -INFINITY;
    for (int k = 0; k < NBR_; k++) mx2 = fmaxf(mx2, tv[k]);
    float s2 = 0.f;
    for (int k = 0; k < NBR_; k++){ tv[k] = expf(tv[k]-mx2); s2 += tv[k]; }
    for (int k = 0; k < NBR_; k++) tv[k] /= s2;
  }
  __syncthreads();
  float nb = 0.f;
#pragma unroll
  for (int k = 0; k < NBR_; k++) nb += tv[k]*select[(size_t)ti[k]*D_ + t];
  select2b[(size_t)b*D_ + t] = f2b(select[(size_t)b*D_ + t] + nb);
  if (b == 0){
    __syncthreads();
    red[t] = wsLoss[t];
    __syncthreads();
    for (int off = 64; off >= 1; off >>= 1){
      if (t < off) red[t] += red[t + off];
      __syncthreads();
    }
    if (t == 0) out_loss[0] = BETA_ * red[0];
  }
}

// ---------------- MFMA scores = sel2 @ emb[1:].T (LDS-staged B) ----------------
__global__ __launch_bounds__(256) void k_scores(
    const short* __restrict__ sel2b, const float* __restrict__ emb,
    float* __restrict__ scores)
{
  __shared__ __align__(16) short Es[64*136];
  const int tid = threadIdx.x;
  const int n0 = blockIdx.x*64;
  for (int it = 0; it < 8; it++){
    int u = it*256 + tid;
    int lr = u >> 5, c = u & 31;
    int n = min(n0 + lr, NSC_ - 1);
    float4 v = *(const float4*)(emb + (size_t)(1 + n)*128 + c*4);
    short4 s4; s4.x=f2b(v.x); s4.y=f2b(v.y); s4.z=f2b(v.z); s4.w=f2b(v.w);
    *(short4*)&Es[lr*136 + c*4] = s4;
  }
  __syncthreads();
  const int lane = tid & 63, wave = tid >> 6;
  const int quad = lane >> 4, l16 = lane & 15;
  int n = n0 + wave*16 + l16;
  f32x4 acc[8];
#pragma unroll
  for (int i=0;i<8;i++) acc[i] = zero4();
  for (int kc = 0; kc < 4; kc++){
    int k = kc*32 + quad*8;
    bf16x8 bb = *(const bf16x8*)&Es[(wave*16 + l16)*136 + k];
#pragma unroll
    for (int rt = 0; rt < 8; rt++){
      bf16x8 a = *(const bf16x8*)&sel2b[(rt*16 + l16)*128 + k];
      acc[rt] = mfma_bf16(a, bb, acc[rt]);
    }
  }
  if (n < NSC_){
#pragma unroll
    for (int rt = 0; rt < 8; rt++)
#pragma unroll
      for (int r = 0; r < 4; r++){
        int brow = rt*16 + quad*4 + r;
        scores[(size_t)brow*NSC_ + n] = acc[rt][r];
      }
  }
}

// ---------------- launcher ----------------
extern "C" void kernel_launch(void* const* d_in, const int* in_sizes, int n_in,
                              void* d_out, int out_size, void* d_ws, size_t ws_size,
                              hipStream_t stream) {
  (void)in_sizes; (void)n_in; (void)out_size; (void)ws_size;
  const int*   inputs  = (const int*)  d_in[0];
  const int*   adj     = (const int*)  d_in[1];
  const int*   mask    = (const int*)  d_in[2];
  const int*   item    = (const int*)  d_in[3];
  const int*   adj_all = (const int*)  d_in[5];
  const float* num_w   = (const float*)d_in[6];
  const float* emb     = (const float*)d_in[7];
  const float* pose    = (const float*)d_in[8];
  const float* a_local = (const float*)d_in[9];
  const float* gw1     = (const float*)d_in[10];
  const float* gw2     = (const float*)d_in[11];
  const float* gw3     = (const float*)d_in[12];
  const float* w1      = (const float*)d_in[13];
  const float* w2      = (const float*)d_in[14];
  const float* glu1w   = (const float*)d_in[15];
  const float* glu1b   = (const float*)d_in[16];
  const float* glu2w   = (const float*)d_in[17];
  float* out = (float*)d_out;

  // workspace layout (float units)
  float* W     = (float*)d_ws;
  float* hl    = W;                    // 819200
  float* hg    = W + 819200;           // 819200
  short* e0pB  = (short*)(W + 1638400);// bf16, 819200 shorts
  short* e1pB  = (short*)(W + 2457600);// bf16, 6553600 shorts
  float* sess  = W + 9011200;          // 16384
  float* g2    = W + 9027584;          // 16384
  float* sel   = W + 9043968;          // 16384
  short* sel2b = (short*)(W + 9060352);// 16384 shorts
  float* norms = W + 9076736;          // 128
  float* wsLoss= W + 9076864;          // 128
  float* n1w   = W + 9076992;          // 51200
  float* n2w   = W + 9128192;          // 409600
  float* betaW = W + 9537792;          // 6400
  float* w1T   = W + 9544192;          // 32768 (2 hops)
  float* glu1wT= W + 9576960;          // 16384
  short* w3Tb  = (short*)(W + 9593344);// 2*128*264 shorts
  int*   n1i   = (int*)(W + 9627136);  // 51200
  int*   n2i   = n1i + 51200;          // 409600

  // d_out scratch (scores region, fully overwritten by k_scores at the end):
  short* embB   = (short*)(out + 819712);
  short* BsessG = (short*)(out + 819712 + 3200000);
  short* hgB    = (short*)(out + 819712 + 3200000 + 2097152);

  k_prep_all<<<3901, 256, 0, stream>>>(emb, item, mask, gw1, gw3, glu1w,
                                       inputs, adj_all, num_w,
                                       embB, w1T, glu1wT, w3Tb, sess,
                                       n1i, n1w, n2i, n2w);
  k_bsess<<<256, 256, 0, stream>>>(w1T, sess, BsessG);
  k_local<<<dim3(2, B_), 256, 0, stream>>>(inputs, embB, adj, a_local, hl);

  // hop0 i0 + i1 attention merged
  k_att2<<<dim3(29, B_), 256, 0, stream>>>(embB, n1i, n1w, n2i, n2w, BsessG,
                                           gw1, gw2, e0pB, e1pB);
  // hop0 i0 + i1 gout merged
  k_gout2<<<900, 256, 0, stream>>>(embB, inputs, n1i, w3Tb, e0pB, e1pB);

  // hop1: A=e1pB dense, self=e0pB dense -> hgB (bf16) -> gout -> hg (f32)
  k_att <<<dim3(4, B_),  256, 0, stream>>>(embB, e1pB, nullptr, n1w,
                                           BsessG + (size_t)128*16384,
                                           gw1 + 129*128, gw2 + 128, hgB, 400);
  k_gout<<<100, 256, 0, stream>>>(embB, e0pB, nullptr, w3Tb + 128*264, hgB, hg, nullptr);

  k_sslhs<<<B_, 128, 0, stream>>>(hl, hg, mask, glu2w, out, wsLoss, g2);
  k_beta10<<<dim3(5, B_), 256, 0, stream>>>(out, mask, pose, w1, w2, glu1wT,
                                            glu1b, g2, betaW);
  k_selnorm<<<B_, 128, 0, stream>>>(out, betaW, sel, norms);
  k_topk<<<B_, 128, 0, stream>>>(sel, norms, wsLoss, sel2b, out + B_*L_*D_);
  k_scores<<<(NSC_ + 63)/64, 256, 0, stream>>>(sel2b, emb, out + B_*L_*D_ + 1);
}

// Round 8
// 450.402 us; speedup vs baseline: 1.2286x; 1.0237x over previous
//
#include <hip/hip_runtime.h>
#include <stdint.h>

// ---------------- constants ----------------
namespace {
constexpr int B_ = 128;
constexpr int L_ = 50;
constexpr int D_ = 128;
constexpr int S_ = 8;
constexpr int NSC_ = 99999;       // NUM_NODE-1
constexpr int NBR_ = 9;
}
#define LEAKY_ 0.2f
#define BETA_ 0.005f

typedef __attribute__((ext_vector_type(8))) __bf16 bf16x8;
typedef __attribute__((ext_vector_type(4))) float f32x4;

__device__ __forceinline__ float leaky_(float x){ return x >= 0.f ? x : LEAKY_*x; }
__device__ __forceinline__ float sigm_(float x){ return 1.f/(1.f+expf(-x)); }

__device__ __forceinline__ short f2b(float f){
  uint32_t u = __float_as_uint(f);
  u += 0x7fffu + ((u >> 16) & 1u);
  return (short)(u >> 16);
}
__device__ __forceinline__ float b2f(short s){
  return __uint_as_float(((uint32_t)(uint16_t)s) << 16);
}
__device__ __forceinline__ f32x4 zero4(){ f32x4 z = {0.f,0.f,0.f,0.f}; return z; }
__device__ __forceinline__ f32x4 mfma_bf16(bf16x8 a, bf16x8 b, f32x4 c){
  return __builtin_amdgcn_mfma_f32_16x16x32_bf16(a, b, c, 0, 0, 0);
}

// ---------------- threefry2x32 (JAX-compatible) ----------------
__device__ __forceinline__ void tf2x32(uint32_t k0, uint32_t k1, uint32_t c0, uint32_t c1,
                                       uint32_t* o0, uint32_t* o1){
  uint32_t ks2 = k0 ^ k1 ^ 0x1BD11BDAu;
  uint32_t x0 = c0 + k0, x1 = c1 + k1;
#define RND_(r) { x0 += x1; x1 = (x1<<(r))|(x1>>(32-(r))); x1 ^= x0; }
  RND_(13) RND_(15) RND_(26) RND_(6)   x0 += k1;  x1 += ks2 + 1u;
  RND_(17) RND_(29) RND_(16) RND_(24)  x0 += ks2; x1 += k0  + 2u;
  RND_(13) RND_(15) RND_(26) RND_(6)   x0 += k0;  x1 += k1  + 3u;
  RND_(17) RND_(29) RND_(16) RND_(24)  x0 += k1;  x1 += ks2 + 4u;
  RND_(13) RND_(15) RND_(26) RND_(6)   x0 += ks2; x1 += k0  + 5u;
#undef RND_
  *o0 = x0; *o1 = x1;
}

// ---------------- fused prep: embB + weight transposes + sampling + Bsess ----------
// blocks 0..3124: embB; 3125..3444: glu1wT/w3T; 3445..3644: sampling; 3645..3900: Bsess
__global__ __launch_bounds__(256) void k_prep_all(
    const float* __restrict__ emb, const int* __restrict__ item,
    const int* __restrict__ mask, const float* __restrict__ gw1,
    const float* __restrict__ gw3, const float* __restrict__ glu1w,
    const int* __restrict__ inputs, const int* __restrict__ adj_all,
    const float* __restrict__ num_w,
    short* __restrict__ embB, float* __restrict__ glu1wT,
    short* __restrict__ w3T,
    int* __restrict__ n1i, float* __restrict__ n1w,
    int* __restrict__ n2i, float* __restrict__ n2w,
    short* __restrict__ Bsess)
{
  int blk = blockIdx.x, tid = threadIdx.x;
  if (blk < 3125){
    size_t base = (size_t)blk*4096 + (size_t)tid*16;
    float4 f0 = *(const float4*)(emb + base);
    float4 f1 = *(const float4*)(emb + base + 4);
    float4 f2 = *(const float4*)(emb + base + 8);
    float4 f3 = *(const float4*)(emb + base + 12);
    short4 s0, s1, s2, s3;
    s0.x=f2b(f0.x); s0.y=f2b(f0.y); s0.z=f2b(f0.z); s0.w=f2b(f0.w);
    s1.x=f2b(f1.x); s1.y=f2b(f1.y); s1.z=f2b(f1.z); s1.w=f2b(f1.w);
    s2.x=f2b(f2.x); s2.y=f2b(f2.y); s2.z=f2b(f2.z); s2.w=f2b(f2.w);
    s3.x=f2b(f3.x); s3.y=f2b(f3.y); s3.z=f2b(f3.z); s3.w=f2b(f3.w);
    *(short4*)(embB + base)      = s0;
    *(short4*)(embB + base + 4)  = s1;
    *(short4*)(embB + base + 8)  = s2;
    *(short4*)(embB + base + 12) = s3;
  } else if (blk < 3445){
    int o = (blk - 3125)*256 + tid;
    if (o < 16384){
      int e = o >> 7, t = o & 127;
      glu1wT[o] = glu1w[t*128 + e];
    } else {
      int o3 = o - 16384;            // < 65536
      int hop = o3 >> 15, r = o3 & 32767;
      int nn = r >> 8, k = r & 255;
      w3T[hop*(128*264) + nn*264 + k] = f2b(gw3[hop*(256*128) + k*128 + nn]);
    }
  } else if (blk < 3645){
    int p = (blk - 3445)*256 + tid;   // p < 51200
    int base = inputs[p >> 3];
    int off  = base*S_ + (p & 7);
    int i1 = adj_all[off];
    n1i[p] = i1;
    n1w[p] = num_w[off];
#pragma unroll
    for (int j = 0; j < 8; j++){
      n2i[(size_t)p*8 + j] = adj_all[i1*8 + j];
      n2w[(size_t)p*8 + j] = num_w[i1*8 + j];
    }
  } else {
    // Bsess: block = 3645 + hop*128 + b
    int i = blk - 3645;
    int hop = i >> 7, b = i & 127;
    __shared__ float sessS[128];
    if (tid < 128){
      float acc = 0.f, ms = 0.f;
      for (int l = 0; l < L_; l++){
        float mk = (float)mask[b*L_ + l];
        ms += mk;
        acc += mk * emb[(size_t)item[b*L_ + l]*D_ + tid];
      }
      sessS[tid] = acc / ms;
    }
    __syncthreads();
    const float* g1 = gw1 + hop*(129*128);
    short* outp = Bsess + ((size_t)hop*128 + b)*16384;
    for (int it = 0; it < 64; it++){
      int u = it*256 + tid;
      int e = u & 127, d = u >> 7;
      outp[u] = f2b(g1[e*128 + d] * sessS[e]);
    }
  }
}

// ---------------- fused: local GAT (blk<256) + att hop0 i0 (256..767) + i1 (768..) --
__global__ __launch_bounds__(256, 4) void k_fused1(
    const short* __restrict__ embB, const int* __restrict__ inputs,
    const int* __restrict__ adj, const float* __restrict__ a_local,
    float* __restrict__ hl,
    const int* __restrict__ n1i, const float* __restrict__ n1w,
    const int* __restrict__ n2i, const float* __restrict__ n2w,
    const short* __restrict__ Bsess,
    const float* __restrict__ w1g, const float* __restrict__ w2g,
    short* __restrict__ e0pB, short* __restrict__ e1pB)
{
  __shared__ __align__(16) short As[128*136];     // 34816 B
  __shared__ float w1lS[128], w2S[128], nwsS[128], logitsS[128], alphaS[128];
  const int blk = blockIdx.x;
  const int tid = threadIdx.x;

  if (blk < 256){
    // ---- local GAT body; LDS carved from As (33312 B <= 34816 B) ----
    float* hs   = (float*)As;                 // L_*129 floats @ 0
    float* attL = (float*)(As + 12900);       // 25*52 floats @ 25800 B
    float* al   = (float*)(As + 15500);       // 4*132 floats @ 31000 B
    int*   idxs = (int*)  (As + 16556);       // L_ ints @ 33112 B
    int b = blk >> 1, half = blk & 1;
    int i0 = half*25;
    if (tid < L_) idxs[tid] = inputs[b*L_ + tid];
    __syncthreads();
    for (int u = tid; u < L_*16; u += 256){
      int i = u >> 4, c = u & 15;
      union { bf16x8 v; short sh[8]; } w;
      w.v = *(const bf16x8*)&embB[(size_t)idxs[i]*128 + c*8];
#pragma unroll
      for (int j = 0; j < 8; j++) hs[i*129 + c*8 + j] = b2f(w.sh[j]);
    }
    for (int e = tid; e < 4*D_; e += 256) al[(e>>7)*132 + (e&127)] = a_local[e];
    __syncthreads();
    for (int p = tid; p < 25*L_; p += 256){
      int il = p / L_, j = p % L_;
      int i = i0 + il;
      int k = adj[((size_t)b*L_ + i)*L_ + j];
      float v = -9e15f;
      if (k >= 1){
        const float* ak = &al[(k-1)*132];
        float acc = 0.f;
        for (int d = 0; d < D_; d++) acc += hs[i*129+d]*hs[j*129+d]*ak[d];
        v = leaky_(acc);
      }
      attL[il*52 + j] = v;
    }
    __syncthreads();
    if (tid < 25){
      int il = tid;
      float mx = -INFINITY;
      for (int j = 0; j < L_; j++) mx = fmaxf(mx, attL[il*52+j]);
      float sm = 0.f;
      for (int j = 0; j < L_; j++){ float e_ = expf(attL[il*52+j] - mx); attL[il*52+j] = e_; sm += e_; }
      float inv = 1.f/sm;
      for (int j = 0; j < L_; j++) attL[il*52+j] *= inv;
    }
    __syncthreads();
    for (int q = tid; q < 25*D_; q += 256){
      int il = q >> 7, d = q & 127;
      float acc = 0.f;
      for (int j = 0; j < L_; j++) acc += attL[il*52+j]*hs[j*129+d];
      hl[((size_t)b*L_ + i0 + il)*D_ + d] = acc;
    }
    return;
  }

  // ---- attention body (identical to R7 k_att2) ----
  int b, r0, rpb;
  const int* nidx; const float* nw; short* outn;
  if (blk < 768){
    int i = blk - 256;
    b = i >> 2; r0 = (i & 3)*128;
    nidx = n1i; nw = n1w; outn = e0pB; rpb = 400;
  } else {
    int i = blk - 768;
    b = i / 25; r0 = (i % 25)*128;
    nidx = n2i; nw = n2w; outn = e1pB; rpb = 3200;
  }
  if (tid < 128){
    w1lS[tid]  = w1g[128*128 + tid];
    w2S[tid]   = w2g[tid];
    int rr = min(r0 + tid, rpb - 1);
    nwsS[tid]  = nw[(size_t)b*rpb + rr];
  }
  for (int it = 0; it < 8; it++){
    int u = it*256 + tid;
    int lr = u >> 4, c = u & 15;
    int rr = min(r0 + lr, rpb - 1);
    const short* src = embB + (size_t)nidx[(size_t)b*rpb + rr]*128;
    *(bf16x8*)&As[lr*136 + c*8] = *(const bf16x8*)&src[c*8];
  }
  __syncthreads();
  const int lane = tid & 63, wave = tid >> 6;
  const int quad = lane >> 4, l16 = lane & 15;
  const int wr0 = wave * 32;
  const short* Bb = Bsess + (size_t)b*16384;
  f32x4 acc[2][8];
#pragma unroll
  for (int i=0;i<2;i++)
#pragma unroll
    for (int j=0;j<8;j++) acc[i][j] = zero4();
  for (int kc = 0; kc < 4; kc++){
    int k = kc*32 + quad*8;
    bf16x8 a0 = *(const bf16x8*)&As[(wr0 + l16)*136 + k];
    bf16x8 a1 = *(const bf16x8*)&As[(wr0 + 16 + l16)*136 + k];
    bf16x8 bb[8];
#pragma unroll
    for (int nt = 0; nt < 8; nt++)
      bb[nt] = *(const bf16x8*)&Bb[(size_t)(nt*16 + l16)*128 + k];
#pragma unroll
    for (int nt = 0; nt < 8; nt++){
      acc[0][nt] = mfma_bf16(a0, bb[nt], acc[0][nt]);
      acc[1][nt] = mfma_bf16(a1, bb[nt], acc[1][nt]);
    }
  }
#pragma unroll
  for (int rt = 0; rt < 2; rt++){
#pragma unroll
    for (int r = 0; r < 4; r++){
      int rowl = wr0 + rt*16 + quad*4 + r;
      float nwv = nwsS[rowl];
      float c = 0.f;
#pragma unroll
      for (int nt = 0; nt < 8; nt++){
        int col = nt*16 + l16;
        float v = acc[rt][nt][r] + nwv * w1lS[col];
        c += leaky_(v) * w2S[col];
      }
      c += __shfl_xor(c, 1, 64);
      c += __shfl_xor(c, 2, 64);
      c += __shfl_xor(c, 4, 64);
      c += __shfl_xor(c, 8, 64);
      if (l16 == 0) logitsS[rowl] = c;
    }
  }
  __syncthreads();
  if (tid < 16){
    float mx = -INFINITY;
    for (int s = 0; s < 8; s++) mx = fmaxf(mx, logitsS[tid*8+s]);
    float sm = 0.f; float ev[8];
    for (int s = 0; s < 8; s++){ ev[s] = expf(logitsS[tid*8+s]-mx); sm += ev[s]; }
    for (int s = 0; s < 8; s++) alphaS[tid*8+s] = ev[s]/sm;
  }
  __syncthreads();
  {
    int mg = tid >> 4;
    int dc = tid & 15;
    float o[8];
#pragma unroll
    for (int j = 0; j < 8; j++) o[j] = 0.f;
#pragma unroll
    for (int s = 0; s < 8; s++){
      float al2 = alphaS[mg*8+s];
      union { bf16x8 v; short sh[8]; } u;
      u.v = *(const bf16x8*)&As[(mg*8+s)*136 + dc*8];
#pragma unroll
      for (int j = 0; j < 8; j++) o[j] += al2 * b2f(u.sh[j]);
    }
    if (r0 + mg*8 < rpb){
      int m = (r0 >> 3) + mg;
      union { short s[8]; bf16x8 v; } pk;
#pragma unroll
      for (int j = 0; j < 8; j++) pk.s[j] = f2b(o[j]);
      *(bf16x8*)(outn + ((size_t)b*(rpb>>3) + m)*128 + dc*8) = pk.v;
    }
  }
}

// ---------------- standalone MFMA att (hop1 dense) ----------------
__global__ __launch_bounds__(256, 4) void k_att(
    const short* __restrict__ embB, const short* __restrict__ denseB,
    const int* __restrict__ nidx, const float* __restrict__ nw,
    const short* __restrict__ Bsess,
    const float* __restrict__ w1g, const float* __restrict__ w2g,
    short* __restrict__ outn, int rpb)
{
  __shared__ __align__(16) short As[128*136];
  __shared__ float w1lS[128], w2S[128], nwsS[128], logitsS[128], alphaS[128];
  const int tid = threadIdx.x;
  const int b = blockIdx.y;
  const int r0 = blockIdx.x * 128;
  if (tid < 128){
    w1lS[tid]  = w1g[128*128 + tid];
    w2S[tid]   = w2g[tid];
    int rr = min(r0 + tid, rpb - 1);
    nwsS[tid]  = nw[(size_t)b*rpb + rr];
  }
  for (int it = 0; it < 8; it++){
    int u = it*256 + tid;
    int lr = u >> 4, c = u & 15;
    int rr = min(r0 + lr, rpb - 1);
    const short* src = denseB ? denseB + ((size_t)b*rpb + rr)*128
                              : embB + (size_t)nidx[(size_t)b*rpb + rr]*128;
    *(bf16x8*)&As[lr*136 + c*8] = *(const bf16x8*)&src[c*8];
  }
  __syncthreads();
  const int lane = tid & 63, wave = tid >> 6;
  const int quad = lane >> 4, l16 = lane & 15;
  const int wr0 = wave * 32;
  const short* Bb = Bsess + (size_t)b*16384;
  f32x4 acc[2][8];
#pragma unroll
  for (int i=0;i<2;i++)
#pragma unroll
    for (int j=0;j<8;j++) acc[i][j] = zero4();
  for (int kc = 0; kc < 4; kc++){
    int k = kc*32 + quad*8;
    bf16x8 a0 = *(const bf16x8*)&As[(wr0 + l16)*136 + k];
    bf16x8 a1 = *(const bf16x8*)&As[(wr0 + 16 + l16)*136 + k];
    bf16x8 bb[8];
#pragma unroll
    for (int nt = 0; nt < 8; nt++)
      bb[nt] = *(const bf16x8*)&Bb[(size_t)(nt*16 + l16)*128 + k];
#pragma unroll
    for (int nt = 0; nt < 8; nt++){
      acc[0][nt] = mfma_bf16(a0, bb[nt], acc[0][nt]);
      acc[1][nt] = mfma_bf16(a1, bb[nt], acc[1][nt]);
    }
  }
#pragma unroll
  for (int rt = 0; rt < 2; rt++){
#pragma unroll
    for (int r = 0; r < 4; r++){
      int rowl = wr0 + rt*16 + quad*4 + r;
      float nwv = nwsS[rowl];
      float c = 0.f;
#pragma unroll
      for (int nt = 0; nt < 8; nt++){
        int col = nt*16 + l16;
        float v = acc[rt][nt][r] + nwv * w1lS[col];
        c += leaky_(v) * w2S[col];
      }
      c += __shfl_xor(c, 1, 64);
      c += __shfl_xor(c, 2, 64);
      c += __shfl_xor(c, 4, 64);
      c += __shfl_xor(c, 8, 64);
      if (l16 == 0) logitsS[rowl] = c;
    }
  }
  __syncthreads();
  if (tid < 16){
    float mx = -INFINITY;
    for (int s = 0; s < 8; s++) mx = fmaxf(mx, logitsS[tid*8+s]);
    float sm = 0.f; float ev[8];
    for (int s = 0; s < 8; s++){ ev[s] = expf(logitsS[tid*8+s]-mx); sm += ev[s]; }
    for (int s = 0; s < 8; s++) alphaS[tid*8+s] = ev[s]/sm;
  }
  __syncthreads();
  {
    int mg = tid >> 4;
    int dc = tid & 15;
    float o[8];
#pragma unroll
    for (int j = 0; j < 8; j++) o[j] = 0.f;
#pragma unroll
    for (int s = 0; s < 8; s++){
      float al = alphaS[mg*8+s];
      union { bf16x8 v; short sh[8]; } u;
      u.v = *(const bf16x8*)&As[(mg*8+s)*136 + dc*8];
#pragma unroll
      for (int j = 0; j < 8; j++) o[j] += al * b2f(u.sh[j]);
    }
    if (r0 + mg*8 < rpb){
      int m = (r0 >> 3) + mg;
      union { short s[8]; bf16x8 v; } pk;
#pragma unroll
      for (int j = 0; j < 8; j++) pk.s[j] = f2b(o[j]);
      *(bf16x8*)(outn + ((size_t)b*(rpb>>3) + m)*128 + dc*8) = pk.v;
    }
  }
}

// ---------------- merged gout hop0 (i0: blk<100, i1: blk>=100), bf16 in-place -------
__global__ __launch_bounds__(256) void k_gout2(
    const short* __restrict__ embB, const int* __restrict__ inputs,
    const int* __restrict__ n1i, const short* __restrict__ w3T,
    short* __restrict__ e0pB, short* __restrict__ e1pB)
{
  const int blk = blockIdx.x;
  const int* self_idx; short* buf; int rblk;
  if (blk < 100){ self_idx = inputs; buf = e0pB; rblk = blk; }
  else          { self_idx = n1i;    buf = e1pB; rblk = blk - 100; }
  const int tid = threadIdx.x;
  const int lane = tid & 63, wave = tid >> 6;
  const int quad = lane >> 4, l16 = lane & 15;
  const int rbase = rblk*64 + wave*16;
  const int row = rbase + l16;
  const short* selfp = embB + (size_t)self_idx[row]*128;
  const short* neighp = buf + (size_t)row*128;
  f32x4 acc[8];
#pragma unroll
  for (int i=0;i<8;i++) acc[i] = zero4();
  for (int kc = 0; kc < 4; kc++){
    int k = kc*32 + quad*8;
    bf16x8 a = *(const bf16x8*)&selfp[k];
#pragma unroll
    for (int nt = 0; nt < 8; nt++){
      bf16x8 bb = *(const bf16x8*)&w3T[(size_t)(nt*16 + l16)*264 + k];
      acc[nt] = mfma_bf16(a, bb, acc[nt]);
    }
  }
  for (int kc = 4; kc < 8; kc++){
    int k = kc*32 + quad*8;
    bf16x8 a = *(const bf16x8*)&neighp[k - 128];
#pragma unroll
    for (int nt = 0; nt < 8; nt++){
      bf16x8 bb = *(const bf16x8*)&w3T[(size_t)(nt*16 + l16)*264 + k];
      acc[nt] = mfma_bf16(a, bb, acc[nt]);
    }
  }
#pragma unroll
  for (int nt = 0; nt < 8; nt++)
#pragma unroll
    for (int r = 0; r < 4; r++){
      int orow = rbase + quad*4 + r;
      buf[(size_t)orow*128 + nt*16 + l16] = f2b(fmaxf(acc[nt][r], 0.f));
    }
}

// ---------------- standalone gout (hop1, f32 out) ----------------
__global__ __launch_bounds__(256) void k_gout(
    const short* __restrict__ embB, const short* __restrict__ selfB,
    const int* __restrict__ self_idx, const short* __restrict__ w3T,
    const short* __restrict__ neighB, float* __restrict__ outF,
    short* __restrict__ outB)
{
  const int tid = threadIdx.x;
  const int lane = tid & 63, wave = tid >> 6;
  const int quad = lane >> 4, l16 = lane & 15;
  const int rbase = blockIdx.x*64 + wave*16;
  const int row = rbase + l16;
  const short* selfp = self_idx ? embB + (size_t)self_idx[row]*128
                                : selfB + (size_t)row*128;
  const short* neighp = neighB + (size_t)row*128;
  f32x4 acc[8];
#pragma unroll
  for (int i=0;i<8;i++) acc[i] = zero4();
  for (int kc = 0; kc < 4; kc++){
    int k = kc*32 + quad*8;
    bf16x8 a = *(const bf16x8*)&selfp[k];
#pragma unroll
    for (int nt = 0; nt < 8; nt++){
      bf16x8 bb = *(const bf16x8*)&w3T[(size_t)(nt*16 + l16)*264 + k];
      acc[nt] = mfma_bf16(a, bb, acc[nt]);
    }
  }
  for (int kc = 4; kc < 8; kc++){
    int k = kc*32 + quad*8;
    bf16x8 a = *(const bf16x8*)&neighp[k - 128];
#pragma unroll
    for (int nt = 0; nt < 8; nt++){
      bf16x8 bb = *(const bf16x8*)&w3T[(size_t)(nt*16 + l16)*264 + k];
      acc[nt] = mfma_bf16(a, bb, acc[nt]);
    }
  }
  if (outF){
#pragma unroll
    for (int nt = 0; nt < 8; nt++)
#pragma unroll
      for (int r = 0; r < 4; r++){
        int orow = rbase + quad*4 + r;
        outF[(size_t)orow*128 + nt*16 + l16] = fmaxf(acc[nt][r], 0.f);
      }
  } else {
#pragma unroll
    for (int nt = 0; nt < 8; nt++)
#pragma unroll
      for (int r = 0; r < 4; r++){
        int orow = rbase + quad*4 + r;
        outB[(size_t)orow*128 + nt*16 + l16] = f2b(fmaxf(acc[nt][r], 0.f));
      }
  }
}

// ---------------- fused: perms + SSL partial + out = hl + hg + hs/g2 ----------------
__global__ __launch_bounds__(128) void k_sslhs(
    const float* __restrict__ hl, const float* __restrict__ hg,
    const int* __restrict__ mask, const float* __restrict__ glu2_w,
    float* __restrict__ out, float* __restrict__ wsLoss,
    float* __restrict__ g2)
{
  __shared__ uint32_t keys[128];
  __shared__ float red[128];
  __shared__ float hss[128];
  __shared__ int pcS[50];
  __shared__ int prbS;
  int b = blockIdx.x, tid = threadIdx.x;
  uint32_t kr0, kr1, kc0, kc1, sk0, sk1, o0, o1;
  tf2x32(0u, 42u, 0u, 0u, &kr0, &kr1);
  tf2x32(0u, 42u, 0u, 1u, &kc0, &kc1);
  tf2x32(kr0, kr1, 0u, 1u, &sk0, &sk1);
  tf2x32(sk0, sk1, 0u, (uint32_t)tid, &o0, &o1);
  keys[tid] = o0 ^ o1;
  __syncthreads();
  {
    uint32_t mk = keys[tid];
    int rank = 0;
    for (int j = 0; j < 128; j++){
      uint32_t kj = keys[j];
      rank += (kj < mk) || (kj == mk && j < tid);
    }
    if (rank == b) prbS = tid;
  }
  __syncthreads();
  tf2x32(kc0, kc1, 0u, 1u, &sk0, &sk1);
  if (tid < 50){
    tf2x32(sk0, sk1, 0u, (uint32_t)tid, &o0, &o1);
    keys[tid] = o0 ^ o1;
  }
  __syncthreads();
  if (tid < 50){
    uint32_t mk = keys[tid];
    int rank = 0;
    for (int j = 0; j < 50; j++){
      uint32_t kj = keys[j];
      rank += (kj < mk) || (kj == mk && j < tid);
    }
    pcS[rank] = tid;
  }
  __syncthreads();
  int prb = prbS, d = tid;
  float pos = 0.f, neg = 0.f, hsacc = 0.f, ms = 0.f;
  for (int l = 0; l < L_; l++){
    size_t off = ((size_t)b*L_ + l)*D_ + d;
    float hlv = hl[off], hgv = hg[off];
    float o = hlv + hgv;
    out[off] = o;
    pos += hlv * hgv;
    neg += hgv * hl[((size_t)prb*L_ + pcS[l])*D_ + d];
    float mk = (float)mask[b*L_ + l];
    ms += mk;
    hsacc += mk * o;
  }
  hss[d] = hsacc / ms;
  red[d] = -logf(1e-8f + sigm_(pos)) - logf(1e-8f + 1.f - sigm_(neg));
  __syncthreads();
  for (int off = 64; off >= 1; off >>= 1){
    if (d < off) red[d] += red[d + off];
    __syncthreads();
  }
  if (d == 0) wsLoss[b] = red[0];
  float g = 0.f;
  for (int e = 0; e < 128; e++) g += hss[e]*glu2_w[d*128 + e];
  g2[(size_t)b*128 + d] = g;
}

// ---------------- beta, 10 l-rows per block ----------------
__global__ __launch_bounds__(256) void k_beta10(
    const float* __restrict__ hidden, const int* __restrict__ mask,
    const float* __restrict__ pose, const float* __restrict__ w1s,
    const float* __restrict__ w2s, const float* __restrict__ glu1wT,
    const float* __restrict__ glu1b, const float* __restrict__ g2,
    float* __restrict__ betaW)
{
  __shared__ float x[10][260];
  __shared__ float buf[10][132];
  __shared__ float bufB[2][16];
  int lg = blockIdx.x, b = blockIdx.y, tid = threadIdx.x;
  int t = tid & 127, eh = tid >> 7;
  int l0 = lg*10;
  for (int u = tid; u < 10*64; u += 256){
    int row = u >> 6, c4 = u & 63;
    float4 v; int col;
    if (c4 < 32){ v = *(const float4*)(pose + (l0+row)*128 + c4*4); col = c4*4; }
    else        { v = *(const float4*)(hidden + ((size_t)b*L_ + l0+row)*128 + (c4-32)*4); col = 128 + (c4-32)*4; }
    *(float4*)&x[row][col] = v;
  }
  __syncthreads();
  float acc[10];
#pragma unroll
  for (int l = 0; l < 10; l++) acc[l] = 0.f;
  {
    int e0 = eh*128;
    for (int e = e0; e < e0 + 128; e += 4){
      float wa = w1s[(e+0)*128 + t];
      float wb = w1s[(e+1)*128 + t];
      float wc = w1s[(e+2)*128 + t];
      float wd = w1s[(e+3)*128 + t];
#pragma unroll
      for (int l = 0; l < 10; l++){
        float4 xv = *(const float4*)&x[l][e];
        acc[l] += xv.x*wa; acc[l] += xv.y*wb; acc[l] += xv.z*wc; acc[l] += xv.w*wd;
      }
    }
  }
  if (eh == 1){
#pragma unroll
    for (int i = 0; i < 10; i++) buf[i][t] = acc[i];
  }
  __syncthreads();
  if (eh == 0){
#pragma unroll
    for (int i = 0; i < 10; i++) acc[i] += buf[i][t];
  }
  __syncthreads();
  if (eh == 0){
#pragma unroll
    for (int l = 0; l < 10; l++) x[l][t] = tanhf(acc[l]);
  }
  __syncthreads();
  float acc2[10];
#pragma unroll
  for (int l = 0; l < 10; l++) acc2[l] = 0.f;
  {
    int e0 = eh*64;
    for (int e = e0; e < e0 + 64; e += 4){
      float wa = glu1wT[(e+0)*128 + t];
      float wb = glu1wT[(e+1)*128 + t];
      float wc = glu1wT[(e+2)*128 + t];
      float wd = glu1wT[(e+3)*128 + t];
#pragma unroll
      for (int l = 0; l < 10; l++){
        float4 xv = *(const float4*)&x[l][e];
        acc2[l] += xv.x*wa; acc2[l] += xv.y*wb; acc2[l] += xv.z*wc; acc2[l] += xv.w*wd;
      }
    }
  }
  if (eh == 1){
#pragma unroll
    for (int i = 0; i < 10; i++) buf[i][t] = acc2[i];
  }
  __syncthreads();
  if (eh == 0){
#pragma unroll
    for (int i = 0; i < 10; i++) acc2[i] += buf[i][t];
  }
  __syncthreads();
  if (eh == 0){
    float g2v = g2[(size_t)b*128 + t];
    float g1b = glu1b[t];
    float w2v = w2s[t];
    int lane = tid & 63, wv = tid >> 6;
#pragma unroll
    for (int l = 0; l < 10; l++){
      float ns = sigm_(acc2[l] + g1b + g2v);
      float v = ns * w2v;
      v += __shfl_xor(v, 1, 64);
      v += __shfl_xor(v, 2, 64);
      v += __shfl_xor(v, 4, 64);
      v += __shfl_xor(v, 8, 64);
      v += __shfl_xor(v, 16, 64);
      v += __shfl_xor(v, 32, 64);
      if (lane == 0) bufB[wv][l] = v;
    }
  }
  __syncthreads();
  if (tid < 10)
    betaW[b*L_ + l0 + tid] = (bufB[0][tid] + bufB[1][tid]) * (float)mask[b*L_ + l0 + tid];
}

// ---------------- select = sum_l beta*hidden; norms ----------------
__global__ __launch_bounds__(128) void k_selnorm(
    const float* __restrict__ hidden, const float* __restrict__ betaW,
    float* __restrict__ select, float* __restrict__ norms)
{
  __shared__ float bet[56];
  __shared__ float red[128];
  int b = blockIdx.x, t = threadIdx.x;
  if (t < L_) bet[t] = betaW[b*L_ + t];
  __syncthreads();
  float sel = 0.f;
  for (int l = 0; l < L_; l++) sel += bet[l]*hidden[((size_t)b*L_ + l)*128 + t];
  select[(size_t)b*128 + t] = sel;
  red[t] = sel*sel + 1e-6f;
  __syncthreads();
  for (int off=64; off>=1; off>>=1){ if (t<off) red[t]+=red[t+off]; __syncthreads(); }
  if (t==0) norms[b] = sqrtf(red[0]);
}

// ---------------- cosine softmax + top-9 + neighbor mix (+ loss finalize) ----------
__global__ __launch_bounds__(128) void k_topk(const float* __restrict__ select,
                                              const float* __restrict__ norms,
                                              const float* __restrict__ wsLoss,
                                              short* __restrict__ select2b,
                                              float* __restrict__ out_loss){
  __shared__ float p[B_];
  __shared__ float red[128];
  __shared__ float tv[NBR_];
  __shared__ int   ti[NBR_];
  int b = blockIdx.x, t = threadIdx.x;
  float dot = 0.f;
  for (int d = 0; d < D_; d++) dot += select[(size_t)b*D_ + d]*select[(size_t)t*D_ + d];
  float logit = dot / (norms[b]*norms[t]);
  red[t] = logit; __syncthreads();
  for (int off = 64; off >= 1; off >>= 1){
    if (t < off) red[t] = fmaxf(red[t], red[t + off]);
    __syncthreads();
  }
  float mx = red[0]; __syncthreads();
  float e_ = expf(logit - mx);
  red[t] = e_; __syncthreads();
  for (int off = 64; off >= 1; off >>= 1){
    if (t < off) red[t] += red[t + off];
    __syncthreads();
  }
  p[t] = e_ / red[0];
  __syncthreads();
  if (t == 0){
    unsigned long long used0 = 0ull, used1 = 0ull;
    for (int k = 0; k < NBR_; k++){
      float best = -INFINITY; int bi = 0;
      for (int j = 0; j < B_; j++){
        bool u = (j < 64) ? ((used0 >> j) & 1ull) : ((used1 >> (j-64)) & 1ull);
        if (!u && p[j] > best){ best = p[j]; bi = j; }
      }
      if (bi < 64) used0 |= 1ull << bi; else used1 |= 1ull << (bi-64);
      tv[k] = best; ti[k] = bi;
    }
    float mx2 = -INFINITY;
    for (int k = 0; k < NBR_; k++) mx2 = fmaxf(mx2, tv[k]);
    float s2 = 0.f;
    for (int k = 0; k < NBR_; k++){ tv[k] = expf(tv[k]-mx2); s2 += tv[k]; }
    for (int k = 0; k < NBR_; k++) tv[k] /= s2;
  }
  __syncthreads();
  float nb = 0.f;
#pragma unroll
  for (int k = 0; k < NBR_; k++) nb += tv[k]*select[(size_t)ti[k]*D_ + t];
  select2b[(size_t)b*D_ + t] = f2b(select[(size_t)b*D_ + t] + nb);
  if (b == 0){
    __syncthreads();
    red[t] = wsLoss[t];
    __syncthreads();
    for (int off = 64; off >= 1; off >>= 1){
      if (t < off) red[t] += red[t + off];
      __syncthreads();
    }
    if (t == 0) out_loss[0] = BETA_ * red[0];
  }
}

// ---------------- MFMA scores = sel2 @ emb[1:].T (LDS-staged B) ----------------
__global__ __launch_bounds__(256) void k_scores(
    const short* __restrict__ sel2b, const float* __restrict__ emb,
    float* __restrict__ scores)
{
  __shared__ __align__(16) short Es[64*136];
  const int tid = threadIdx.x;
  const int n0 = blockIdx.x*64;
  for (int it = 0; it < 8; it++){
    int u = it*256 + tid;
    int lr = u >> 5, c = u & 31;
    int n = min(n0 + lr, NSC_ - 1);
    float4 v = *(const float4*)(emb + (size_t)(1 + n)*128 + c*4);
    short4 s4; s4.x=f2b(v.x); s4.y=f2b(v.y); s4.z=f2b(v.z); s4.w=f2b(v.w);
    *(short4*)&Es[lr*136 + c*4] = s4;
  }
  __syncthreads();
  const int lane = tid & 63, wave = tid >> 6;
  const int quad = lane >> 4, l16 = lane & 15;
  int n = n0 + wave*16 + l16;
  f32x4 acc[8];
#pragma unroll
  for (int i=0;i<8;i++) acc[i] = zero4();
  for (int kc = 0; kc < 4; kc++){
    int k = kc*32 + quad*8;
    bf16x8 bb = *(const bf16x8*)&Es[(wave*16 + l16)*136 + k];
#pragma unroll
    for (int rt = 0; rt < 8; rt++){
      bf16x8 a = *(const bf16x8*)&sel2b[(rt*16 + l16)*128 + k];
      acc[rt] = mfma_bf16(a, bb, acc[rt]);
    }
  }
  if (n < NSC_){
#pragma unroll
    for (int rt = 0; rt < 8; rt++)
#pragma unroll
      for (int r = 0; r < 4; r++){
        int brow = rt*16 + quad*4 + r;
        scores[(size_t)brow*NSC_ + n] = acc[rt][r];
      }
  }
}

// ---------------- launcher ----------------
extern "C" void kernel_launch(void* const* d_in, const int* in_sizes, int n_in,
                              void* d_out, int out_size, void* d_ws, size_t ws_size,
                              hipStream_t stream) {
  (void)in_sizes; (void)n_in; (void)out_size; (void)ws_size;
  const int*   inputs  = (const int*)  d_in[0];
  const int*   adj     = (const int*)  d_in[1];
  const int*   mask    = (const int*)  d_in[2];
  const int*   item    = (const int*)  d_in[3];
  const int*   adj_all = (const int*)  d_in[5];
  const float* num_w   = (const float*)d_in[6];
  const float* emb     = (const float*)d_in[7];
  const float* pose    = (const float*)d_in[8];
  const float* a_local = (const float*)d_in[9];
  const float* gw1     = (const float*)d_in[10];
  const float* gw2     = (const float*)d_in[11];
  const float* gw3     = (const float*)d_in[12];
  const float* w1      = (const float*)d_in[13];
  const float* w2      = (const float*)d_in[14];
  const float* glu1w   = (const float*)d_in[15];
  const float* glu1b   = (const float*)d_in[16];
  const float* glu2w   = (const float*)d_in[17];
  float* out = (float*)d_out;

  // workspace layout (float units)
  float* W     = (float*)d_ws;
  float* hl    = W;                    // 819200
  float* hg    = W + 819200;           // 819200
  short* e0pB  = (short*)(W + 1638400);// bf16, 819200 shorts
  short* e1pB  = (short*)(W + 2457600);// bf16, 6553600 shorts
  float* g2    = W + 9027584;          // 16384
  float* sel   = W + 9043968;          // 16384
  short* sel2b = (short*)(W + 9060352);// 16384 shorts
  float* norms = W + 9076736;          // 128
  float* wsLoss= W + 9076864;          // 128
  float* n1w   = W + 9076992;          // 51200
  float* n2w   = W + 9128192;          // 409600
  float* betaW = W + 9537792;          // 6400
  float* glu1wT= W + 9576960;          // 16384
  short* w3Tb  = (short*)(W + 9593344);// 2*128*264 shorts
  int*   n1i   = (int*)(W + 9627136);  // 51200
  int*   n2i   = n1i + 51200;          // 409600

  // d_out scratch (scores region, fully overwritten by k_scores at the end):
  short* embB   = (short*)(out + 819712);
  short* BsessG = (short*)(out + 819712 + 3200000);
  short* hgB    = (short*)(out + 819712 + 3200000 + 2097152);

  k_prep_all<<<3901, 256, 0, stream>>>(emb, item, mask, gw1, gw3, glu1w,
                                       inputs, adj_all, num_w,
                                       embB, glu1wT, w3Tb,
                                       n1i, n1w, n2i, n2w, BsessG);

  // local + att hop0 i0 + att hop0 i1 in one dispatch
  k_fused1<<<3968, 256, 0, stream>>>(embB, inputs, adj, a_local, hl,
                                     n1i, n1w, n2i, n2w, BsessG,
                                     gw1, gw2, e0pB, e1pB);
  // hop0 i0 + i1 gout merged
  k_gout2<<<900, 256, 0, stream>>>(embB, inputs, n1i, w3Tb, e0pB, e1pB);

  // hop1: A=e1pB dense, self=e0pB dense -> hgB (bf16) -> gout -> hg (f32)
  k_att <<<dim3(4, B_),  256, 0, stream>>>(embB, e1pB, nullptr, n1w,
                                           BsessG + (size_t)128*16384,
                                           gw1 + 129*128, gw2 + 128, hgB, 400);
  k_gout<<<100, 256, 0, stream>>>(embB, e0pB, nullptr, w3Tb + 128*264, hgB, hg, nullptr);

  k_sslhs<<<B_, 128, 0, stream>>>(hl, hg, mask, glu2w, out, wsLoss, g2);
  k_beta10<<<dim3(5, B_), 256, 0, stream>>>(out, mask, pose, w1, w2, glu1wT,
                                            glu1b, g2, betaW);
  k_selnorm<<<B_, 128, 0, stream>>>(out, betaW, sel, norms);
  k_topk<<<B_, 128, 0, stream>>>(sel, norms, wsLoss, sel2b, out + B_*L_*D_);
  k_scores<<<(NSC_ + 63)/64, 256, 0, stream>>>(sel2b, emb, out + B_*L_*D_ + 1);
}

// Round 9
// 443.982 us; speedup vs baseline: 1.2463x; 1.0145x over previous
//
#include <hip/hip_runtime.h>
#include <stdint.h>

// ---------------- constants ----------------
namespace {
constexpr int B_ = 128;
constexpr int L_ = 50;
constexpr int D_ = 128;
constexpr int S_ = 8;
constexpr int NSC_ = 99999;       // NUM_NODE-1
constexpr int NBR_ = 9;
}
#define LEAKY_ 0.2f
#define BETA_ 0.005f

typedef __attribute__((ext_vector_type(8))) __bf16 bf16x8;
typedef __attribute__((ext_vector_type(4))) float f32x4;

__device__ __forceinline__ float leaky_(float x){ return x >= 0.f ? x : LEAKY_*x; }
__device__ __forceinline__ float sigm_(float x){ return 1.f/(1.f+expf(-x)); }

__device__ __forceinline__ short f2b(float f){
  uint32_t u = __float_as_uint(f);
  u += 0x7fffu + ((u >> 16) & 1u);
  return (short)(u >> 16);
}
__device__ __forceinline__ float b2f(short s){
  return __uint_as_float(((uint32_t)(uint16_t)s) << 16);
}
__device__ __forceinline__ f32x4 zero4(){ f32x4 z = {0.f,0.f,0.f,0.f}; return z; }
__device__ __forceinline__ f32x4 mfma_bf16(bf16x8 a, bf16x8 b, f32x4 c){
  return __builtin_amdgcn_mfma_f32_16x16x32_bf16(a, b, c, 0, 0, 0);
}

// ---------------- threefry2x32 (JAX-compatible) ----------------
__device__ __forceinline__ void tf2x32(uint32_t k0, uint32_t k1, uint32_t c0, uint32_t c1,
                                       uint32_t* o0, uint32_t* o1){
  uint32_t ks2 = k0 ^ k1 ^ 0x1BD11BDAu;
  uint32_t x0 = c0 + k0, x1 = c1 + k1;
#define RND_(r) { x0 += x1; x1 = (x1<<(r))|(x1>>(32-(r))); x1 ^= x0; }
  RND_(13) RND_(15) RND_(26) RND_(6)   x0 += k1;  x1 += ks2 + 1u;
  RND_(17) RND_(29) RND_(16) RND_(24)  x0 += ks2; x1 += k0  + 2u;
  RND_(13) RND_(15) RND_(26) RND_(6)   x0 += k0;  x1 += k1  + 3u;
  RND_(17) RND_(29) RND_(16) RND_(24)  x0 += k1;  x1 += ks2 + 4u;
  RND_(13) RND_(15) RND_(26) RND_(6)   x0 += ks2; x1 += k0  + 5u;
#undef RND_
  *o0 = x0; *o1 = x1;
}

// ---------------- fused prep: embB + weight transposes + sampling + Bsess ----------
__global__ __launch_bounds__(256) void k_prep_all(
    const float* __restrict__ emb, const int* __restrict__ item,
    const int* __restrict__ mask, const float* __restrict__ gw1,
    const float* __restrict__ gw3, const float* __restrict__ glu1w,
    const int* __restrict__ inputs, const int* __restrict__ adj_all,
    const float* __restrict__ num_w,
    short* __restrict__ embB, float* __restrict__ glu1wT,
    short* __restrict__ w3T,
    int* __restrict__ n1i, float* __restrict__ n1w,
    int* __restrict__ n2i, float* __restrict__ n2w,
    short* __restrict__ Bsess)
{
  int blk = blockIdx.x, tid = threadIdx.x;
  if (blk < 3125){
    size_t base = (size_t)blk*4096 + (size_t)tid*16;
    float4 f0 = *(const float4*)(emb + base);
    float4 f1 = *(const float4*)(emb + base + 4);
    float4 f2 = *(const float4*)(emb + base + 8);
    float4 f3 = *(const float4*)(emb + base + 12);
    short4 s0, s1, s2, s3;
    s0.x=f2b(f0.x); s0.y=f2b(f0.y); s0.z=f2b(f0.z); s0.w=f2b(f0.w);
    s1.x=f2b(f1.x); s1.y=f2b(f1.y); s1.z=f2b(f1.z); s1.w=f2b(f1.w);
    s2.x=f2b(f2.x); s2.y=f2b(f2.y); s2.z=f2b(f2.z); s2.w=f2b(f2.w);
    s3.x=f2b(f3.x); s3.y=f2b(f3.y); s3.z=f2b(f3.z); s3.w=f2b(f3.w);
    *(short4*)(embB + base)      = s0;
    *(short4*)(embB + base + 4)  = s1;
    *(short4*)(embB + base + 8)  = s2;
    *(short4*)(embB + base + 12) = s3;
  } else if (blk < 3445){
    int o = (blk - 3125)*256 + tid;
    if (o < 16384){
      int e = o >> 7, t = o & 127;
      glu1wT[o] = glu1w[t*128 + e];
    } else {
      int o3 = o - 16384;            // < 65536
      int hop = o3 >> 15, r = o3 & 32767;
      int nn = r >> 8, k = r & 255;
      w3T[hop*(128*264) + nn*264 + k] = f2b(gw3[hop*(256*128) + k*128 + nn]);
    }
  } else if (blk < 3645){
    int p = (blk - 3445)*256 + tid;   // p < 51200
    int base = inputs[p >> 3];
    int off  = base*S_ + (p & 7);
    int i1 = adj_all[off];
    n1i[p] = i1;
    n1w[p] = num_w[off];
#pragma unroll
    for (int j = 0; j < 8; j++){
      n2i[(size_t)p*8 + j] = adj_all[i1*8 + j];
      n2w[(size_t)p*8 + j] = num_w[i1*8 + j];
    }
  } else {
    // Bsess: block = 3645 + hop*128 + b
    int i = blk - 3645;
    int hop = i >> 7, b = i & 127;
    __shared__ float sessS[128];
    if (tid < 128){
      float acc = 0.f, ms = 0.f;
      for (int l = 0; l < L_; l++){
        float mk = (float)mask[b*L_ + l];
        ms += mk;
        acc += mk * emb[(size_t)item[b*L_ + l]*D_ + tid];
      }
      sessS[tid] = acc / ms;
    }
    __syncthreads();
    const float* g1 = gw1 + hop*(129*128);
    short* outp = Bsess + ((size_t)hop*128 + b)*16384;
    for (int it = 0; it < 64; it++){
      int u = it*256 + tid;
      int e = u & 127, d = u >> 7;
      outp[u] = f2b(g1[e*128 + d] * sessS[e]);
    }
  }
}

// ---------------- fused: local GAT (blk<256) + att hop0 i0 (256..767) + i1 (768..) --
__global__ __launch_bounds__(256, 4) void k_fused1(
    const short* __restrict__ embB, const int* __restrict__ inputs,
    const int* __restrict__ adj, const float* __restrict__ a_local,
    float* __restrict__ hl,
    const int* __restrict__ n1i, const float* __restrict__ n1w,
    const int* __restrict__ n2i, const float* __restrict__ n2w,
    const short* __restrict__ Bsess,
    const float* __restrict__ w1g, const float* __restrict__ w2g,
    short* __restrict__ e0pB, short* __restrict__ e1pB)
{
  __shared__ __align__(16) short As[128*136];     // 34816 B
  __shared__ float w1lS[128], w2S[128], nwsS[128], logitsS[128], alphaS[128];
  const int blk = blockIdx.x;
  const int tid = threadIdx.x;

  if (blk < 256){
    float* hs   = (float*)As;                 // L_*129 floats @ 0
    float* attL = (float*)(As + 12900);       // 25*52 floats @ 25800 B
    float* al   = (float*)(As + 15500);       // 4*132 floats @ 31000 B
    int*   idxs = (int*)  (As + 16556);       // L_ ints @ 33112 B
    int b = blk >> 1, half = blk & 1;
    int i0 = half*25;
    if (tid < L_) idxs[tid] = inputs[b*L_ + tid];
    __syncthreads();
    for (int u = tid; u < L_*16; u += 256){
      int i = u >> 4, c = u & 15;
      union { bf16x8 v; short sh[8]; } w;
      w.v = *(const bf16x8*)&embB[(size_t)idxs[i]*128 + c*8];
#pragma unroll
      for (int j = 0; j < 8; j++) hs[i*129 + c*8 + j] = b2f(w.sh[j]);
    }
    for (int e = tid; e < 4*D_; e += 256) al[(e>>7)*132 + (e&127)] = a_local[e];
    __syncthreads();
    for (int p = tid; p < 25*L_; p += 256){
      int il = p / L_, j = p % L_;
      int i = i0 + il;
      int k = adj[((size_t)b*L_ + i)*L_ + j];
      float v = -9e15f;
      if (k >= 1){
        const float* ak = &al[(k-1)*132];
        float acc = 0.f;
        for (int d = 0; d < D_; d++) acc += hs[i*129+d]*hs[j*129+d]*ak[d];
        v = leaky_(acc);
      }
      attL[il*52 + j] = v;
    }
    __syncthreads();
    if (tid < 25){
      int il = tid;
      float mx = -INFINITY;
      for (int j = 0; j < L_; j++) mx = fmaxf(mx, attL[il*52+j]);
      float sm = 0.f;
      for (int j = 0; j < L_; j++){ float e_ = expf(attL[il*52+j] - mx); attL[il*52+j] = e_; sm += e_; }
      float inv = 1.f/sm;
      for (int j = 0; j < L_; j++) attL[il*52+j] *= inv;
    }
    __syncthreads();
    for (int q = tid; q < 25*D_; q += 256){
      int il = q >> 7, d = q & 127;
      float acc = 0.f;
      for (int j = 0; j < L_; j++) acc += attL[il*52+j]*hs[j*129+d];
      hl[((size_t)b*L_ + i0 + il)*D_ + d] = acc;
    }
    return;
  }

  // ---- attention body ----
  int b, r0, rpb;
  const int* nidx; const float* nw; short* outn;
  if (blk < 768){
    int i = blk - 256;
    b = i >> 2; r0 = (i & 3)*128;
    nidx = n1i; nw = n1w; outn = e0pB; rpb = 400;
  } else {
    int i = blk - 768;
    b = i / 25; r0 = (i % 25)*128;
    nidx = n2i; nw = n2w; outn = e1pB; rpb = 3200;
  }
  if (tid < 128){
    w1lS[tid]  = w1g[128*128 + tid];
    w2S[tid]   = w2g[tid];
    int rr = min(r0 + tid, rpb - 1);
    nwsS[tid]  = nw[(size_t)b*rpb + rr];
  }
  for (int it = 0; it < 8; it++){
    int u = it*256 + tid;
    int lr = u >> 4, c = u & 15;
    int rr = min(r0 + lr, rpb - 1);
    const short* src = embB + (size_t)nidx[(size_t)b*rpb + rr]*128;
    *(bf16x8*)&As[lr*136 + c*8] = *(const bf16x8*)&src[c*8];
  }
  __syncthreads();
  const int lane = tid & 63, wave = tid >> 6;
  const int quad = lane >> 4, l16 = lane & 15;
  const int wr0 = wave * 32;
  const short* Bb = Bsess + (size_t)b*16384;
  f32x4 acc[2][8];
#pragma unroll
  for (int i=0;i<2;i++)
#pragma unroll
    for (int j=0;j<8;j++) acc[i][j] = zero4();
  for (int kc = 0; kc < 4; kc++){
    int k = kc*32 + quad*8;
    bf16x8 a0 = *(const bf16x8*)&As[(wr0 + l16)*136 + k];
    bf16x8 a1 = *(const bf16x8*)&As[(wr0 + 16 + l16)*136 + k];
    bf16x8 bb[8];
#pragma unroll
    for (int nt = 0; nt < 8; nt++)
      bb[nt] = *(const bf16x8*)&Bb[(size_t)(nt*16 + l16)*128 + k];
#pragma unroll
    for (int nt = 0; nt < 8; nt++){
      acc[0][nt] = mfma_bf16(a0, bb[nt], acc[0][nt]);
      acc[1][nt] = mfma_bf16(a1, bb[nt], acc[1][nt]);
    }
  }
#pragma unroll
  for (int rt = 0; rt < 2; rt++){
#pragma unroll
    for (int r = 0; r < 4; r++){
      int rowl = wr0 + rt*16 + quad*4 + r;
      float nwv = nwsS[rowl];
      float c = 0.f;
#pragma unroll
      for (int nt = 0; nt < 8; nt++){
        int col = nt*16 + l16;
        float v = acc[rt][nt][r] + nwv * w1lS[col];
        c += leaky_(v) * w2S[col];
      }
      c += __shfl_xor(c, 1, 64);
      c += __shfl_xor(c, 2, 64);
      c += __shfl_xor(c, 4, 64);
      c += __shfl_xor(c, 8, 64);
      if (l16 == 0) logitsS[rowl] = c;
    }
  }
  __syncthreads();
  if (tid < 16){
    float mx = -INFINITY;
    for (int s = 0; s < 8; s++) mx = fmaxf(mx, logitsS[tid*8+s]);
    float sm = 0.f; float ev[8];
    for (int s = 0; s < 8; s++){ ev[s] = expf(logitsS[tid*8+s]-mx); sm += ev[s]; }
    for (int s = 0; s < 8; s++) alphaS[tid*8+s] = ev[s]/sm;
  }
  __syncthreads();
  {
    int mg = tid >> 4;
    int dc = tid & 15;
    float o[8];
#pragma unroll
    for (int j = 0; j < 8; j++) o[j] = 0.f;
#pragma unroll
    for (int s = 0; s < 8; s++){
      float al2 = alphaS[mg*8+s];
      union { bf16x8 v; short sh[8]; } u;
      u.v = *(const bf16x8*)&As[(mg*8+s)*136 + dc*8];
#pragma unroll
      for (int j = 0; j < 8; j++) o[j] += al2 * b2f(u.sh[j]);
    }
    if (r0 + mg*8 < rpb){
      int m = (r0 >> 3) + mg;
      union { short s[8]; bf16x8 v; } pk;
#pragma unroll
      for (int j = 0; j < 8; j++) pk.s[j] = f2b(o[j]);
      *(bf16x8*)(outn + ((size_t)b*(rpb>>3) + m)*128 + dc*8) = pk.v;
    }
  }
}

// ---------------- merged gout hop0 (i0: blk<100, i1: blk>=100), bf16 in-place -------
__global__ __launch_bounds__(256) void k_gout2(
    const short* __restrict__ embB, const int* __restrict__ inputs,
    const int* __restrict__ n1i, const short* __restrict__ w3T,
    short* __restrict__ e0pB, short* __restrict__ e1pB)
{
  const int blk = blockIdx.x;
  const int* self_idx; short* buf; int rblk;
  if (blk < 100){ self_idx = inputs; buf = e0pB; rblk = blk; }
  else          { self_idx = n1i;    buf = e1pB; rblk = blk - 100; }
  const int tid = threadIdx.x;
  const int lane = tid & 63, wave = tid >> 6;
  const int quad = lane >> 4, l16 = lane & 15;
  const int rbase = rblk*64 + wave*16;
  const int row = rbase + l16;
  const short* selfp = embB + (size_t)self_idx[row]*128;
  const short* neighp = buf + (size_t)row*128;
  f32x4 acc[8];
#pragma unroll
  for (int i=0;i<8;i++) acc[i] = zero4();
  for (int kc = 0; kc < 4; kc++){
    int k = kc*32 + quad*8;
    bf16x8 a = *(const bf16x8*)&selfp[k];
#pragma unroll
    for (int nt = 0; nt < 8; nt++){
      bf16x8 bb = *(const bf16x8*)&w3T[(size_t)(nt*16 + l16)*264 + k];
      acc[nt] = mfma_bf16(a, bb, acc[nt]);
    }
  }
  for (int kc = 4; kc < 8; kc++){
    int k = kc*32 + quad*8;
    bf16x8 a = *(const bf16x8*)&neighp[k - 128];
#pragma unroll
    for (int nt = 0; nt < 8; nt++){
      bf16x8 bb = *(const bf16x8*)&w3T[(size_t)(nt*16 + l16)*264 + k];
      acc[nt] = mfma_bf16(a, bb, acc[nt]);
    }
  }
#pragma unroll
  for (int nt = 0; nt < 8; nt++)
#pragma unroll
    for (int r = 0; r < 4; r++){
      int orow = rbase + quad*4 + r;
      buf[(size_t)orow*128 + nt*16 + l16] = f2b(fmaxf(acc[nt][r], 0.f));
    }
}

// ---------------- fused hop1: att (dense A=e1pB) + gout -> hg f32 ----------------
// grid (4, B_). Per block: 128 A-rows -> 16 att rows (LDS GA) -> gout 16 rows.
__global__ __launch_bounds__(256) void k_attg1(
    const short* __restrict__ e1pB, const short* __restrict__ e0pB,
    const float* __restrict__ n1w, const short* __restrict__ Bsess,
    const float* __restrict__ w1g, const float* __restrict__ w2g,
    const short* __restrict__ w3T, float* __restrict__ hg)
{
  __shared__ __align__(16) short As[128*136];   // 34816 B
  __shared__ __align__(16) short GA[16*264];    // 8448 B: cols 0..127 self, 128..255 att
  __shared__ float w1lS[128], w2S[128], nwsS[128], logitsS[128], alphaS[128];
  const int tid = threadIdx.x;
  const int b = blockIdx.y;
  const int r0 = blockIdx.x * 128;
  const int rpb = 400, mpb = 50;
  const int m0 = r0 >> 3;
  if (tid < 128){
    w1lS[tid]  = w1g[128*128 + tid];
    w2S[tid]   = w2g[tid];
    int rr = min(r0 + tid, rpb - 1);
    nwsS[tid]  = n1w[(size_t)b*rpb + rr];
  }
  for (int it = 0; it < 8; it++){
    int u = it*256 + tid;
    int lr = u >> 4, c = u & 15;
    int rr = min(r0 + lr, rpb - 1);
    *(bf16x8*)&As[lr*136 + c*8] =
      *(const bf16x8*)&e1pB[((size_t)b*rpb + rr)*128 + c*8];
  }
  {
    int r = tid >> 4, c = tid & 15;
    int g = b*mpb + min(m0 + r, mpb - 1);
    *(bf16x8*)&GA[r*264 + c*8] = *(const bf16x8*)&e0pB[(size_t)g*128 + c*8];
  }
  __syncthreads();
  const int lane = tid & 63, wave = tid >> 6;
  const int quad = lane >> 4, l16 = lane & 15;
  const int wr0 = wave * 32;
  const short* Bb = Bsess + (size_t)b*16384;
  f32x4 acc[2][8];
#pragma unroll
  for (int i=0;i<2;i++)
#pragma unroll
    for (int j=0;j<8;j++) acc[i][j] = zero4();
  for (int kc = 0; kc < 4; kc++){
    int k = kc*32 + quad*8;
    bf16x8 a0 = *(const bf16x8*)&As[(wr0 + l16)*136 + k];
    bf16x8 a1 = *(const bf16x8*)&As[(wr0 + 16 + l16)*136 + k];
    bf16x8 bb[8];
#pragma unroll
    for (int nt = 0; nt < 8; nt++)
      bb[nt] = *(const bf16x8*)&Bb[(size_t)(nt*16 + l16)*128 + k];
#pragma unroll
    for (int nt = 0; nt < 8; nt++){
      acc[0][nt] = mfma_bf16(a0, bb[nt], acc[0][nt]);
      acc[1][nt] = mfma_bf16(a1, bb[nt], acc[1][nt]);
    }
  }
#pragma unroll
  for (int rt = 0; rt < 2; rt++){
#pragma unroll
    for (int r = 0; r < 4; r++){
      int rowl = wr0 + rt*16 + quad*4 + r;
      float nwv = nwsS[rowl];
      float c = 0.f;
#pragma unroll
      for (int nt = 0; nt < 8; nt++){
        int col = nt*16 + l16;
        float v = acc[rt][nt][r] + nwv * w1lS[col];
        c += leaky_(v) * w2S[col];
      }
      c += __shfl_xor(c, 1, 64);
      c += __shfl_xor(c, 2, 64);
      c += __shfl_xor(c, 4, 64);
      c += __shfl_xor(c, 8, 64);
      if (l16 == 0) logitsS[rowl] = c;
    }
  }
  __syncthreads();
  if (tid < 16){
    float mx = -INFINITY;
    for (int s = 0; s < 8; s++) mx = fmaxf(mx, logitsS[tid*8+s]);
    float sm = 0.f; float ev[8];
    for (int s = 0; s < 8; s++){ ev[s] = expf(logitsS[tid*8+s]-mx); sm += ev[s]; }
    for (int s = 0; s < 8; s++) alphaS[tid*8+s] = ev[s]/sm;
  }
  __syncthreads();
  {
    int mg = tid >> 4;
    int dc = tid & 15;
    float o[8];
#pragma unroll
    for (int j = 0; j < 8; j++) o[j] = 0.f;
#pragma unroll
    for (int s = 0; s < 8; s++){
      float al2 = alphaS[mg*8+s];
      union { bf16x8 v; short sh[8]; } u;
      u.v = *(const bf16x8*)&As[(mg*8+s)*136 + dc*8];
#pragma unroll
      for (int j = 0; j < 8; j++) o[j] += al2 * b2f(u.sh[j]);
    }
    union { short s[8]; bf16x8 v; } pk;
#pragma unroll
    for (int j = 0; j < 8; j++) pk.s[j] = f2b(o[j]);
    *(bf16x8*)&GA[mg*264 + 128 + dc*8] = pk.v;  // junk rows (m>=mpb) discarded below
  }
  __syncthreads();
  // gout: [16 x 256] @ w3T -> [16 x 128]; each wave does 2 col-tiles
  f32x4 gacc[2];
  gacc[0] = zero4(); gacc[1] = zero4();
  for (int kc = 0; kc < 8; kc++){
    int k = kc*32 + quad*8;
    bf16x8 a = *(const bf16x8*)&GA[l16*264 + k];
#pragma unroll
    for (int j = 0; j < 2; j++){
      int nt = wave*2 + j;
      bf16x8 bb = *(const bf16x8*)&w3T[(size_t)(nt*16 + l16)*264 + k];
      gacc[j] = mfma_bf16(a, bb, gacc[j]);
    }
  }
#pragma unroll
  for (int j = 0; j < 2; j++){
    int col = (wave*2 + j)*16 + l16;
#pragma unroll
    for (int r = 0; r < 4; r++){
      int ml = m0 + quad*4 + r;
      if (ml < mpb)
        hg[((size_t)b*mpb + ml)*128 + col] = fmaxf(gacc[j][r], 0.f);
    }
  }
}

// ---------------- fused: perms + SSL partial + out = hl + hg + hs/g2 + zero select --
__global__ __launch_bounds__(128) void k_sslhs(
    const float* __restrict__ hl, const float* __restrict__ hg,
    const int* __restrict__ mask, const float* __restrict__ glu2_w,
    float* __restrict__ out, float* __restrict__ wsLoss,
    float* __restrict__ g2, float* __restrict__ select)
{
  __shared__ uint32_t keys[128];
  __shared__ float red[128];
  __shared__ float hss[128];
  __shared__ int pcS[50];
  __shared__ int prbS;
  int b = blockIdx.x, tid = threadIdx.x;
  select[(size_t)b*128 + tid] = 0.f;
  uint32_t kr0, kr1, kc0, kc1, sk0, sk1, o0, o1;
  tf2x32(0u, 42u, 0u, 0u, &kr0, &kr1);
  tf2x32(0u, 42u, 0u, 1u, &kc0, &kc1);
  tf2x32(kr0, kr1, 0u, 1u, &sk0, &sk1);
  tf2x32(sk0, sk1, 0u, (uint32_t)tid, &o0, &o1);
  keys[tid] = o0 ^ o1;
  __syncthreads();
  {
    uint32_t mk = keys[tid];
    int rank = 0;
    for (int j = 0; j < 128; j++){
      uint32_t kj = keys[j];
      rank += (kj < mk) || (kj == mk && j < tid);
    }
    if (rank == b) prbS = tid;
  }
  __syncthreads();
  tf2x32(kc0, kc1, 0u, 1u, &sk0, &sk1);
  if (tid < 50){
    tf2x32(sk0, sk1, 0u, (uint32_t)tid, &o0, &o1);
    keys[tid] = o0 ^ o1;
  }
  __syncthreads();
  if (tid < 50){
    uint32_t mk = keys[tid];
    int rank = 0;
    for (int j = 0; j < 50; j++){
      uint32_t kj = keys[j];
      rank += (kj < mk) || (kj == mk && j < tid);
    }
    pcS[rank] = tid;
  }
  __syncthreads();
  int prb = prbS, d = tid;
  float pos = 0.f, neg = 0.f, hsacc = 0.f, ms = 0.f;
  for (int l = 0; l < L_; l++){
    size_t off = ((size_t)b*L_ + l)*D_ + d;
    float hlv = hl[off], hgv = hg[off];
    float o = hlv + hgv;
    out[off] = o;
    pos += hlv * hgv;
    neg += hgv * hl[((size_t)prb*L_ + pcS[l])*D_ + d];
    float mk = (float)mask[b*L_ + l];
    ms += mk;
    hsacc += mk * o;
  }
  hss[d] = hsacc / ms;
  red[d] = -logf(1e-8f + sigm_(pos)) - logf(1e-8f + 1.f - sigm_(neg));
  __syncthreads();
  for (int off = 64; off >= 1; off >>= 1){
    if (d < off) red[d] += red[d + off];
    __syncthreads();
  }
  if (d == 0) wsLoss[b] = red[0];
  float g = 0.f;
  for (int e = 0; e < 128; e++) g += hss[e]*glu2_w[d*128 + e];
  g2[(size_t)b*128 + d] = g;
}

// ---------------- beta, 10 l-rows per block; partial select via atomicAdd ----------
__global__ __launch_bounds__(256) void k_beta10(
    const float* __restrict__ hidden, const int* __restrict__ mask,
    const float* __restrict__ pose, const float* __restrict__ w1s,
    const float* __restrict__ w2s, const float* __restrict__ glu1wT,
    const float* __restrict__ glu1b, const float* __restrict__ g2,
    float* __restrict__ select)
{
  __shared__ float x[10][260];
  __shared__ float buf[10][132];
  __shared__ float bufB[2][16];
  __shared__ float bet10[10];
  int lg = blockIdx.x, b = blockIdx.y, tid = threadIdx.x;
  int t = tid & 127, eh = tid >> 7;
  int l0 = lg*10;
  for (int u = tid; u < 10*64; u += 256){
    int row = u >> 6, c4 = u & 63;
    float4 v; int col;
    if (c4 < 32){ v = *(const float4*)(pose + (l0+row)*128 + c4*4); col = c4*4; }
    else        { v = *(const float4*)(hidden + ((size_t)b*L_ + l0+row)*128 + (c4-32)*4); col = 128 + (c4-32)*4; }
    *(float4*)&x[row][col] = v;
  }
  __syncthreads();
  float acc[10];
#pragma unroll
  for (int l = 0; l < 10; l++) acc[l] = 0.f;
  {
    int e0 = eh*128;
    for (int e = e0; e < e0 + 128; e += 4){
      float wa = w1s[(e+0)*128 + t];
      float wb = w1s[(e+1)*128 + t];
      float wc = w1s[(e+2)*128 + t];
      float wd = w1s[(e+3)*128 + t];
#pragma unroll
      for (int l = 0; l < 10; l++){
        float4 xv = *(const float4*)&x[l][e];
        acc[l] += xv.x*wa; acc[l] += xv.y*wb; acc[l] += xv.z*wc; acc[l] += xv.w*wd;
      }
    }
  }
  if (eh == 1){
#pragma unroll
    for (int i = 0; i < 10; i++) buf[i][t] = acc[i];
  }
  __syncthreads();
  if (eh == 0){
#pragma unroll
    for (int i = 0; i < 10; i++) acc[i] += buf[i][t];
  }
  __syncthreads();
  if (eh == 0){
#pragma unroll
    for (int l = 0; l < 10; l++) x[l][t] = tanhf(acc[l]);
  }
  __syncthreads();
  float acc2[10];
#pragma unroll
  for (int l = 0; l < 10; l++) acc2[l] = 0.f;
  {
    int e0 = eh*64;
    for (int e = e0; e < e0 + 64; e += 4){
      float wa = glu1wT[(e+0)*128 + t];
      float wb = glu1wT[(e+1)*128 + t];
      float wc = glu1wT[(e+2)*128 + t];
      float wd = glu1wT[(e+3)*128 + t];
#pragma unroll
      for (int l = 0; l < 10; l++){
        float4 xv = *(const float4*)&x[l][e];
        acc2[l] += xv.x*wa; acc2[l] += xv.y*wb; acc2[l] += xv.z*wc; acc2[l] += xv.w*wd;
      }
    }
  }
  if (eh == 1){
#pragma unroll
    for (int i = 0; i < 10; i++) buf[i][t] = acc2[i];
  }
  __syncthreads();
  if (eh == 0){
#pragma unroll
    for (int i = 0; i < 10; i++) acc2[i] += buf[i][t];
  }
  __syncthreads();
  if (eh == 0){
    float g2v = g2[(size_t)b*128 + t];
    float g1b = glu1b[t];
    float w2v = w2s[t];
    int lane = tid & 63, wv = tid >> 6;
#pragma unroll
    for (int l = 0; l < 10; l++){
      float ns = sigm_(acc2[l] + g1b + g2v);
      float v = ns * w2v;
      v += __shfl_xor(v, 1, 64);
      v += __shfl_xor(v, 2, 64);
      v += __shfl_xor(v, 4, 64);
      v += __shfl_xor(v, 8, 64);
      v += __shfl_xor(v, 16, 64);
      v += __shfl_xor(v, 32, 64);
      if (lane == 0) bufB[wv][l] = v;
    }
  }
  __syncthreads();
  if (tid < 10)
    bet10[tid] = (bufB[0][tid] + bufB[1][tid]) * (float)mask[b*L_ + l0 + tid];
  __syncthreads();
  if (eh == 0){
    float part = 0.f;
#pragma unroll
    for (int i = 0; i < 10; i++) part += bet10[i] * x[i][128 + t];
    atomicAdd(&select[(size_t)b*128 + t], part);
  }
}

// ---------------- cosine softmax + top-9 + neighbor mix (+ norms + loss) ----------
__global__ __launch_bounds__(128) void k_topk(const float* __restrict__ select,
                                              const float* __restrict__ wsLoss,
                                              short* __restrict__ select2b,
                                              float* __restrict__ out_loss){
  __shared__ float p[B_];
  __shared__ float red[128];
  __shared__ float nrm[128];
  __shared__ float tv[NBR_];
  __shared__ int   ti[NBR_];
  int b = blockIdx.x, t = threadIdx.x;
  float dot = 0.f, nsq = 0.f;
  for (int d = 0; d < D_; d++){
    float sv = select[(size_t)t*D_ + d];
    dot += select[(size_t)b*D_ + d]*sv;
    nsq += sv*sv + 1e-6f;
  }
  nrm[t] = sqrtf(nsq);
  __syncthreads();
  float logit = dot / (nrm[b]*nrm[t]);
  red[t] = logit; __syncthreads();
  for (int off = 64; off >= 1; off >>= 1){
    if (t < off) red[t] = fmaxf(red[t], red[t + off]);
    __syncthreads();
  }
  float mx = red[0]; __syncthreads();
  float e_ = expf(logit - mx);
  red[t] = e_; __syncthreads();
  for (int off = 64; off >= 1; off >>= 1){
    if (t < off) red[t] += red[t + off];
    __syncthreads();
  }
  p[t] = e_ / red[0];
  __syncthreads();
  if (t == 0){
    unsigned long long used0 = 0ull, used1 = 0ull;
    for (int k = 0; k < NBR_; k++){
      float best = -INFINITY; int bi = 0;
      for (int j = 0; j < B_; j++){
        bool u = (j < 64) ? ((used0 >> j) & 1ull) : ((used1 >> (j-64)) & 1ull);
        if (!u && p[j] > best){ best = p[j]; bi = j; }
      }
      if (bi < 64) used0 |= 1ull << bi; else used1 |= 1ull << (bi-64);
      tv[k] = best; ti[k] = bi;
    }
    float mx2 = -INFINITY;
    for (int k = 0; k < NBR_; k++) mx2 = fmaxf(mx2, tv[k]);
    float s2 = 0.f;
    for (int k = 0; k < NBR_; k++){ tv[k] = expf(tv[k]-mx2); s2 += tv[k]; }
    for (int k = 0; k < NBR_; k++) tv[k] /= s2;
  }
  __syncthreads();
  float nb = 0.f;
#pragma unroll
  for (int k = 0; k < NBR_; k++) nb += tv[k]*select[(size_t)ti[k]*D_ + t];
  select2b[(size_t)b*D_ + t] = f2b(select[(size_t)b*D_ + t] + nb);
  if (b == 0){
    __syncthreads();
    red[t] = wsLoss[t];
    __syncthreads();
    for (int off = 64; off >= 1; off >>= 1){
      if (t < off) red[t] += red[t + off];
      __syncthreads();
    }
    if (t == 0) out_loss[0] = BETA_ * red[0];
  }
}

// ---------------- MFMA scores = sel2 @ emb[1:].T (LDS-staged B) ----------------
__global__ __launch_bounds__(256) void k_scores(
    const short* __restrict__ sel2b, const float* __restrict__ emb,
    float* __restrict__ scores)
{
  __shared__ __align__(16) short Es[64*136];
  const int tid = threadIdx.x;
  const int n0 = blockIdx.x*64;
  for (int it = 0; it < 8; it++){
    int u = it*256 + tid;
    int lr = u >> 5, c = u & 31;
    int n = min(n0 + lr, NSC_ - 1);
    float4 v = *(const float4*)(emb + (size_t)(1 + n)*128 + c*4);
    short4 s4; s4.x=f2b(v.x); s4.y=f2b(v.y); s4.z=f2b(v.z); s4.w=f2b(v.w);
    *(short4*)&Es[lr*136 + c*4] = s4;
  }
  __syncthreads();
  const int lane = tid & 63, wave = tid >> 6;
  const int quad = lane >> 4, l16 = lane & 15;
  int n = n0 + wave*16 + l16;
  f32x4 acc[8];
#pragma unroll
  for (int i=0;i<8;i++) acc[i] = zero4();
  for (int kc = 0; kc < 4; kc++){
    int k = kc*32 + quad*8;
    bf16x8 bb = *(const bf16x8*)&Es[(wave*16 + l16)*136 + k];
#pragma unroll
    for (int rt = 0; rt < 8; rt++){
      bf16x8 a = *(const bf16x8*)&sel2b[(rt*16 + l16)*128 + k];
      acc[rt] = mfma_bf16(a, bb, acc[rt]);
    }
  }
  if (n < NSC_){
#pragma unroll
    for (int rt = 0; rt < 8; rt++)
#pragma unroll
      for (int r = 0; r < 4; r++){
        int brow = rt*16 + quad*4 + r;
        scores[(size_t)brow*NSC_ + n] = acc[rt][r];
      }
  }
}

// ---------------- launcher ----------------
extern "C" void kernel_launch(void* const* d_in, const int* in_sizes, int n_in,
                              void* d_out, int out_size, void* d_ws, size_t ws_size,
                              hipStream_t stream) {
  (void)in_sizes; (void)n_in; (void)out_size; (void)ws_size;
  const int*   inputs  = (const int*)  d_in[0];
  const int*   adj     = (const int*)  d_in[1];
  const int*   mask    = (const int*)  d_in[2];
  const int*   item    = (const int*)  d_in[3];
  const int*   adj_all = (const int*)  d_in[5];
  const float* num_w   = (const float*)d_in[6];
  const float* emb     = (const float*)d_in[7];
  const float* pose    = (const float*)d_in[8];
  const float* a_local = (const float*)d_in[9];
  const float* gw1     = (const float*)d_in[10];
  const float* gw2     = (const float*)d_in[11];
  const float* gw3     = (const float*)d_in[12];
  const float* w1      = (const float*)d_in[13];
  const float* w2      = (const float*)d_in[14];
  const float* glu1w   = (const float*)d_in[15];
  const float* glu1b   = (const float*)d_in[16];
  const float* glu2w   = (const float*)d_in[17];
  float* out = (float*)d_out;

  // workspace layout (float units)
  float* W     = (float*)d_ws;
  float* hl    = W;                    // 819200
  float* hg    = W + 819200;           // 819200
  short* e0pB  = (short*)(W + 1638400);// bf16, 819200 shorts
  short* e1pB  = (short*)(W + 2457600);// bf16, 6553600 shorts
  float* g2    = W + 9027584;          // 16384
  float* sel   = W + 9043968;          // 16384
  short* sel2b = (short*)(W + 9060352);// 16384 shorts
  float* wsLoss= W + 9076864;          // 128
  float* n1w   = W + 9076992;          // 51200
  float* n2w   = W + 9128192;          // 409600
  float* glu1wT= W + 9576960;          // 16384
  short* w3Tb  = (short*)(W + 9593344);// 2*128*264 shorts
  int*   n1i   = (int*)(W + 9627136);  // 51200
  int*   n2i   = n1i + 51200;          // 409600

  // d_out scratch (scores region, fully overwritten by k_scores at the end):
  short* embB   = (short*)(out + 819712);
  short* BsessG = (short*)(out + 819712 + 3200000);

  k_prep_all<<<3901, 256, 0, stream>>>(emb, item, mask, gw1, gw3, glu1w,
                                       inputs, adj_all, num_w,
                                       embB, glu1wT, w3Tb,
                                       n1i, n1w, n2i, n2w, BsessG);

  // local + att hop0 i0 + att hop0 i1 in one dispatch
  k_fused1<<<3968, 256, 0, stream>>>(embB, inputs, adj, a_local, hl,
                                     n1i, n1w, n2i, n2w, BsessG,
                                     gw1, gw2, e0pB, e1pB);
  // hop0 i0 + i1 gout merged
  k_gout2<<<900, 256, 0, stream>>>(embB, inputs, n1i, w3Tb, e0pB, e1pB);

  // hop1 fused att+gout -> hg
  k_attg1<<<dim3(4, B_), 256, 0, stream>>>(e1pB, e0pB, n1w,
                                           BsessG + (size_t)128*16384,
                                           gw1 + 129*128, gw2 + 128,
                                           w3Tb + 128*264, hg);

  k_sslhs<<<B_, 128, 0, stream>>>(hl, hg, mask, glu2w, out, wsLoss, g2, sel);
  k_beta10<<<dim3(5, B_), 256, 0, stream>>>(out, mask, pose, w1, w2, glu1wT,
                                            glu1b, g2, sel);
  k_topk<<<B_, 128, 0, stream>>>(sel, wsLoss, sel2b, out + B_*L_*D_);
  k_scores<<<(NSC_ + 63)/64, 256, 0, stream>>>(sel2b, emb, out + B_*L_*D_ + 1);
}

// Round 10
// 387.201 us; speedup vs baseline: 1.4291x; 1.1466x over previous
//
#include <hip/hip_runtime.h>
#include <stdint.h>

// ---------------- constants ----------------
namespace {
constexpr int B_ = 128;
constexpr int L_ = 50;
constexpr int D_ = 128;
constexpr int S_ = 8;
constexpr int NSC_ = 99999;       // NUM_NODE-1
constexpr int NBR_ = 9;
}
#define LEAKY_ 0.2f
#define BETA_ 0.005f

typedef __attribute__((ext_vector_type(8))) __bf16 bf16x8;
typedef __attribute__((ext_vector_type(4))) float f32x4;

__device__ __forceinline__ float leaky_(float x){ return x >= 0.f ? x : LEAKY_*x; }
__device__ __forceinline__ float sigm_(float x){ return 1.f/(1.f+expf(-x)); }

__device__ __forceinline__ short f2b(float f){
  uint32_t u = __float_as_uint(f);
  u += 0x7fffu + ((u >> 16) & 1u);
  return (short)(u >> 16);
}
__device__ __forceinline__ float b2f(short s){
  return __uint_as_float(((uint32_t)(uint16_t)s) << 16);
}
__device__ __forceinline__ f32x4 zero4(){ f32x4 z = {0.f,0.f,0.f,0.f}; return z; }
__device__ __forceinline__ f32x4 mfma_bf16(bf16x8 a, bf16x8 b, f32x4 c){
  return __builtin_amdgcn_mfma_f32_16x16x32_bf16(a, b, c, 0, 0, 0);
}

// ---------------- threefry2x32 (JAX-compatible) ----------------
__device__ __forceinline__ void tf2x32(uint32_t k0, uint32_t k1, uint32_t c0, uint32_t c1,
                                       uint32_t* o0, uint32_t* o1){
  uint32_t ks2 = k0 ^ k1 ^ 0x1BD11BDAu;
  uint32_t x0 = c0 + k0, x1 = c1 + k1;
#define RND_(r) { x0 += x1; x1 = (x1<<(r))|(x1>>(32-(r))); x1 ^= x0; }
  RND_(13) RND_(15) RND_(26) RND_(6)   x0 += k1;  x1 += ks2 + 1u;
  RND_(17) RND_(29) RND_(16) RND_(24)  x0 += ks2; x1 += k0  + 2u;
  RND_(13) RND_(15) RND_(26) RND_(6)   x0 += k0;  x1 += k1  + 3u;
  RND_(17) RND_(29) RND_(16) RND_(24)  x0 += k1;  x1 += ks2 + 4u;
  RND_(13) RND_(15) RND_(26) RND_(6)   x0 += ks2; x1 += k0  + 5u;
#undef RND_
  *o0 = x0; *o1 = x1;
}

// ---------------- fused prep: embB + weight transposes + sampling + Bsess ----------
__global__ __launch_bounds__(256) void k_prep_all(
    const float* __restrict__ emb, const int* __restrict__ item,
    const int* __restrict__ mask, const float* __restrict__ gw1,
    const float* __restrict__ gw3, const float* __restrict__ glu1w,
    const int* __restrict__ inputs, const int* __restrict__ adj_all,
    const float* __restrict__ num_w,
    short* __restrict__ embB, float* __restrict__ glu1wT,
    short* __restrict__ w3T,
    int* __restrict__ n1i, float* __restrict__ n1w,
    int* __restrict__ n2i, float* __restrict__ n2w,
    short* __restrict__ Bsess)
{
  int blk = blockIdx.x, tid = threadIdx.x;
  if (blk < 3125){
    size_t base = (size_t)blk*4096 + (size_t)tid*16;
    float4 f0 = *(const float4*)(emb + base);
    float4 f1 = *(const float4*)(emb + base + 4);
    float4 f2 = *(const float4*)(emb + base + 8);
    float4 f3 = *(const float4*)(emb + base + 12);
    short4 s0, s1, s2, s3;
    s0.x=f2b(f0.x); s0.y=f2b(f0.y); s0.z=f2b(f0.z); s0.w=f2b(f0.w);
    s1.x=f2b(f1.x); s1.y=f2b(f1.y); s1.z=f2b(f1.z); s1.w=f2b(f1.w);
    s2.x=f2b(f2.x); s2.y=f2b(f2.y); s2.z=f2b(f2.z); s2.w=f2b(f2.w);
    s3.x=f2b(f3.x); s3.y=f2b(f3.y); s3.z=f2b(f3.z); s3.w=f2b(f3.w);
    *(short4*)(embB + base)      = s0;
    *(short4*)(embB + base + 4)  = s1;
    *(short4*)(embB + base + 8)  = s2;
    *(short4*)(embB + base + 12) = s3;
  } else if (blk < 3445){
    int o = (blk - 3125)*256 + tid;
    if (o < 16384){
      int e = o >> 7, t = o & 127;
      glu1wT[o] = glu1w[t*128 + e];
    } else {
      int o3 = o - 16384;            // < 65536
      int hop = o3 >> 15, r = o3 & 32767;
      int nn = r >> 8, k = r & 255;
      w3T[hop*(128*264) + nn*264 + k] = f2b(gw3[hop*(256*128) + k*128 + nn]);
    }
  } else if (blk < 3645){
    int p = (blk - 3445)*256 + tid;   // p < 51200
    int base = inputs[p >> 3];
    int off  = base*S_ + (p & 7);
    int i1 = adj_all[off];
    n1i[p] = i1;
    n1w[p] = num_w[off];
#pragma unroll
    for (int j = 0; j < 8; j++){
      n2i[(size_t)p*8 + j] = adj_all[i1*8 + j];
      n2w[(size_t)p*8 + j] = num_w[i1*8 + j];
    }
  } else {
    // Bsess: block = 3645 + hop*128 + b
    int i = blk - 3645;
    int hop = i >> 7, b = i & 127;
    __shared__ float sessS[128];
    if (tid < 128){
      float acc = 0.f, ms = 0.f;
      for (int l = 0; l < L_; l++){
        float mk = (float)mask[b*L_ + l];
        ms += mk;
        acc += mk * emb[(size_t)item[b*L_ + l]*D_ + tid];
      }
      sessS[tid] = acc / ms;
    }
    __syncthreads();
    const float* g1 = gw1 + hop*(129*128);
    short* outp = Bsess + ((size_t)hop*128 + b)*16384;
    for (int it = 0; it < 64; it++){
      int u = it*256 + tid;
      int e = u & 127, d = u >> 7;
      outp[u] = f2b(g1[e*128 + d] * sessS[e]);
    }
  }
}

// ---------------- fused: local GAT (blk<256) + att hop0 i0 (256..767) + i1 (768..) --
__global__ __launch_bounds__(256, 4) void k_fused1(
    const short* __restrict__ embB, const int* __restrict__ inputs,
    const int* __restrict__ adj, const float* __restrict__ a_local,
    float* __restrict__ hl,
    const int* __restrict__ n1i, const float* __restrict__ n1w,
    const int* __restrict__ n2i, const float* __restrict__ n2w,
    const short* __restrict__ Bsess,
    const float* __restrict__ w1g, const float* __restrict__ w2g,
    short* __restrict__ e0pB, short* __restrict__ e1pB)
{
  __shared__ __align__(16) short As[128*136];     // 34816 B
  __shared__ float w1lS[128], w2S[128], nwsS[128], logitsS[128], alphaS[128];
  const int blk = blockIdx.x;
  const int tid = threadIdx.x;

  if (blk < 256){
    float* hs   = (float*)As;                 // L_*129 floats @ 0
    float* attL = (float*)(As + 12900);       // 25*52 floats @ 25800 B
    float* al   = (float*)(As + 15500);       // 4*132 floats @ 31000 B
    int*   idxs = (int*)  (As + 16556);       // L_ ints @ 33112 B
    int b = blk >> 1, half = blk & 1;
    int i0 = half*25;
    if (tid < L_) idxs[tid] = inputs[b*L_ + tid];
    __syncthreads();
    for (int u = tid; u < L_*16; u += 256){
      int i = u >> 4, c = u & 15;
      union { bf16x8 v; short sh[8]; } w;
      w.v = *(const bf16x8*)&embB[(size_t)idxs[i]*128 + c*8];
#pragma unroll
      for (int j = 0; j < 8; j++) hs[i*129 + c*8 + j] = b2f(w.sh[j]);
    }
    for (int e = tid; e < 4*D_; e += 256) al[(e>>7)*132 + (e&127)] = a_local[e];
    __syncthreads();
    for (int p = tid; p < 25*L_; p += 256){
      int il = p / L_, j = p % L_;
      int i = i0 + il;
      int k = adj[((size_t)b*L_ + i)*L_ + j];
      float v = -9e15f;
      if (k >= 1){
        const float* ak = &al[(k-1)*132];
        float acc = 0.f;
        for (int d = 0; d < D_; d++) acc += hs[i*129+d]*hs[j*129+d]*ak[d];
        v = leaky_(acc);
      }
      attL[il*52 + j] = v;
    }
    __syncthreads();
    if (tid < 25){
      int il = tid;
      float mx = -INFINITY;
      for (int j = 0; j < L_; j++) mx = fmaxf(mx, attL[il*52+j]);
      float sm = 0.f;
      for (int j = 0; j < L_; j++){ float e_ = expf(attL[il*52+j] - mx); attL[il*52+j] = e_; sm += e_; }
      float inv = 1.f/sm;
      for (int j = 0; j < L_; j++) attL[il*52+j] *= inv;
    }
    __syncthreads();
    for (int q = tid; q < 25*D_; q += 256){
      int il = q >> 7, d = q & 127;
      float acc = 0.f;
      for (int j = 0; j < L_; j++) acc += attL[il*52+j]*hs[j*129+d];
      hl[((size_t)b*L_ + i0 + il)*D_ + d] = acc;
    }
    return;
  }

  // ---- attention body ----
  int b, r0, rpb;
  const int* nidx; const float* nw; short* outn;
  if (blk < 768){
    int i = blk - 256;
    b = i >> 2; r0 = (i & 3)*128;
    nidx = n1i; nw = n1w; outn = e0pB; rpb = 400;
  } else {
    int i = blk - 768;
    b = i / 25; r0 = (i % 25)*128;
    nidx = n2i; nw = n2w; outn = e1pB; rpb = 3200;
  }
  if (tid < 128){
    w1lS[tid]  = w1g[128*128 + tid];
    w2S[tid]   = w2g[tid];
    int rr = min(r0 + tid, rpb - 1);
    nwsS[tid]  = nw[(size_t)b*rpb + rr];
  }
  for (int it = 0; it < 8; it++){
    int u = it*256 + tid;
    int lr = u >> 4, c = u & 15;
    int rr = min(r0 + lr, rpb - 1);
    const short* src = embB + (size_t)nidx[(size_t)b*rpb + rr]*128;
    *(bf16x8*)&As[lr*136 + c*8] = *(const bf16x8*)&src[c*8];
  }
  __syncthreads();
  const int lane = tid & 63, wave = tid >> 6;
  const int quad = lane >> 4, l16 = lane & 15;
  const int wr0 = wave * 32;
  const short* Bb = Bsess + (size_t)b*16384;
  f32x4 acc[2][8];
#pragma unroll
  for (int i=0;i<2;i++)
#pragma unroll
    for (int j=0;j<8;j++) acc[i][j] = zero4();
  for (int kc = 0; kc < 4; kc++){
    int k = kc*32 + quad*8;
    bf16x8 a0 = *(const bf16x8*)&As[(wr0 + l16)*136 + k];
    bf16x8 a1 = *(const bf16x8*)&As[(wr0 + 16 + l16)*136 + k];
    bf16x8 bb[8];
#pragma unroll
    for (int nt = 0; nt < 8; nt++)
      bb[nt] = *(const bf16x8*)&Bb[(size_t)(nt*16 + l16)*128 + k];
#pragma unroll
    for (int nt = 0; nt < 8; nt++){
      acc[0][nt] = mfma_bf16(a0, bb[nt], acc[0][nt]);
      acc[1][nt] = mfma_bf16(a1, bb[nt], acc[1][nt]);
    }
  }
#pragma unroll
  for (int rt = 0; rt < 2; rt++){
#pragma unroll
    for (int r = 0; r < 4; r++){
      int rowl = wr0 + rt*16 + quad*4 + r;
      float nwv = nwsS[rowl];
      float c = 0.f;
#pragma unroll
      for (int nt = 0; nt < 8; nt++){
        int col = nt*16 + l16;
        float v = acc[rt][nt][r] + nwv * w1lS[col];
        c += leaky_(v) * w2S[col];
      }
      c += __shfl_xor(c, 1, 64);
      c += __shfl_xor(c, 2, 64);
      c += __shfl_xor(c, 4, 64);
      c += __shfl_xor(c, 8, 64);
      if (l16 == 0) logitsS[rowl] = c;
    }
  }
  __syncthreads();
  if (tid < 16){
    float mx = -INFINITY;
    for (int s = 0; s < 8; s++) mx = fmaxf(mx, logitsS[tid*8+s]);
    float sm = 0.f; float ev[8];
    for (int s = 0; s < 8; s++){ ev[s] = expf(logitsS[tid*8+s]-mx); sm += ev[s]; }
    for (int s = 0; s < 8; s++) alphaS[tid*8+s] = ev[s]/sm;
  }
  __syncthreads();
  {
    int mg = tid >> 4;
    int dc = tid & 15;
    float o[8];
#pragma unroll
    for (int j = 0; j < 8; j++) o[j] = 0.f;
#pragma unroll
    for (int s = 0; s < 8; s++){
      float al2 = alphaS[mg*8+s];
      union { bf16x8 v; short sh[8]; } u;
      u.v = *(const bf16x8*)&As[(mg*8+s)*136 + dc*8];
#pragma unroll
      for (int j = 0; j < 8; j++) o[j] += al2 * b2f(u.sh[j]);
    }
    if (r0 + mg*8 < rpb){
      int m = (r0 >> 3) + mg;
      union { short s[8]; bf16x8 v; } pk;
#pragma unroll
      for (int j = 0; j < 8; j++) pk.s[j] = f2b(o[j]);
      *(bf16x8*)(outn + ((size_t)b*(rpb>>3) + m)*128 + dc*8) = pk.v;
    }
  }
}

// ---------------- merged gout hop0 (i0: blk<100, i1: blk>=100), bf16 in-place -------
__global__ __launch_bounds__(256) void k_gout2(
    const short* __restrict__ embB, const int* __restrict__ inputs,
    const int* __restrict__ n1i, const short* __restrict__ w3T,
    short* __restrict__ e0pB, short* __restrict__ e1pB)
{
  const int blk = blockIdx.x;
  const int* self_idx; short* buf; int rblk;
  if (blk < 100){ self_idx = inputs; buf = e0pB; rblk = blk; }
  else          { self_idx = n1i;    buf = e1pB; rblk = blk - 100; }
  const int tid = threadIdx.x;
  const int lane = tid & 63, wave = tid >> 6;
  const int quad = lane >> 4, l16 = lane & 15;
  const int rbase = rblk*64 + wave*16;
  const int row = rbase + l16;
  const short* selfp = embB + (size_t)self_idx[row]*128;
  const short* neighp = buf + (size_t)row*128;
  f32x4 acc[8];
#pragma unroll
  for (int i=0;i<8;i++) acc[i] = zero4();
  for (int kc = 0; kc < 4; kc++){
    int k = kc*32 + quad*8;
    bf16x8 a = *(const bf16x8*)&selfp[k];
#pragma unroll
    for (int nt = 0; nt < 8; nt++){
      bf16x8 bb = *(const bf16x8*)&w3T[(size_t)(nt*16 + l16)*264 + k];
      acc[nt] = mfma_bf16(a, bb, acc[nt]);
    }
  }
  for (int kc = 4; kc < 8; kc++){
    int k = kc*32 + quad*8;
    bf16x8 a = *(const bf16x8*)&neighp[k - 128];
#pragma unroll
    for (int nt = 0; nt < 8; nt++){
      bf16x8 bb = *(const bf16x8*)&w3T[(size_t)(nt*16 + l16)*264 + k];
      acc[nt] = mfma_bf16(a, bb, acc[nt]);
    }
  }
#pragma unroll
  for (int nt = 0; nt < 8; nt++)
#pragma unroll
    for (int r = 0; r < 4; r++){
      int orow = rbase + quad*4 + r;
      buf[(size_t)orow*128 + nt*16 + l16] = f2b(fmaxf(acc[nt][r], 0.f));
    }
}

// ---------------- fused hop1: att (dense A=e1pB) + gout -> hg f32 ----------------
__global__ __launch_bounds__(256) void k_attg1(
    const short* __restrict__ e1pB, const short* __restrict__ e0pB,
    const float* __restrict__ n1w, const short* __restrict__ Bsess,
    const float* __restrict__ w1g, const float* __restrict__ w2g,
    const short* __restrict__ w3T, float* __restrict__ hg)
{
  __shared__ __align__(16) short As[128*136];   // 34816 B
  __shared__ __align__(16) short GA[16*264];    // 8448 B
  __shared__ float w1lS[128], w2S[128], nwsS[128], logitsS[128], alphaS[128];
  const int tid = threadIdx.x;
  const int b = blockIdx.y;
  const int r0 = blockIdx.x * 128;
  const int rpb = 400, mpb = 50;
  const int m0 = r0 >> 3;
  if (tid < 128){
    w1lS[tid]  = w1g[128*128 + tid];
    w2S[tid]   = w2g[tid];
    int rr = min(r0 + tid, rpb - 1);
    nwsS[tid]  = n1w[(size_t)b*rpb + rr];
  }
  for (int it = 0; it < 8; it++){
    int u = it*256 + tid;
    int lr = u >> 4, c = u & 15;
    int rr = min(r0 + lr, rpb - 1);
    *(bf16x8*)&As[lr*136 + c*8] =
      *(const bf16x8*)&e1pB[((size_t)b*rpb + rr)*128 + c*8];
  }
  {
    int r = tid >> 4, c = tid & 15;
    int g = b*mpb + min(m0 + r, mpb - 1);
    *(bf16x8*)&GA[r*264 + c*8] = *(const bf16x8*)&e0pB[(size_t)g*128 + c*8];
  }
  __syncthreads();
  const int lane = tid & 63, wave = tid >> 6;
  const int quad = lane >> 4, l16 = lane & 15;
  const int wr0 = wave * 32;
  const short* Bb = Bsess + (size_t)b*16384;
  f32x4 acc[2][8];
#pragma unroll
  for (int i=0;i<2;i++)
#pragma unroll
    for (int j=0;j<8;j++) acc[i][j] = zero4();
  for (int kc = 0; kc < 4; kc++){
    int k = kc*32 + quad*8;
    bf16x8 a0 = *(const bf16x8*)&As[(wr0 + l16)*136 + k];
    bf16x8 a1 = *(const bf16x8*)&As[(wr0 + 16 + l16)*136 + k];
    bf16x8 bb[8];
#pragma unroll
    for (int nt = 0; nt < 8; nt++)
      bb[nt] = *(const bf16x8*)&Bb[(size_t)(nt*16 + l16)*128 + k];
#pragma unroll
    for (int nt = 0; nt < 8; nt++){
      acc[0][nt] = mfma_bf16(a0, bb[nt], acc[0][nt]);
      acc[1][nt] = mfma_bf16(a1, bb[nt], acc[1][nt]);
    }
  }
#pragma unroll
  for (int rt = 0; rt < 2; rt++){
#pragma unroll
    for (int r = 0; r < 4; r++){
      int rowl = wr0 + rt*16 + quad*4 + r;
      float nwv = nwsS[rowl];
      float c = 0.f;
#pragma unroll
      for (int nt = 0; nt < 8; nt++){
        int col = nt*16 + l16;
        float v = acc[rt][nt][r] + nwv * w1lS[col];
        c += leaky_(v) * w2S[col];
      }
      c += __shfl_xor(c, 1, 64);
      c += __shfl_xor(c, 2, 64);
      c += __shfl_xor(c, 4, 64);
      c += __shfl_xor(c, 8, 64);
      if (l16 == 0) logitsS[rowl] = c;
    }
  }
  __syncthreads();
  if (tid < 16){
    float mx = -INFINITY;
    for (int s = 0; s < 8; s++) mx = fmaxf(mx, logitsS[tid*8+s]);
    float sm = 0.f; float ev[8];
    for (int s = 0; s < 8; s++){ ev[s] = expf(logitsS[tid*8+s]-mx); sm += ev[s]; }
    for (int s = 0; s < 8; s++) alphaS[tid*8+s] = ev[s]/sm;
  }
  __syncthreads();
  {
    int mg = tid >> 4;
    int dc = tid & 15;
    float o[8];
#pragma unroll
    for (int j = 0; j < 8; j++) o[j] = 0.f;
#pragma unroll
    for (int s = 0; s < 8; s++){
      float al2 = alphaS[mg*8+s];
      union { bf16x8 v; short sh[8]; } u;
      u.v = *(const bf16x8*)&As[(mg*8+s)*136 + dc*8];
#pragma unroll
      for (int j = 0; j < 8; j++) o[j] += al2 * b2f(u.sh[j]);
    }
    union { short s[8]; bf16x8 v; } pk;
#pragma unroll
    for (int j = 0; j < 8; j++) pk.s[j] = f2b(o[j]);
    *(bf16x8*)&GA[mg*264 + 128 + dc*8] = pk.v;  // junk rows (m>=mpb) discarded below
  }
  __syncthreads();
  // gout: [16 x 256] @ w3T -> [16 x 128]; each wave does 2 col-tiles
  f32x4 gacc[2];
  gacc[0] = zero4(); gacc[1] = zero4();
  for (int kc = 0; kc < 8; kc++){
    int k = kc*32 + quad*8;
    bf16x8 a = *(const bf16x8*)&GA[l16*264 + k];
#pragma unroll
    for (int j = 0; j < 2; j++){
      int nt = wave*2 + j;
      bf16x8 bb = *(const bf16x8*)&w3T[(size_t)(nt*16 + l16)*264 + k];
      gacc[j] = mfma_bf16(a, bb, gacc[j]);
    }
  }
#pragma unroll
  for (int j = 0; j < 2; j++){
    int col = (wave*2 + j)*16 + l16;
#pragma unroll
    for (int r = 0; r < 4; r++){
      int ml = m0 + quad*4 + r;
      if (ml < mpb)
        hg[((size_t)b*mpb + ml)*128 + col] = fmaxf(gacc[j][r], 0.f);
    }
  }
}

// ---------------- fused: perms + SSL partial + out = hl + hg + hs/g2 + zero select --
__global__ __launch_bounds__(128) void k_sslhs(
    const float* __restrict__ hl, const float* __restrict__ hg,
    const int* __restrict__ mask, const float* __restrict__ glu2_w,
    float* __restrict__ out, float* __restrict__ wsLoss,
    float* __restrict__ g2, float* __restrict__ select)
{
  __shared__ uint32_t keys[128];
  __shared__ float red[128];
  __shared__ float hss[128];
  __shared__ int pcS[50];
  __shared__ int prbS;
  int b = blockIdx.x, tid = threadIdx.x;
  select[(size_t)b*128 + tid] = 0.f;
  uint32_t kr0, kr1, kc0, kc1, sk0, sk1, o0, o1;
  tf2x32(0u, 42u, 0u, 0u, &kr0, &kr1);
  tf2x32(0u, 42u, 0u, 1u, &kc0, &kc1);
  tf2x32(kr0, kr1, 0u, 1u, &sk0, &sk1);
  tf2x32(sk0, sk1, 0u, (uint32_t)tid, &o0, &o1);
  keys[tid] = o0 ^ o1;
  __syncthreads();
  {
    uint32_t mk = keys[tid];
    int rank = 0;
    for (int j = 0; j < 128; j++){
      uint32_t kj = keys[j];
      rank += (kj < mk) || (kj == mk && j < tid);
    }
    if (rank == b) prbS = tid;
  }
  __syncthreads();
  tf2x32(kc0, kc1, 0u, 1u, &sk0, &sk1);
  if (tid < 50){
    tf2x32(sk0, sk1, 0u, (uint32_t)tid, &o0, &o1);
    keys[tid] = o0 ^ o1;
  }
  __syncthreads();
  if (tid < 50){
    uint32_t mk = keys[tid];
    int rank = 0;
    for (int j = 0; j < 50; j++){
      uint32_t kj = keys[j];
      rank += (kj < mk) || (kj == mk && j < tid);
    }
    pcS[rank] = tid;
  }
  __syncthreads();
  int prb = prbS, d = tid;
  float pos = 0.f, neg = 0.f, hsacc = 0.f, ms = 0.f;
  for (int l = 0; l < L_; l++){
    size_t off = ((size_t)b*L_ + l)*D_ + d;
    float hlv = hl[off], hgv = hg[off];
    float o = hlv + hgv;
    out[off] = o;
    pos += hlv * hgv;
    neg += hgv * hl[((size_t)prb*L_ + pcS[l])*D_ + d];
    float mk = (float)mask[b*L_ + l];
    ms += mk;
    hsacc += mk * o;
  }
  hss[d] = hsacc / ms;
  red[d] = -logf(1e-8f + sigm_(pos)) - logf(1e-8f + 1.f - sigm_(neg));
  __syncthreads();
  for (int off = 64; off >= 1; off >>= 1){
    if (d < off) red[d] += red[d + off];
    __syncthreads();
  }
  if (d == 0) wsLoss[b] = red[0];
  float g = 0.f;
  for (int e = 0; e < 128; e++) g += hss[e]*glu2_w[d*128 + e];
  g2[(size_t)b*128 + d] = g;
}

// ---------------- beta, 10 l-rows per block; partial select via atomicAdd ----------
__global__ __launch_bounds__(256) void k_beta10(
    const float* __restrict__ hidden, const int* __restrict__ mask,
    const float* __restrict__ pose, const float* __restrict__ w1s,
    const float* __restrict__ w2s, const float* __restrict__ glu1wT,
    const float* __restrict__ glu1b, const float* __restrict__ g2,
    float* __restrict__ select)
{
  __shared__ float x[10][260];
  __shared__ float buf[10][132];
  __shared__ float bufB[2][16];
  __shared__ float bet10[10];
  int lg = blockIdx.x, b = blockIdx.y, tid = threadIdx.x;
  int t = tid & 127, eh = tid >> 7;
  int l0 = lg*10;
  for (int u = tid; u < 10*64; u += 256){
    int row = u >> 6, c4 = u & 63;
    float4 v; int col;
    if (c4 < 32){ v = *(const float4*)(pose + (l0+row)*128 + c4*4); col = c4*4; }
    else        { v = *(const float4*)(hidden + ((size_t)b*L_ + l0+row)*128 + (c4-32)*4); col = 128 + (c4-32)*4; }
    *(float4*)&x[row][col] = v;
  }
  __syncthreads();
  float acc[10];
#pragma unroll
  for (int l = 0; l < 10; l++) acc[l] = 0.f;
  {
    int e0 = eh*128;
    for (int e = e0; e < e0 + 128; e += 4){
      float wa = w1s[(e+0)*128 + t];
      float wb = w1s[(e+1)*128 + t];
      float wc = w1s[(e+2)*128 + t];
      float wd = w1s[(e+3)*128 + t];
#pragma unroll
      for (int l = 0; l < 10; l++){
        float4 xv = *(const float4*)&x[l][e];
        acc[l] += xv.x*wa; acc[l] += xv.y*wb; acc[l] += xv.z*wc; acc[l] += xv.w*wd;
      }
    }
  }
  if (eh == 1){
#pragma unroll
    for (int i = 0; i < 10; i++) buf[i][t] = acc[i];
  }
  __syncthreads();
  if (eh == 0){
#pragma unroll
    for (int i = 0; i < 10; i++) acc[i] += buf[i][t];
  }
  __syncthreads();
  if (eh == 0){
#pragma unroll
    for (int l = 0; l < 10; l++) x[l][t] = tanhf(acc[l]);
  }
  __syncthreads();
  float acc2[10];
#pragma unroll
  for (int l = 0; l < 10; l++) acc2[l] = 0.f;
  {
    int e0 = eh*64;
    for (int e = e0; e < e0 + 64; e += 4){
      float wa = glu1wT[(e+0)*128 + t];
      float wb = glu1wT[(e+1)*128 + t];
      float wc = glu1wT[(e+2)*128 + t];
      float wd = glu1wT[(e+3)*128 + t];
#pragma unroll
      for (int l = 0; l < 10; l++){
        float4 xv = *(const float4*)&x[l][e];
        acc2[l] += xv.x*wa; acc2[l] += xv.y*wb; acc2[l] += xv.z*wc; acc2[l] += xv.w*wd;
      }
    }
  }
  if (eh == 1){
#pragma unroll
    for (int i = 0; i < 10; i++) buf[i][t] = acc2[i];
  }
  __syncthreads();
  if (eh == 0){
#pragma unroll
    for (int i = 0; i < 10; i++) acc2[i] += buf[i][t];
  }
  __syncthreads();
  if (eh == 0){
    float g2v = g2[(size_t)b*128 + t];
    float g1b = glu1b[t];
    float w2v = w2s[t];
    int lane = tid & 63, wv = tid >> 6;
#pragma unroll
    for (int l = 0; l < 10; l++){
      float ns = sigm_(acc2[l] + g1b + g2v);
      float v = ns * w2v;
      v += __shfl_xor(v, 1, 64);
      v += __shfl_xor(v, 2, 64);
      v += __shfl_xor(v, 4, 64);
      v += __shfl_xor(v, 8, 64);
      v += __shfl_xor(v, 16, 64);
      v += __shfl_xor(v, 32, 64);
      if (lane == 0) bufB[wv][l] = v;
    }
  }
  __syncthreads();
  if (tid < 10)
    bet10[tid] = (bufB[0][tid] + bufB[1][tid]) * (float)mask[b*L_ + l0 + tid];
  __syncthreads();
  if (eh == 0){
    float part = 0.f;
#pragma unroll
    for (int i = 0; i < 10; i++) part += bet10[i] * x[i][128 + t];
    atomicAdd(&select[(size_t)b*128 + t], part);
  }
}

// ---------------- cosine softmax + parallel top-9 + neighbor mix (+ norms + loss) ---
__global__ __launch_bounds__(128) void k_topk(const float* __restrict__ select,
                                              const float* __restrict__ wsLoss,
                                              short* __restrict__ select2b,
                                              float* __restrict__ out_loss){
  __shared__ float p[B_];
  __shared__ float red[128];
  __shared__ float nrm[128];
  __shared__ float tv[NBR_];
  __shared__ int   ti[NBR_];
  __shared__ float wvS[2];
  __shared__ int   wiS[2];
  int b = blockIdx.x, t = threadIdx.x;
  float dot = 0.f, nsq = 0.f;
  for (int d = 0; d < D_; d++){
    float sv = select[(size_t)t*D_ + d];
    dot += select[(size_t)b*D_ + d]*sv;
    nsq += sv*sv + 1e-6f;
  }
  nrm[t] = sqrtf(nsq);
  __syncthreads();
  float logit = dot / (nrm[b]*nrm[t]);
  red[t] = logit; __syncthreads();
  for (int off = 64; off >= 1; off >>= 1){
    if (t < off) red[t] = fmaxf(red[t], red[t + off]);
    __syncthreads();
  }
  float mx = red[0]; __syncthreads();
  float e_ = expf(logit - mx);
  red[t] = e_; __syncthreads();
  for (int off = 64; off >= 1; off >>= 1){
    if (t < off) red[t] += red[t + off];
    __syncthreads();
  }
  p[t] = e_ / red[0];
  __syncthreads();
  // parallel top-9: argmax tree with strict larger-value / lower-index tie-break
  // (matches the serial ascending scan with strict '>')
  {
    bool used = false;
    const int lane = t & 63, wv = t >> 6;
    for (int k = 0; k < NBR_; k++){
      float v = used ? -INFINITY : p[t];
      int idx = t;
#pragma unroll
      for (int off = 1; off <= 32; off <<= 1){
        float ov = __shfl_xor(v, off, 64);
        int   oi = __shfl_xor(idx, off, 64);
        if (ov > v || (ov == v && oi < idx)){ v = ov; idx = oi; }
      }
      if (lane == 0){ wvS[wv] = v; wiS[wv] = idx; }
      __syncthreads();
      if (t == 0){
        float v0 = wvS[0], v1 = wvS[1];
        ti[k] = (v1 > v0) ? wiS[1] : wiS[0];
        tv[k] = (v1 > v0) ? v1 : v0;
      }
      __syncthreads();
      if (t == ti[k]) used = true;
    }
  }
  if (t == 0){
    float mx2 = -INFINITY;
    for (int k = 0; k < NBR_; k++) mx2 = fmaxf(mx2, tv[k]);
    float s2 = 0.f;
    float tvl[NBR_];
    for (int k = 0; k < NBR_; k++){ tvl[k] = expf(tv[k]-mx2); s2 += tvl[k]; }
    for (int k = 0; k < NBR_; k++) tv[k] = tvl[k]/s2;
  }
  __syncthreads();
  float nb = 0.f;
#pragma unroll
  for (int k = 0; k < NBR_; k++) nb += tv[k]*select[(size_t)ti[k]*D_ + t];
  select2b[(size_t)b*D_ + t] = f2b(select[(size_t)b*D_ + t] + nb);
  if (b == 0){
    __syncthreads();
    red[t] = wsLoss[t];
    __syncthreads();
    for (int off = 64; off >= 1; off >>= 1){
      if (t < off) red[t] += red[t + off];
      __syncthreads();
    }
    if (t == 0) out_loss[0] = BETA_ * red[0];
  }
}

// ---------------- MFMA scores = sel2 @ emb[1:].T (LDS-staged B) ----------------
__global__ __launch_bounds__(256) void k_scores(
    const short* __restrict__ sel2b, const float* __restrict__ emb,
    float* __restrict__ scores)
{
  __shared__ __align__(16) short Es[64*136];
  const int tid = threadIdx.x;
  const int n0 = blockIdx.x*64;
  for (int it = 0; it < 8; it++){
    int u = it*256 + tid;
    int lr = u >> 5, c = u & 31;
    int n = min(n0 + lr, NSC_ - 1);
    float4 v = *(const float4*)(emb + (size_t)(1 + n)*128 + c*4);
    short4 s4; s4.x=f2b(v.x); s4.y=f2b(v.y); s4.z=f2b(v.z); s4.w=f2b(v.w);
    *(short4*)&Es[lr*136 + c*4] = s4;
  }
  __syncthreads();
  const int lane = tid & 63, wave = tid >> 6;
  const int quad = lane >> 4, l16 = lane & 15;
  int n = n0 + wave*16 + l16;
  f32x4 acc[8];
#pragma unroll
  for (int i=0;i<8;i++) acc[i] = zero4();
  for (int kc = 0; kc < 4; kc++){
    int k = kc*32 + quad*8;
    bf16x8 bb = *(const bf16x8*)&Es[(wave*16 + l16)*136 + k];
#pragma unroll
    for (int rt = 0; rt < 8; rt++){
      bf16x8 a = *(const bf16x8*)&sel2b[(rt*16 + l16)*128 + k];
      acc[rt] = mfma_bf16(a, bb, acc[rt]);
    }
  }
  if (n < NSC_){
#pragma unroll
    for (int rt = 0; rt < 8; rt++)
#pragma unroll
      for (int r = 0; r < 4; r++){
        int brow = rt*16 + quad*4 + r;
        scores[(size_t)brow*NSC_ + n] = acc[rt][r];
      }
  }
}

// ---------------- launcher ----------------
extern "C" void kernel_launch(void* const* d_in, const int* in_sizes, int n_in,
                              void* d_out, int out_size, void* d_ws, size_t ws_size,
                              hipStream_t stream) {
  (void)in_sizes; (void)n_in; (void)out_size; (void)ws_size;
  const int*   inputs  = (const int*)  d_in[0];
  const int*   adj     = (const int*)  d_in[1];
  const int*   mask    = (const int*)  d_in[2];
  const int*   item    = (const int*)  d_in[3];
  const int*   adj_all = (const int*)  d_in[5];
  const float* num_w   = (const float*)d_in[6];
  const float* emb     = (const float*)d_in[7];
  const float* pose    = (const float*)d_in[8];
  const float* a_local = (const float*)d_in[9];
  const float* gw1     = (const float*)d_in[10];
  const float* gw2     = (const float*)d_in[11];
  const float* gw3     = (const float*)d_in[12];
  const float* w1      = (const float*)d_in[13];
  const float* w2      = (const float*)d_in[14];
  const float* glu1w   = (const float*)d_in[15];
  const float* glu1b   = (const float*)d_in[16];
  const float* glu2w   = (const float*)d_in[17];
  float* out = (float*)d_out;

  // workspace layout (float units)
  float* W     = (float*)d_ws;
  float* hl    = W;                    // 819200
  float* hg    = W + 819200;           // 819200
  short* e0pB  = (short*)(W + 1638400);// bf16, 819200 shorts
  short* e1pB  = (short*)(W + 2457600);// bf16, 6553600 shorts
  float* g2    = W + 9027584;          // 16384
  float* sel   = W + 9043968;          // 16384
  short* sel2b = (short*)(W + 9060352);// 16384 shorts
  float* wsLoss= W + 9076864;          // 128
  float* n1w   = W + 9076992;          // 51200
  float* n2w   = W + 9128192;          // 409600
  float* glu1wT= W + 9576960;          // 16384
  short* w3Tb  = (short*)(W + 9593344);// 2*128*264 shorts
  int*   n1i   = (int*)(W + 9627136);  // 51200
  int*   n2i   = n1i + 51200;          // 409600

  // d_out scratch (scores region, fully overwritten by k_scores at the end):
  short* embB   = (short*)(out + 819712);
  short* BsessG = (short*)(out + 819712 + 3200000);

  k_prep_all<<<3901, 256, 0, stream>>>(emb, item, mask, gw1, gw3, glu1w,
                                       inputs, adj_all, num_w,
                                       embB, glu1wT, w3Tb,
                                       n1i, n1w, n2i, n2w, BsessG);

  // local + att hop0 i0 + att hop0 i1 in one dispatch
  k_fused1<<<3968, 256, 0, stream>>>(embB, inputs, adj, a_local, hl,
                                     n1i, n1w, n2i, n2w, BsessG,
                                     gw1, gw2, e0pB, e1pB);
  // hop0 i0 + i1 gout merged
  k_gout2<<<900, 256, 0, stream>>>(embB, inputs, n1i, w3Tb, e0pB, e1pB);

  // hop1 fused att+gout -> hg
  k_attg1<<<dim3(4, B_), 256, 0, stream>>>(e1pB, e0pB, n1w,
                                           BsessG + (size_t)128*16384,
                                           gw1 + 129*128, gw2 + 128,
                                           w3Tb + 128*264, hg);

  k_sslhs<<<B_, 128, 0, stream>>>(hl, hg, mask, glu2w, out, wsLoss, g2, sel);
  k_beta10<<<dim3(5, B_), 256, 0, stream>>>(out, mask, pose, w1, w2, glu1wT,
                                            glu1b, g2, sel);
  k_topk<<<B_, 128, 0, stream>>>(sel, wsLoss, sel2b, out + B_*L_*D_);
  k_scores<<<(NSC_ + 63)/64, 256, 0, stream>>>(sel2b, emb, out + B_*L_*D_ + 1);
}